// Round 1
// baseline (2222.684 us; speedup 1.0000x reference)
//
#include <hip/hip_runtime.h>
#include <math.h>

// Problem constants
#define BB 4
#define LL 512
#define DMODEL 1024
#define DSTATE 16
#define DCONV 4
#define DINNER 2048
#define DTRANK 64
#define MROWS (BB*LL)          // 2048 rows of (b,l)

__device__ __forceinline__ float softplusf(float x) {
    return x > 20.f ? x : log1pf(__expf(x));
}

// ---------------------------------------------------------------------------
// Generic TN GEMM: C[M][N] = A[M][K] * W[N][K]^T  (both K-contiguous)
// 128x128 tile, 256 threads, 8x8 per thread, BK=16.
// EPI 0: none; 1: dt epilogue softplus(clip(acc+bias,1e-5,1)+bias); 2: nan_to_num
// M must be a multiple of 128 (always 2048 here). N bounds-checked.
// ---------------------------------------------------------------------------
template<int EPI>
__global__ __launch_bounds__(256) void gemm_tn(
    const float* __restrict__ A, const float* __restrict__ W,
    float* __restrict__ C, const float* __restrict__ bias,
    int N, int K, int lda, int ldw, int ldc)
{
    __shared__ float As[128][17];
    __shared__ float Ws[128][17];
    const int tid = threadIdx.x;
    const int tx = tid & 15;        // 0..15 -> col group
    const int ty = tid >> 4;        // 0..15 -> row group
    const int rowBase = blockIdx.y * 128;
    const int colBase = blockIdx.x * 128;

    float acc[8][8];
#pragma unroll
    for (int i = 0; i < 8; ++i)
#pragma unroll
        for (int j = 0; j < 8; ++j) acc[i][j] = 0.f;

    for (int k0 = 0; k0 < K; k0 += 16) {
#pragma unroll
        for (int i = 0; i < 8; ++i) {
            int e = tid + i * 256;          // 0..2047
            int r = e >> 4, kk = e & 15;
            As[r][kk] = A[(size_t)(rowBase + r) * lda + (k0 + kk)];
            int wr = colBase + r;
            Ws[r][kk] = (wr < N) ? W[(size_t)wr * ldw + (k0 + kk)] : 0.f;
        }
        __syncthreads();
#pragma unroll
        for (int kk = 0; kk < 16; ++kk) {
            float a[8], w[8];
#pragma unroll
            for (int i = 0; i < 8; ++i) a[i] = As[ty + 16 * i][kk];
#pragma unroll
            for (int j = 0; j < 8; ++j) w[j] = Ws[tx + 16 * j][kk];
#pragma unroll
            for (int i = 0; i < 8; ++i)
#pragma unroll
                for (int j = 0; j < 8; ++j) acc[i][j] += a[i] * w[j];
        }
        __syncthreads();
    }

#pragma unroll
    for (int i = 0; i < 8; ++i) {
        int r = rowBase + ty + 16 * i;
#pragma unroll
        for (int j = 0; j < 8; ++j) {
            int c = colBase + tx + 16 * j;
            if (c < N) {
                float v = acc[i][j];
                if (EPI == 1) {
                    float t = v + bias[c];
                    t = fminf(fmaxf(t, 1e-5f), 1.0f);
                    v = softplusf(t + bias[c]);
                } else if (EPI == 2) {
                    if (isnan(v)) v = 0.f;
                    else if (isinf(v)) v = (v > 0.f) ? 1.f : -1.f;
                }
                C[(size_t)r * ldc + c] = v;
            }
        }
    }
}

// ---------------------------------------------------------------------------
// Depthwise causal conv1d, both directions. xz layout: [b*L + l][4096]
// x channel d = xz[.][d]. Bwd consumes time-reversed x and writes in the
// reversed layout (row = position in reversed sequence).
// ---------------------------------------------------------------------------
__global__ __launch_bounds__(256) void conv_kernel(
    const float* __restrict__ xz,
    const float* __restrict__ wf, const float* __restrict__ bf,
    const float* __restrict__ wb, const float* __restrict__ bb,
    float* __restrict__ xcf, float* __restrict__ xcb)
{
    int idx = blockIdx.x * 256 + threadIdx.x;   // 2*B*L*DINNER threads
    int d = idx & (DINNER - 1);
    int rest = idx >> 11;          // dir*2048 + b*512 + l
    int l = rest & (LL - 1);
    int b = (rest >> 9) & (BB - 1);
    int dir = rest >> 11;

    const float* w = dir ? wb : wf;
    float accv = (dir ? bb : bf)[d];
#pragma unroll
    for (int k = 0; k < DCONV; ++k) {
        int j = l - (DCONV - 1) + k;
        if (j >= 0) {
            int jj = dir ? (LL - 1 - j) : j;
            accv += w[d * DCONV + k] * xz[((size_t)(b * LL + jj)) * (2 * DINNER) + d];
        }
    }
    (dir ? xcb : xcf)[((size_t)(b * LL + l)) * DINNER + d] = accv;
}

// ---------------------------------------------------------------------------
// Selective scan. One thread per (dir, b, d): 16 states in registers,
// 512 sequential steps. Reads delta from dl (G3 output), overwrites the
// same element with y (+u*D) -> race-free, replay-safe.
// ---------------------------------------------------------------------------
__global__ __launch_bounds__(256) void scan_kernel(
    const float* __restrict__ Alog_f, const float* __restrict__ Alog_b,
    const float* __restrict__ Df, const float* __restrict__ Db,
    const float* __restrict__ xdbl_f, const float* __restrict__ xdbl_b,
    const float* __restrict__ xc_f, const float* __restrict__ xc_b,
    float* __restrict__ dl_f, float* __restrict__ dl_b)
{
    int g = blockIdx.x * 256 + threadIdx.x;     // 2*B*DINNER
    int d = g & (DINNER - 1);
    int b = (g >> 11) & (BB - 1);
    int dir = g >> 13;

    const float* Alog = dir ? Alog_b : Alog_f;
    const float* xdbl = dir ? xdbl_b : xdbl_f;
    const float* xc   = dir ? xc_b   : xc_f;
    float* dl         = dir ? dl_b   : dl_f;
    float Dv = (dir ? Db : Df)[d];

    float Aa[DSTATE], h[DSTATE];
#pragma unroll
    for (int n = 0; n < DSTATE; ++n) {
        Aa[n] = -__expf(Alog[d * DSTATE + n]);
        h[n] = 0.f;
    }

    for (int t = 0; t < LL; ++t) {
        size_t row = (size_t)(b * LL + t);
        float delta = dl[row * DINNER + d];
        float u = xc[row * DINNER + d];
        u = fminf(fmaxf(u, -10.f), 10.f);
        float du = delta * u;
        const float* bc = xdbl + row * 96 + DTRANK;
        float y = 0.f;
#pragma unroll
        for (int n = 0; n < DSTATE; ++n) {
            h[n] = __expf(delta * Aa[n]) * h[n] + du * bc[n];
            y += h[n] * bc[DSTATE + n];
        }
        dl[row * DINNER + d] = y + u * Dv;
    }
}

// ---------------------------------------------------------------------------
// Gate: ytot[b,l,d] = (y_f[b,l,d] + y_b[b, L-1-l, d]) * silu(z[b,l,d])
// ---------------------------------------------------------------------------
__global__ __launch_bounds__(256) void gate_kernel(
    const float* __restrict__ yf, const float* __restrict__ yb,
    const float* __restrict__ xz, float* __restrict__ ytot)
{
    int idx = blockIdx.x * 256 + threadIdx.x;   // B*L*DINNER
    int d = idx & (DINNER - 1);
    int l = (idx >> 11) & (LL - 1);
    int b = idx >> 20;
    size_t rowf = (size_t)(b * LL + l);
    size_t rowb = (size_t)(b * LL + (LL - 1 - l));
    float y = yf[rowf * DINNER + d] + yb[rowb * DINNER + d];
    float z = xz[rowf * (2 * DINNER) + DINNER + d];
    float s = z / (1.f + __expf(-z));
    ytot[rowf * DINNER + d] = y * s;
}

// ---------------------------------------------------------------------------
extern "C" void kernel_launch(void* const* d_in, const int* in_sizes, int n_in,
                              void* d_out, int out_size, void* d_ws, size_t ws_size,
                              hipStream_t stream)
{
    const float* hidden    = (const float*)d_in[0];
    const float* in_proj_w = (const float*)d_in[1];
    const float* conv_w    = (const float*)d_in[2];
    const float* conv_b    = (const float*)d_in[3];
    const float* xproj_w   = (const float*)d_in[4];
    const float* dtproj_w  = (const float*)d_in[5];
    const float* dtproj_b  = (const float*)d_in[6];
    const float* A_log     = (const float*)d_in[7];
    const float* Dvec      = (const float*)d_in[8];
    const float* conv_bw   = (const float*)d_in[9];
    const float* conv_bb   = (const float*)d_in[10];
    const float* xproj_bw  = (const float*)d_in[11];
    const float* dtproj_bw = (const float*)d_in[12];
    const float* dtproj_bb = (const float*)d_in[13];
    const float* A_b_log   = (const float*)d_in[14];
    const float* D_b       = (const float*)d_in[15];
    const float* out_pw    = (const float*)d_in[16];
    float* out = (float*)d_out;

    float* ws = (float*)d_ws;
    float* xz     = ws;                      // 2048*4096 = 8388608
    float* xc_f   = xz + 8388608;            // 2048*2048 = 4194304
    float* xc_b   = xc_f + 4194304;          // 4194304
    float* xdbl_f = xc_b + 4194304;          // 2048*96 = 196608
    float* xdbl_b = xdbl_f + 196608;         // 196608
    float* dl_f   = xdbl_b + 196608;         // 4194304 (delta -> y)
    float* dl_b   = dl_f + 4194304;          // 4194304
    float* ytot   = xc_f;                    // reuse (xc consumed by scan)

    dim3 blk(256);

    // G1: xz = hidden @ in_proj_w.T   (M=2048, N=4096, K=1024)
    gemm_tn<0><<<dim3(4096 / 128, MROWS / 128), blk, 0, stream>>>(
        hidden, in_proj_w, xz, nullptr, 4096, 1024, 1024, 1024, 4096);

    // conv both dirs
    conv_kernel<<<dim3(2 * BB * LL * DINNER / 256), blk, 0, stream>>>(
        xz, conv_w, conv_b, conv_bw, conv_bb, xc_f, xc_b);

    // G2: x_dbl = xc @ x_proj_w.T  (M=2048, N=96, K=2048)
    gemm_tn<0><<<dim3(1, MROWS / 128), blk, 0, stream>>>(
        xc_f, xproj_w, xdbl_f, nullptr, 96, 2048, 2048, 2048, 96);
    gemm_tn<0><<<dim3(1, MROWS / 128), blk, 0, stream>>>(
        xc_b, xproj_bw, xdbl_b, nullptr, 96, 2048, 2048, 2048, 96);

    // G3: delta = softplus(clip(xdbl[:, :64] @ dtw.T + b, 1e-5, 1) + b)
    gemm_tn<1><<<dim3(DINNER / 128, MROWS / 128), blk, 0, stream>>>(
        xdbl_f, dtproj_w, dl_f, dtproj_b, 2048, 64, 96, 64, 2048);
    gemm_tn<1><<<dim3(DINNER / 128, MROWS / 128), blk, 0, stream>>>(
        xdbl_b, dtproj_bw, dl_b, dtproj_bb, 2048, 64, 96, 64, 2048);

    // scan (both dirs)
    scan_kernel<<<dim3(2 * BB * DINNER / 256), blk, 0, stream>>>(
        A_log, A_b_log, Dvec, D_b, xdbl_f, xdbl_b, xc_f, xc_b, dl_f, dl_b);

    // gate
    gate_kernel<<<dim3(BB * LL * DINNER / 256), blk, 0, stream>>>(
        dl_f, dl_b, xz, ytot);

    // G4: out = ytot @ out_proj_w.T  (M=2048, N=1024, K=2048) + nan_to_num
    gemm_tn<2><<<dim3(DMODEL / 128, MROWS / 128), blk, 0, stream>>>(
        ytot, out_pw, out, nullptr, 1024, 2048, 2048, 2048, 1024);
}

// Round 2
// 1319.341 us; speedup vs baseline: 1.6847x; 1.6847x over previous
//
#include <hip/hip_runtime.h>
#include <math.h>

// Problem constants
#define BB 4
#define LL 512
#define DMODEL 1024
#define DSTATE 16
#define DCONV 4
#define DINNER 2048
#define DTRANK 64
#define MROWS (BB*LL)          // 2048 rows of (b,l)
#define G2KS 2                 // split-K factor for the N=96 GEMM

__device__ __forceinline__ float softplusf(float x) {
    return x > 20.f ? x : log1pf(__expf(x));
}

// ---------------------------------------------------------------------------
// Generic TN GEMM: C[M][N] = A[M][K] * W[N][K]^T  (both K-contiguous)
// 128x128 tile, 256 threads, 8x8 per thread, BK=16.
// EPI 0: none; 1: dt epilogue softplus(clip(acc+bias,1e-5,1)+bias); 2: nan_to_num
// ---------------------------------------------------------------------------
template<int EPI>
__global__ __launch_bounds__(256) void gemm_tn(
    const float* __restrict__ A, const float* __restrict__ W,
    float* __restrict__ C, const float* __restrict__ bias,
    int N, int K, int lda, int ldw, int ldc)
{
    __shared__ float As[128][17];
    __shared__ float Ws[128][17];
    const int tid = threadIdx.x;
    const int tx = tid & 15;        // 0..15 -> col group
    const int ty = tid >> 4;        // 0..15 -> row group
    const int rowBase = blockIdx.y * 128;
    const int colBase = blockIdx.x * 128;

    float acc[8][8];
#pragma unroll
    for (int i = 0; i < 8; ++i)
#pragma unroll
        for (int j = 0; j < 8; ++j) acc[i][j] = 0.f;

    for (int k0 = 0; k0 < K; k0 += 16) {
#pragma unroll
        for (int i = 0; i < 8; ++i) {
            int e = tid + i * 256;          // 0..2047
            int r = e >> 4, kk = e & 15;
            As[r][kk] = A[(size_t)(rowBase + r) * lda + (k0 + kk)];
            int wr = colBase + r;
            Ws[r][kk] = (wr < N) ? W[(size_t)wr * ldw + (k0 + kk)] : 0.f;
        }
        __syncthreads();
#pragma unroll
        for (int kk = 0; kk < 16; ++kk) {
            float a[8], w[8];
#pragma unroll
            for (int i = 0; i < 8; ++i) a[i] = As[ty + 16 * i][kk];
#pragma unroll
            for (int j = 0; j < 8; ++j) w[j] = Ws[tx + 16 * j][kk];
#pragma unroll
            for (int i = 0; i < 8; ++i)
#pragma unroll
                for (int j = 0; j < 8; ++j) acc[i][j] += a[i] * w[j];
        }
        __syncthreads();
    }

#pragma unroll
    for (int i = 0; i < 8; ++i) {
        int r = rowBase + ty + 16 * i;
#pragma unroll
        for (int j = 0; j < 8; ++j) {
            int c = colBase + tx + 16 * j;
            if (c < N) {
                float v = acc[i][j];
                if (EPI == 1) {
                    float t = v + bias[c];
                    t = fminf(fmaxf(t, 1e-5f), 1.0f);
                    v = softplusf(t + bias[c]);
                } else if (EPI == 2) {
                    if (isnan(v)) v = 0.f;
                    else if (isinf(v)) v = (v > 0.f) ? 1.f : -1.f;
                }
                C[(size_t)r * ldc + c] = v;
            }
        }
    }
}

// ---------------------------------------------------------------------------
// G2 specialized: x_dbl[dir] = xc[dir] @ xproj[dir].T   (M=2048, N=96, K=2048)
// Fused both dirs + split-K. grid = (64 Mtiles of 32 rows, G2KS, 2 dirs)
// = 256 blocks. Writes partials; g2_reduce sums them.
// ---------------------------------------------------------------------------
__global__ __launch_bounds__(256) void g2_kernel(
    const float* __restrict__ xc_f, const float* __restrict__ xc_b,
    const float* __restrict__ wf, const float* __restrict__ wb,
    float* __restrict__ part)   // [2][G2KS][2048][96]
{
    const int dir = blockIdx.z;
    const float* A = dir ? xc_b : xc_f;
    const float* W = dir ? wb : wf;
    const int rowBase = blockIdx.x * 32;
    const int kBase = blockIdx.y * (2048 / G2KS);

    __shared__ float As[32][36];     // row stride 144B (16B aligned)
    __shared__ float WsT[32][100];   // [kk][col], read stride-1 conflict-free

    const int tid = threadIdx.x;
    const int tx = tid & 31;
    const int ty = tid >> 5;

    float acc[4][3];
#pragma unroll
    for (int i = 0; i < 4; ++i)
#pragma unroll
        for (int j = 0; j < 3; ++j) acc[i][j] = 0.f;

    for (int k0 = 0; k0 < 2048 / G2KS; k0 += 32) {
        {   // A tile: 32 rows x 32 k -> 256 float4, 1 per thread
            int r = tid >> 3, q = tid & 7;
            const float4 v = *(const float4*)&A[(size_t)(rowBase + r) * 2048 + kBase + k0 + q * 4];
            *(float4*)&As[r][q * 4] = v;
        }
#pragma unroll
        for (int t = 0; t < 3; ++t) {   // W tile: 96 rows x 32 k, transposed
            int idx = tid + 256 * t;
            int wr = idx >> 3, q = idx & 7;
            const float4 v = *(const float4*)&W[(size_t)wr * 2048 + kBase + k0 + q * 4];
            WsT[q * 4 + 0][wr] = v.x;
            WsT[q * 4 + 1][wr] = v.y;
            WsT[q * 4 + 2][wr] = v.z;
            WsT[q * 4 + 3][wr] = v.w;
        }
        __syncthreads();
#pragma unroll
        for (int kk = 0; kk < 32; ++kk) {
            float a[4], w[3];
#pragma unroll
            for (int i = 0; i < 4; ++i) a[i] = As[ty + 8 * i][kk];
#pragma unroll
            for (int j = 0; j < 3; ++j) w[j] = WsT[kk][tx + 32 * j];
#pragma unroll
            for (int i = 0; i < 4; ++i)
#pragma unroll
                for (int j = 0; j < 3; ++j) acc[i][j] += a[i] * w[j];
        }
        __syncthreads();
    }

    float* p = part + ((size_t)(dir * G2KS + blockIdx.y) * 2048) * 96;
#pragma unroll
    for (int i = 0; i < 4; ++i) {
        int r = rowBase + ty + 8 * i;
#pragma unroll
        for (int j = 0; j < 3; ++j)
            p[(size_t)r * 96 + tx + 32 * j] = acc[i][j];
    }
}

__global__ __launch_bounds__(256) void g2_reduce(
    const float* __restrict__ part, float* __restrict__ xf, float* __restrict__ xb)
{
    int idx = blockIdx.x * 256 + threadIdx.x;   // 2*2048*96 total
    int c = idx % 96;
    int r = (idx / 96) & 2047;
    int dir = idx / (96 * 2048);
    float s = 0.f;
#pragma unroll
    for (int ks = 0; ks < G2KS; ++ks)
        s += part[((size_t)(dir * G2KS + ks) * 2048 + r) * 96 + c];
    (dir ? xb : xf)[(size_t)r * 96 + c] = s;
}

// ---------------------------------------------------------------------------
// Depthwise causal conv1d, both directions.
// ---------------------------------------------------------------------------
__global__ __launch_bounds__(256) void conv_kernel(
    const float* __restrict__ xz,
    const float* __restrict__ wf, const float* __restrict__ bf,
    const float* __restrict__ wb, const float* __restrict__ bb,
    float* __restrict__ xcf, float* __restrict__ xcb)
{
    int idx = blockIdx.x * 256 + threadIdx.x;   // 2*B*L*DINNER threads
    int d = idx & (DINNER - 1);
    int rest = idx >> 11;          // dir*2048 + b*512 + l
    int l = rest & (LL - 1);
    int b = (rest >> 9) & (BB - 1);
    int dir = rest >> 11;

    const float* w = dir ? wb : wf;
    float accv = (dir ? bb : bf)[d];
#pragma unroll
    for (int k = 0; k < DCONV; ++k) {
        int j = l - (DCONV - 1) + k;
        if (j >= 0) {
            int jj = dir ? (LL - 1 - j) : j;
            accv += w[d * DCONV + k] * xz[((size_t)(b * LL + jj)) * (2 * DINNER) + d];
        }
    }
    (dir ? xcb : xcf)[((size_t)(b * LL + l)) * DINNER + d] = accv;
}

// ---------------------------------------------------------------------------
// Selective scan. One thread per (dir, b, d).
// ---------------------------------------------------------------------------
__global__ __launch_bounds__(256) void scan_kernel(
    const float* __restrict__ Alog_f, const float* __restrict__ Alog_b,
    const float* __restrict__ Df, const float* __restrict__ Db,
    const float* __restrict__ xdbl_f, const float* __restrict__ xdbl_b,
    const float* __restrict__ xc_f, const float* __restrict__ xc_b,
    float* __restrict__ dl_f, float* __restrict__ dl_b)
{
    int g = blockIdx.x * 256 + threadIdx.x;     // 2*B*DINNER
    int d = g & (DINNER - 1);
    int b = (g >> 11) & (BB - 1);
    int dir = g >> 13;

    const float* Alog = dir ? Alog_b : Alog_f;
    const float* xdbl = dir ? xdbl_b : xdbl_f;
    const float* xc   = dir ? xc_b   : xc_f;
    float* dl         = dir ? dl_b   : dl_f;
    float Dv = (dir ? Db : Df)[d];

    float Aa[DSTATE], h[DSTATE];
#pragma unroll
    for (int n = 0; n < DSTATE; ++n) {
        Aa[n] = -__expf(Alog[d * DSTATE + n]);
        h[n] = 0.f;
    }

    for (int t = 0; t < LL; ++t) {
        size_t row = (size_t)(b * LL + t);
        float delta = dl[row * DINNER + d];
        float u = xc[row * DINNER + d];
        u = fminf(fmaxf(u, -10.f), 10.f);
        float du = delta * u;
        const float* bc = xdbl + row * 96 + DTRANK;
        float y = 0.f;
#pragma unroll
        for (int n = 0; n < DSTATE; ++n) {
            h[n] = __expf(delta * Aa[n]) * h[n] + du * bc[n];
            y += h[n] * bc[DSTATE + n];
        }
        dl[row * DINNER + d] = y + u * Dv;
    }
}

// ---------------------------------------------------------------------------
// Gate: ytot[b,l,d] = (y_f[b,l,d] + y_b[b, L-1-l, d]) * silu(z[b,l,d])
// ---------------------------------------------------------------------------
__global__ __launch_bounds__(256) void gate_kernel(
    const float* __restrict__ yf, const float* __restrict__ yb,
    const float* __restrict__ xz, float* __restrict__ ytot)
{
    int idx = blockIdx.x * 256 + threadIdx.x;   // B*L*DINNER
    int d = idx & (DINNER - 1);
    int l = (idx >> 11) & (LL - 1);
    int b = idx >> 20;
    size_t rowf = (size_t)(b * LL + l);
    size_t rowb = (size_t)(b * LL + (LL - 1 - l));
    float y = yf[rowf * DINNER + d] + yb[rowb * DINNER + d];
    float z = xz[rowf * (2 * DINNER) + DINNER + d];
    float s = z / (1.f + __expf(-z));
    ytot[rowf * DINNER + d] = y * s;
}

// ---------------------------------------------------------------------------
extern "C" void kernel_launch(void* const* d_in, const int* in_sizes, int n_in,
                              void* d_out, int out_size, void* d_ws, size_t ws_size,
                              hipStream_t stream)
{
    const float* hidden    = (const float*)d_in[0];
    const float* in_proj_w = (const float*)d_in[1];
    const float* conv_w    = (const float*)d_in[2];
    const float* conv_b    = (const float*)d_in[3];
    const float* xproj_w   = (const float*)d_in[4];
    const float* dtproj_w  = (const float*)d_in[5];
    const float* dtproj_b  = (const float*)d_in[6];
    const float* A_log     = (const float*)d_in[7];
    const float* Dvec      = (const float*)d_in[8];
    const float* conv_bw   = (const float*)d_in[9];
    const float* conv_bb   = (const float*)d_in[10];
    const float* xproj_bw  = (const float*)d_in[11];
    const float* dtproj_bw = (const float*)d_in[12];
    const float* dtproj_bb = (const float*)d_in[13];
    const float* A_b_log   = (const float*)d_in[14];
    const float* D_b       = (const float*)d_in[15];
    const float* out_pw    = (const float*)d_in[16];
    float* out = (float*)d_out;

    float* ws = (float*)d_ws;
    float* xz     = ws;                      // 2048*4096 = 8388608
    float* xc_f   = xz + 8388608;            // 4194304
    float* xc_b   = xc_f + 4194304;          // 4194304
    float* xdbl_f = xc_b + 4194304;          // 196608
    float* xdbl_b = xdbl_f + 196608;         // 196608
    float* dl_f   = xdbl_b + 196608;         // 4194304 (delta -> y)
    float* dl_b   = dl_f + 4194304;          // 4194304
    float* g2part = dl_b + 4194304;          // 2*G2KS*2048*96 = 786432
    float* ytot   = xc_f;                    // reuse (xc consumed by scan)

    dim3 blk(256);

    // G1: xz = hidden @ in_proj_w.T   (M=2048, N=4096, K=1024)
    gemm_tn<0><<<dim3(4096 / 128, MROWS / 128), blk, 0, stream>>>(
        hidden, in_proj_w, xz, nullptr, 4096, 1024, 1024, 1024, 4096);

    // conv both dirs
    conv_kernel<<<dim3(2 * BB * LL * DINNER / 256), blk, 0, stream>>>(
        xz, conv_w, conv_b, conv_bw, conv_bb, xc_f, xc_b);

    // G2: x_dbl = xc @ x_proj_w.T  (both dirs, split-K, 256 blocks)
    g2_kernel<<<dim3(64, G2KS, 2), blk, 0, stream>>>(
        xc_f, xc_b, xproj_w, xproj_bw, g2part);
    g2_reduce<<<dim3(2 * 2048 * 96 / 256), blk, 0, stream>>>(
        g2part, xdbl_f, xdbl_b);

    // G3: delta = softplus(clip(xdbl[:, :64] @ dtw.T + b, 1e-5, 1) + b)
    gemm_tn<1><<<dim3(DINNER / 128, MROWS / 128), blk, 0, stream>>>(
        xdbl_f, dtproj_w, dl_f, dtproj_b, 2048, 64, 96, 64, 2048);
    gemm_tn<1><<<dim3(DINNER / 128, MROWS / 128), blk, 0, stream>>>(
        xdbl_b, dtproj_bw, dl_b, dtproj_bb, 2048, 64, 96, 64, 2048);

    // scan (both dirs)
    scan_kernel<<<dim3(2 * BB * DINNER / 256), blk, 0, stream>>>(
        A_log, A_b_log, Dvec, D_b, xdbl_f, xdbl_b, xc_f, xc_b, dl_f, dl_b);

    // gate
    gate_kernel<<<dim3(BB * LL * DINNER / 256), blk, 0, stream>>>(
        dl_f, dl_b, xz, ytot);

    // G4: out = ytot @ out_proj_w.T  (M=2048, N=1024, K=2048) + nan_to_num
    gemm_tn<2><<<dim3(DMODEL / 128, MROWS / 128), blk, 0, stream>>>(
        ytot, out_pw, out, nullptr, 1024, 2048, 2048, 2048, 1024);
}

// Round 3
// 606.414 us; speedup vs baseline: 3.6653x; 2.1756x over previous
//
#include <hip/hip_runtime.h>
#include <hip/hip_bf16.h>
#include <math.h>

// Problem constants
#define BB 4
#define LL 512
#define DMODEL 1024
#define DSTATE 16
#define DCONV 4
#define DINNER 2048
#define DTRANK 64
#define MROWS (BB*LL)          // 2048 rows of (b,l)
#define G2KS 2                 // split-K factor for the N=96 GEMM

typedef __hip_bfloat16 bf16;
typedef __attribute__((ext_vector_type(8))) short short8;
typedef __attribute__((ext_vector_type(4))) float f32x4;

__device__ __forceinline__ float softplusf(float x) {
    return x > 20.f ? x : log1pf(__expf(x));
}

// ---------------------------------------------------------------------------
// bf16 MFMA TN GEMM: C[M][N](f32) = A[M][K](bf16) * W[N][K](bf16)^T
// 128x128 tile, 256 threads = 4 waves (2x2), 4x4 16x16x32 fragments per wave.
// M, N multiples of 128; K multiple of 32.
// EPI 0: none; 2: nan_to_num
// ---------------------------------------------------------------------------
template<int EPI>
__global__ __launch_bounds__(256) void gemm_bf16(
    const bf16* __restrict__ A, const bf16* __restrict__ W,
    float* __restrict__ C, int N, int K, int lda, int ldw, int ldc)
{
    // LDS tiles: [128 rows][40 bf16] (32 used + 8 pad), 80B row stride (16B-mult)
    __shared__ bf16 lA[128 * 40];
    __shared__ bf16 lW[128 * 40];

    const int tid = threadIdx.x;
    const int lane = tid & 63;
    const int wid = tid >> 6;        // 0..3
    const int wr = wid >> 1;         // wave row 0..1 (64-row half)
    const int wc = wid & 1;          // wave col 0..1 (64-col half)
    const int rowBase = blockIdx.y * 128;
    const int colBase = blockIdx.x * 128;

    const int r16 = lane & 15;       // fragment row/col within 16
    const int kg = lane >> 4;        // k-group 0..3 (8 k each)

    f32x4 acc[4][4];
#pragma unroll
    for (int m = 0; m < 4; ++m)
#pragma unroll
        for (int n = 0; n < 4; ++n) acc[m][n] = (f32x4)0.f;

    // staging coords: thread covers 8 consecutive k of one row
    const int srow = tid >> 2;            // 0..63 (+64 on second iter)
    const int scol = (tid & 3) * 8;       // 0,8,16,24

    for (int k0 = 0; k0 < K; k0 += 32) {
#pragma unroll
        for (int it = 0; it < 2; ++it) {
            int r = srow + it * 64;
            short8 va = *(const short8*)&A[(size_t)(rowBase + r) * lda + k0 + scol];
            short8 vw = *(const short8*)&W[(size_t)(colBase + r) * ldw + k0 + scol];
            *(short8*)&lA[r * 40 + scol] = va;
            *(short8*)&lW[r * 40 + scol] = vw;
        }
        __syncthreads();

        short8 a[4], b[4];
#pragma unroll
        for (int m = 0; m < 4; ++m)
            a[m] = *(const short8*)&lA[(wr * 64 + m * 16 + r16) * 40 + kg * 8];
#pragma unroll
        for (int n = 0; n < 4; ++n)
            b[n] = *(const short8*)&lW[(wc * 64 + n * 16 + r16) * 40 + kg * 8];
#pragma unroll
        for (int m = 0; m < 4; ++m)
#pragma unroll
            for (int n = 0; n < 4; ++n)
                acc[m][n] = __builtin_amdgcn_mfma_f32_16x16x32_bf16(
                    a[m], b[n], acc[m][n], 0, 0, 0);
        __syncthreads();
    }

    // C/D layout (m89/m91): col = lane&15, row = (lane>>4)*4 + reg
#pragma unroll
    for (int m = 0; m < 4; ++m) {
#pragma unroll
        for (int n = 0; n < 4; ++n) {
            int gc = colBase + wc * 64 + n * 16 + r16;
#pragma unroll
            for (int j = 0; j < 4; ++j) {
                int gr = rowBase + wr * 64 + m * 16 + kg * 4 + j;
                float v = acc[m][n][j];
                if (EPI == 2) {
                    if (isnan(v)) v = 0.f;
                    else if (isinf(v)) v = (v > 0.f) ? 1.f : -1.f;
                }
                C[(size_t)gr * ldc + gc] = v;
            }
        }
    }
}

// ---------------------------------------------------------------------------
// f32 -> bf16 cast, 8 elems/thread
// ---------------------------------------------------------------------------
__global__ __launch_bounds__(256) void cast_kernel(
    const float* __restrict__ in, bf16* __restrict__ out, int n)
{
    int i = (blockIdx.x * 256 + threadIdx.x) * 8;
    if (i >= n) return;
    float4 x = *(const float4*)&in[i];
    float4 y = *(const float4*)&in[i + 4];
    bf16 t[8] = { __float2bfloat16(x.x), __float2bfloat16(x.y),
                  __float2bfloat16(x.z), __float2bfloat16(x.w),
                  __float2bfloat16(y.x), __float2bfloat16(y.y),
                  __float2bfloat16(y.z), __float2bfloat16(y.w) };
    *(short8*)&out[i] = *(short8*)t;
}

// ---------------------------------------------------------------------------
// Generic fp32 TN GEMM (kept for G3 only). EPI 1: dt epilogue.
// ---------------------------------------------------------------------------
template<int EPI>
__global__ __launch_bounds__(256) void gemm_tn(
    const float* __restrict__ A, const float* __restrict__ W,
    float* __restrict__ C, const float* __restrict__ bias,
    int N, int K, int lda, int ldw, int ldc)
{
    __shared__ float As[128][17];
    __shared__ float Ws[128][17];
    const int tid = threadIdx.x;
    const int tx = tid & 15;
    const int ty = tid >> 4;
    const int rowBase = blockIdx.y * 128;
    const int colBase = blockIdx.x * 128;

    float acc[8][8];
#pragma unroll
    for (int i = 0; i < 8; ++i)
#pragma unroll
        for (int j = 0; j < 8; ++j) acc[i][j] = 0.f;

    for (int k0 = 0; k0 < K; k0 += 16) {
#pragma unroll
        for (int i = 0; i < 8; ++i) {
            int e = tid + i * 256;
            int r = e >> 4, kk = e & 15;
            As[r][kk] = A[(size_t)(rowBase + r) * lda + (k0 + kk)];
            int wr = colBase + r;
            Ws[r][kk] = (wr < N) ? W[(size_t)wr * ldw + (k0 + kk)] : 0.f;
        }
        __syncthreads();
#pragma unroll
        for (int kk = 0; kk < 16; ++kk) {
            float a[8], w[8];
#pragma unroll
            for (int i = 0; i < 8; ++i) a[i] = As[ty + 16 * i][kk];
#pragma unroll
            for (int j = 0; j < 8; ++j) w[j] = Ws[tx + 16 * j][kk];
#pragma unroll
            for (int i = 0; i < 8; ++i)
#pragma unroll
                for (int j = 0; j < 8; ++j) acc[i][j] += a[i] * w[j];
        }
        __syncthreads();
    }

#pragma unroll
    for (int i = 0; i < 8; ++i) {
        int r = rowBase + ty + 16 * i;
#pragma unroll
        for (int j = 0; j < 8; ++j) {
            int c = colBase + tx + 16 * j;
            if (c < N) {
                float v = acc[i][j];
                if (EPI == 1) {
                    float t = v + bias[c];
                    t = fminf(fmaxf(t, 1e-5f), 1.0f);
                    v = softplusf(t + bias[c]);
                }
                C[(size_t)r * ldc + c] = v;
            }
        }
    }
}

// ---------------------------------------------------------------------------
// G2 specialized: x_dbl[dir] = xc[dir] @ xproj[dir].T   (M=2048, N=96, K=2048)
// ---------------------------------------------------------------------------
__global__ __launch_bounds__(256) void g2_kernel(
    const float* __restrict__ xc_f, const float* __restrict__ xc_b,
    const float* __restrict__ wf, const float* __restrict__ wb,
    float* __restrict__ part)   // [2][G2KS][2048][96]
{
    const int dir = blockIdx.z;
    const float* A = dir ? xc_b : xc_f;
    const float* W = dir ? wb : wf;
    const int rowBase = blockIdx.x * 32;
    const int kBase = blockIdx.y * (2048 / G2KS);

    __shared__ float As[32][36];
    __shared__ float WsT[32][100];

    const int tid = threadIdx.x;
    const int tx = tid & 31;
    const int ty = tid >> 5;

    float acc[4][3];
#pragma unroll
    for (int i = 0; i < 4; ++i)
#pragma unroll
        for (int j = 0; j < 3; ++j) acc[i][j] = 0.f;

    for (int k0 = 0; k0 < 2048 / G2KS; k0 += 32) {
        {
            int r = tid >> 3, q = tid & 7;
            const float4 v = *(const float4*)&A[(size_t)(rowBase + r) * 2048 + kBase + k0 + q * 4];
            *(float4*)&As[r][q * 4] = v;
        }
#pragma unroll
        for (int t = 0; t < 3; ++t) {
            int idx = tid + 256 * t;
            int wr = idx >> 3, q = idx & 7;
            const float4 v = *(const float4*)&W[(size_t)wr * 2048 + kBase + k0 + q * 4];
            WsT[q * 4 + 0][wr] = v.x;
            WsT[q * 4 + 1][wr] = v.y;
            WsT[q * 4 + 2][wr] = v.z;
            WsT[q * 4 + 3][wr] = v.w;
        }
        __syncthreads();
#pragma unroll
        for (int kk = 0; kk < 32; ++kk) {
            float a[4], w[3];
#pragma unroll
            for (int i = 0; i < 4; ++i) a[i] = As[ty + 8 * i][kk];
#pragma unroll
            for (int j = 0; j < 3; ++j) w[j] = WsT[kk][tx + 32 * j];
#pragma unroll
            for (int i = 0; i < 4; ++i)
#pragma unroll
                for (int j = 0; j < 3; ++j) acc[i][j] += a[i] * w[j];
        }
        __syncthreads();
    }

    float* p = part + ((size_t)(dir * G2KS + blockIdx.y) * 2048) * 96;
#pragma unroll
    for (int i = 0; i < 4; ++i) {
        int r = rowBase + ty + 8 * i;
#pragma unroll
        for (int j = 0; j < 3; ++j)
            p[(size_t)r * 96 + tx + 32 * j] = acc[i][j];
    }
}

__global__ __launch_bounds__(256) void g2_reduce(
    const float* __restrict__ part, float* __restrict__ xf, float* __restrict__ xb)
{
    int idx = blockIdx.x * 256 + threadIdx.x;
    int c = idx % 96;
    int r = (idx / 96) & 2047;
    int dir = idx / (96 * 2048);
    float s = 0.f;
#pragma unroll
    for (int ks = 0; ks < G2KS; ++ks)
        s += part[((size_t)(dir * G2KS + ks) * 2048 + r) * 96 + c];
    (dir ? xb : xf)[(size_t)r * 96 + c] = s;
}

// ---------------------------------------------------------------------------
// Depthwise causal conv1d, both directions.
// ---------------------------------------------------------------------------
__global__ __launch_bounds__(256) void conv_kernel(
    const float* __restrict__ xz,
    const float* __restrict__ wf, const float* __restrict__ bf,
    const float* __restrict__ wb, const float* __restrict__ bb,
    float* __restrict__ xcf, float* __restrict__ xcb)
{
    int idx = blockIdx.x * 256 + threadIdx.x;
    int d = idx & (DINNER - 1);
    int rest = idx >> 11;
    int l = rest & (LL - 1);
    int b = (rest >> 9) & (BB - 1);
    int dir = rest >> 11;

    const float* w = dir ? wb : wf;
    float accv = (dir ? bb : bf)[d];
#pragma unroll
    for (int k = 0; k < DCONV; ++k) {
        int j = l - (DCONV - 1) + k;
        if (j >= 0) {
            int jj = dir ? (LL - 1 - j) : j;
            accv += w[d * DCONV + k] * xz[((size_t)(b * LL + jj)) * (2 * DINNER) + d];
        }
    }
    (dir ? xcb : xcf)[((size_t)(b * LL + l)) * DINNER + d] = accv;
}

// ---------------------------------------------------------------------------
// Selective scan. One thread per (dir, b, d).
// ---------------------------------------------------------------------------
__global__ __launch_bounds__(256) void scan_kernel(
    const float* __restrict__ Alog_f, const float* __restrict__ Alog_b,
    const float* __restrict__ Df, const float* __restrict__ Db,
    const float* __restrict__ xdbl_f, const float* __restrict__ xdbl_b,
    const float* __restrict__ xc_f, const float* __restrict__ xc_b,
    float* __restrict__ dl_f, float* __restrict__ dl_b)
{
    int g = blockIdx.x * 256 + threadIdx.x;
    int d = g & (DINNER - 1);
    int b = (g >> 11) & (BB - 1);
    int dir = g >> 13;

    const float* Alog = dir ? Alog_b : Alog_f;
    const float* xdbl = dir ? xdbl_b : xdbl_f;
    const float* xc   = dir ? xc_b   : xc_f;
    float* dl         = dir ? dl_b   : dl_f;
    float Dv = (dir ? Db : Df)[d];

    float Aa[DSTATE], h[DSTATE];
#pragma unroll
    for (int n = 0; n < DSTATE; ++n) {
        Aa[n] = -__expf(Alog[d * DSTATE + n]);
        h[n] = 0.f;
    }

    for (int t = 0; t < LL; ++t) {
        size_t row = (size_t)(b * LL + t);
        float delta = dl[row * DINNER + d];
        float u = xc[row * DINNER + d];
        u = fminf(fmaxf(u, -10.f), 10.f);
        float du = delta * u;
        const float* bc = xdbl + row * 96 + DTRANK;
        float y = 0.f;
#pragma unroll
        for (int n = 0; n < DSTATE; ++n) {
            h[n] = __expf(delta * Aa[n]) * h[n] + du * bc[n];
            y += h[n] * bc[DSTATE + n];
        }
        dl[row * DINNER + d] = y + u * Dv;
    }
}

// ---------------------------------------------------------------------------
// Gate: ytot[b,l,d] = (y_f + y_b_rev) * silu(z), written as bf16 for G4
// ---------------------------------------------------------------------------
__global__ __launch_bounds__(256) void gate_kernel(
    const float* __restrict__ yf, const float* __restrict__ yb,
    const float* __restrict__ xz, bf16* __restrict__ ytot)
{
    int idx = blockIdx.x * 256 + threadIdx.x;
    int d = idx & (DINNER - 1);
    int l = (idx >> 11) & (LL - 1);
    int b = idx >> 20;
    size_t rowf = (size_t)(b * LL + l);
    size_t rowb = (size_t)(b * LL + (LL - 1 - l));
    float y = yf[rowf * DINNER + d] + yb[rowb * DINNER + d];
    float z = xz[rowf * (2 * DINNER) + DINNER + d];
    float s = z / (1.f + __expf(-z));
    ytot[rowf * DINNER + d] = __float2bfloat16(y * s);
}

// ---------------------------------------------------------------------------
extern "C" void kernel_launch(void* const* d_in, const int* in_sizes, int n_in,
                              void* d_out, int out_size, void* d_ws, size_t ws_size,
                              hipStream_t stream)
{
    const float* hidden    = (const float*)d_in[0];
    const float* in_proj_w = (const float*)d_in[1];
    const float* conv_w    = (const float*)d_in[2];
    const float* conv_b    = (const float*)d_in[3];
    const float* xproj_w   = (const float*)d_in[4];
    const float* dtproj_w  = (const float*)d_in[5];
    const float* dtproj_b  = (const float*)d_in[6];
    const float* A_log     = (const float*)d_in[7];
    const float* Dvec      = (const float*)d_in[8];
    const float* conv_bw   = (const float*)d_in[9];
    const float* conv_bb   = (const float*)d_in[10];
    const float* xproj_bw  = (const float*)d_in[11];
    const float* dtproj_bw = (const float*)d_in[12];
    const float* dtproj_bb = (const float*)d_in[13];
    const float* A_b_log   = (const float*)d_in[14];
    const float* D_b       = (const float*)d_in[15];
    const float* out_pw    = (const float*)d_in[16];
    float* out = (float*)d_out;

    float* ws = (float*)d_ws;
    float* xz     = ws;                      // 8388608 f32
    float* xc_f   = xz + 8388608;            // 4194304
    float* xc_b   = xc_f + 4194304;          // 4194304
    float* xdbl_f = xc_b + 4194304;          // 196608
    float* xdbl_b = xdbl_f + 196608;         // 196608
    float* dl_f   = xdbl_b + 196608;         // 4194304 (delta -> y)
    float* dl_b   = dl_f + 4194304;          // 4194304
    float* g2part = dl_b + 4194304;          // 786432

    // bf16 aliases over regions that are dead at the time of use:
    // hbf (1M f32-equiv) + wbf (2M) live only until G1; dl written first by G3.
    bf16* hbf = (bf16*)dl_f;                 // 2M bf16
    bf16* wbf = (bf16*)(dl_f + 1048576);     // 4M bf16
    // ytot_bf16 + obf live after scan; xc dead after scan.
    bf16* ytot_bf = (bf16*)xc_f;             // 4M bf16 (2M f32-equiv)
    bf16* obf = (bf16*)xc_b;                 // 2M bf16

    dim3 blk(256);

    // casts for G1
    cast_kernel<<<dim3(2097152 / 8 / 256), blk, 0, stream>>>(hidden, hbf, 2097152);
    cast_kernel<<<dim3(4194304 / 8 / 256), blk, 0, stream>>>(in_proj_w, wbf, 4194304);

    // G1: xz = hidden @ in_proj_w.T   (M=2048, N=4096, K=1024) bf16 MFMA
    gemm_bf16<0><<<dim3(4096 / 128, MROWS / 128), blk, 0, stream>>>(
        hbf, wbf, xz, 4096, 1024, 1024, 1024, 4096);

    // conv both dirs
    conv_kernel<<<dim3(2 * BB * LL * DINNER / 256), blk, 0, stream>>>(
        xz, conv_w, conv_b, conv_bw, conv_bb, xc_f, xc_b);

    // G2: x_dbl = xc @ x_proj_w.T  (both dirs, split-K)
    g2_kernel<<<dim3(64, G2KS, 2), blk, 0, stream>>>(
        xc_f, xc_b, xproj_w, xproj_bw, g2part);
    g2_reduce<<<dim3(2 * 2048 * 96 / 256), blk, 0, stream>>>(
        g2part, xdbl_f, xdbl_b);

    // G3: delta = softplus(clip(xdbl[:, :64] @ dtw.T + b, 1e-5, 1) + b)
    gemm_tn<1><<<dim3(DINNER / 128, MROWS / 128), blk, 0, stream>>>(
        xdbl_f, dtproj_w, dl_f, dtproj_b, 2048, 64, 96, 64, 2048);
    gemm_tn<1><<<dim3(DINNER / 128, MROWS / 128), blk, 0, stream>>>(
        xdbl_b, dtproj_bw, dl_b, dtproj_bb, 2048, 64, 96, 64, 2048);

    // scan (both dirs)
    scan_kernel<<<dim3(2 * BB * DINNER / 256), blk, 0, stream>>>(
        A_log, A_b_log, Dvec, D_b, xdbl_f, xdbl_b, xc_f, xc_b, dl_f, dl_b);

    // gate -> bf16 ytot (into dead xc_f region)
    gate_kernel<<<dim3(BB * LL * DINNER / 256), blk, 0, stream>>>(
        dl_f, dl_b, xz, ytot_bf);

    // cast out_proj_w (xc_b region dead after scan)
    cast_kernel<<<dim3(2097152 / 8 / 256), blk, 0, stream>>>(out_pw, obf, 2097152);

    // G4: out = ytot @ out_proj_w.T  (M=2048, N=1024, K=2048) bf16 MFMA + nan_to_num
    gemm_bf16<2><<<dim3(DMODEL / 128, MROWS / 128), blk, 0, stream>>>(
        ytot_bf, obf, out, 1024, 2048, 2048, 2048, 1024);
}

// Round 4
// 381.653 us; speedup vs baseline: 5.8238x; 1.5889x over previous
//
#include <hip/hip_runtime.h>
#include <hip/hip_bf16.h>
#include <math.h>

// Problem constants
#define BB 4
#define LL 512
#define DMODEL 1024
#define DSTATE 16
#define DCONV 4
#define DINNER 2048
#define DTRANK 64
#define MROWS (BB*LL)          // 2048 rows of (b,l)
#define G2KS 2                 // split-K factor for the N=96 GEMM
#define SCHUNK 64              // scan chunk length
#define SNC (LL / SCHUNK)      // 8 chunks

typedef __hip_bfloat16 bf16;
typedef __attribute__((ext_vector_type(8))) short short8;
typedef __attribute__((ext_vector_type(4))) float f32x4;

__device__ __forceinline__ float softplusf(float x) {
    return x > 20.f ? x : log1pf(__expf(x));
}

// ---------------------------------------------------------------------------
// bf16 MFMA TN GEMM: C[M][N](f32) = A[M][K](bf16) * W[N][K](bf16)^T
// ---------------------------------------------------------------------------
template<int EPI>
__global__ __launch_bounds__(256) void gemm_bf16(
    const bf16* __restrict__ A, const bf16* __restrict__ W,
    float* __restrict__ C, int N, int K, int lda, int ldw, int ldc)
{
    __shared__ bf16 lA[128 * 40];
    __shared__ bf16 lW[128 * 40];

    const int tid = threadIdx.x;
    const int lane = tid & 63;
    const int wid = tid >> 6;
    const int wr = wid >> 1;
    const int wc = wid & 1;
    const int rowBase = blockIdx.y * 128;
    const int colBase = blockIdx.x * 128;

    const int r16 = lane & 15;
    const int kg = lane >> 4;

    f32x4 acc[4][4];
#pragma unroll
    for (int m = 0; m < 4; ++m)
#pragma unroll
        for (int n = 0; n < 4; ++n) acc[m][n] = (f32x4)0.f;

    const int srow = tid >> 2;
    const int scol = (tid & 3) * 8;

    for (int k0 = 0; k0 < K; k0 += 32) {
#pragma unroll
        for (int it = 0; it < 2; ++it) {
            int r = srow + it * 64;
            short8 va = *(const short8*)&A[(size_t)(rowBase + r) * lda + k0 + scol];
            short8 vw = *(const short8*)&W[(size_t)(colBase + r) * ldw + k0 + scol];
            *(short8*)&lA[r * 40 + scol] = va;
            *(short8*)&lW[r * 40 + scol] = vw;
        }
        __syncthreads();

        short8 a[4], b[4];
#pragma unroll
        for (int m = 0; m < 4; ++m)
            a[m] = *(const short8*)&lA[(wr * 64 + m * 16 + r16) * 40 + kg * 8];
#pragma unroll
        for (int n = 0; n < 4; ++n)
            b[n] = *(const short8*)&lW[(wc * 64 + n * 16 + r16) * 40 + kg * 8];
#pragma unroll
        for (int m = 0; m < 4; ++m)
#pragma unroll
            for (int n = 0; n < 4; ++n)
                acc[m][n] = __builtin_amdgcn_mfma_f32_16x16x32_bf16(
                    a[m], b[n], acc[m][n], 0, 0, 0);
        __syncthreads();
    }

#pragma unroll
    for (int m = 0; m < 4; ++m) {
#pragma unroll
        for (int n = 0; n < 4; ++n) {
            int gc = colBase + wc * 64 + n * 16 + r16;
#pragma unroll
            for (int j = 0; j < 4; ++j) {
                int gr = rowBase + wr * 64 + m * 16 + kg * 4 + j;
                float v = acc[m][n][j];
                if (EPI == 2) {
                    if (isnan(v)) v = 0.f;
                    else if (isinf(v)) v = (v > 0.f) ? 1.f : -1.f;
                }
                C[(size_t)gr * ldc + gc] = v;
            }
        }
    }
}

// ---------------------------------------------------------------------------
// f32 -> bf16 cast
// ---------------------------------------------------------------------------
__global__ __launch_bounds__(256) void cast_kernel(
    const float* __restrict__ in, bf16* __restrict__ out, int n)
{
    int i = (blockIdx.x * 256 + threadIdx.x) * 8;
    if (i >= n) return;
    float4 x = *(const float4*)&in[i];
    float4 y = *(const float4*)&in[i + 4];
    bf16 t[8] = { __float2bfloat16(x.x), __float2bfloat16(x.y),
                  __float2bfloat16(x.z), __float2bfloat16(x.w),
                  __float2bfloat16(y.x), __float2bfloat16(y.y),
                  __float2bfloat16(y.z), __float2bfloat16(y.w) };
    *(short8*)&out[i] = *(short8*)t;
}

// ---------------------------------------------------------------------------
// G3 dual-direction fp32 GEMM + dt epilogue.
// dt = softplus(clip(xdbl[:, :64] @ dtw.T + bias, 1e-5, 1) + bias)
// M=2048, N=2048, K=64, lda=96, ldw=64, ldc=2048. blockIdx.z = dir.
// ---------------------------------------------------------------------------
__global__ __launch_bounds__(256) void g3_kernel(
    const float* __restrict__ xf, const float* __restrict__ xb,
    const float* __restrict__ wf, const float* __restrict__ wb,
    const float* __restrict__ biasf, const float* __restrict__ biasb,
    float* __restrict__ of, float* __restrict__ ob)
{
    const int dir = blockIdx.z;
    const float* A = dir ? xb : xf;
    const float* W = dir ? wb : wf;
    const float* bias = dir ? biasb : biasf;
    float* C = dir ? ob : of;

    __shared__ float As[128][17];
    __shared__ float Ws[128][17];
    const int tid = threadIdx.x;
    const int tx = tid & 15;
    const int ty = tid >> 4;
    const int rowBase = blockIdx.y * 128;
    const int colBase = blockIdx.x * 128;

    float acc[8][8];
#pragma unroll
    for (int i = 0; i < 8; ++i)
#pragma unroll
        for (int j = 0; j < 8; ++j) acc[i][j] = 0.f;

    for (int k0 = 0; k0 < 64; k0 += 16) {
#pragma unroll
        for (int i = 0; i < 8; ++i) {
            int e = tid + i * 256;
            int r = e >> 4, kk = e & 15;
            As[r][kk] = A[(size_t)(rowBase + r) * 96 + (k0 + kk)];
            Ws[r][kk] = W[(size_t)(colBase + r) * 64 + (k0 + kk)];
        }
        __syncthreads();
#pragma unroll
        for (int kk = 0; kk < 16; ++kk) {
            float a[8], w[8];
#pragma unroll
            for (int i = 0; i < 8; ++i) a[i] = As[ty + 16 * i][kk];
#pragma unroll
            for (int j = 0; j < 8; ++j) w[j] = Ws[tx + 16 * j][kk];
#pragma unroll
            for (int i = 0; i < 8; ++i)
#pragma unroll
                for (int j = 0; j < 8; ++j) acc[i][j] += a[i] * w[j];
        }
        __syncthreads();
    }

#pragma unroll
    for (int i = 0; i < 8; ++i) {
        int r = rowBase + ty + 16 * i;
#pragma unroll
        for (int j = 0; j < 8; ++j) {
            int c = colBase + tx + 16 * j;
            float t = acc[i][j] + bias[c];
            t = fminf(fmaxf(t, 1e-5f), 1.0f);
            C[(size_t)r * 2048 + c] = softplusf(t + bias[c]);
        }
    }
}

// ---------------------------------------------------------------------------
// G2 specialized: x_dbl[dir] = xc[dir] @ xproj[dir].T   (M=2048, N=96, K=2048)
// ---------------------------------------------------------------------------
__global__ __launch_bounds__(256) void g2_kernel(
    const float* __restrict__ xc_f, const float* __restrict__ xc_b,
    const float* __restrict__ wf, const float* __restrict__ wb,
    float* __restrict__ part)
{
    const int dir = blockIdx.z;
    const float* A = dir ? xc_b : xc_f;
    const float* W = dir ? wb : wf;
    const int rowBase = blockIdx.x * 32;
    const int kBase = blockIdx.y * (2048 / G2KS);

    __shared__ float As[32][36];
    __shared__ float WsT[32][100];

    const int tid = threadIdx.x;
    const int tx = tid & 31;
    const int ty = tid >> 5;

    float acc[4][3];
#pragma unroll
    for (int i = 0; i < 4; ++i)
#pragma unroll
        for (int j = 0; j < 3; ++j) acc[i][j] = 0.f;

    for (int k0 = 0; k0 < 2048 / G2KS; k0 += 32) {
        {
            int r = tid >> 3, q = tid & 7;
            const float4 v = *(const float4*)&A[(size_t)(rowBase + r) * 2048 + kBase + k0 + q * 4];
            *(float4*)&As[r][q * 4] = v;
        }
#pragma unroll
        for (int t = 0; t < 3; ++t) {
            int idx = tid + 256 * t;
            int wr = idx >> 3, q = idx & 7;
            const float4 v = *(const float4*)&W[(size_t)wr * 2048 + kBase + k0 + q * 4];
            WsT[q * 4 + 0][wr] = v.x;
            WsT[q * 4 + 1][wr] = v.y;
            WsT[q * 4 + 2][wr] = v.z;
            WsT[q * 4 + 3][wr] = v.w;
        }
        __syncthreads();
#pragma unroll
        for (int kk = 0; kk < 32; ++kk) {
            float a[4], w[3];
#pragma unroll
            for (int i = 0; i < 4; ++i) a[i] = As[ty + 8 * i][kk];
#pragma unroll
            for (int j = 0; j < 3; ++j) w[j] = WsT[kk][tx + 32 * j];
#pragma unroll
            for (int i = 0; i < 4; ++i)
#pragma unroll
                for (int j = 0; j < 3; ++j) acc[i][j] += a[i] * w[j];
        }
        __syncthreads();
    }

    float* p = part + ((size_t)(dir * G2KS + blockIdx.y) * 2048) * 96;
#pragma unroll
    for (int i = 0; i < 4; ++i) {
        int r = rowBase + ty + 8 * i;
#pragma unroll
        for (int j = 0; j < 3; ++j)
            p[(size_t)r * 96 + tx + 32 * j] = acc[i][j];
    }
}

__global__ __launch_bounds__(256) void g2_reduce(
    const float* __restrict__ part, float* __restrict__ xf, float* __restrict__ xb)
{
    int idx = blockIdx.x * 256 + threadIdx.x;
    int c = idx % 96;
    int r = (idx / 96) & 2047;
    int dir = idx / (96 * 2048);
    float s = 0.f;
#pragma unroll
    for (int ks = 0; ks < G2KS; ++ks)
        s += part[((size_t)(dir * G2KS + ks) * 2048 + r) * 96 + c];
    (dir ? xb : xf)[(size_t)r * 96 + c] = s;
}

// ---------------------------------------------------------------------------
// Depthwise causal conv1d, both directions.
// ---------------------------------------------------------------------------
__global__ __launch_bounds__(256) void conv_kernel(
    const float* __restrict__ xz,
    const float* __restrict__ wf, const float* __restrict__ bf,
    const float* __restrict__ wb, const float* __restrict__ bb,
    float* __restrict__ xcf, float* __restrict__ xcb)
{
    int idx = blockIdx.x * 256 + threadIdx.x;
    int d = idx & (DINNER - 1);
    int rest = idx >> 11;
    int l = rest & (LL - 1);
    int b = (rest >> 9) & (BB - 1);
    int dir = rest >> 11;

    const float* w = dir ? wb : wf;
    float accv = (dir ? bb : bf)[d];
#pragma unroll
    for (int k = 0; k < DCONV; ++k) {
        int j = l - (DCONV - 1) + k;
        if (j >= 0) {
            int jj = dir ? (LL - 1 - j) : j;
            accv += w[d * DCONV + k] * xz[((size_t)(b * LL + jj)) * (2 * DINNER) + d];
        }
    }
    (dir ? xcb : xcf)[((size_t)(b * LL + l)) * DINNER + d] = accv;
}

// ---------------------------------------------------------------------------
// Chunked scan phase 1: per (dir,b,chunk,d) compute local h_end (h0=0) and
// sum of deltas. grid (8 dgroups, SNC, 8 dir*b).
// ---------------------------------------------------------------------------
__global__ __launch_bounds__(256) void scan1_kernel(
    const float* __restrict__ Alog_f, const float* __restrict__ Alog_b,
    const float* __restrict__ xdbl_f, const float* __restrict__ xdbl_b,
    const float* __restrict__ xc_f, const float* __restrict__ xc_b,
    const float* __restrict__ dl_f, const float* __restrict__ dl_b,
    float* __restrict__ sdel, float* __restrict__ hend)
{
    const int tid = threadIdx.x;
    const int d = blockIdx.x * 256 + tid;
    const int c = blockIdx.y;
    const int z = blockIdx.z;           // dir*4 + b
    const int dir = z >> 2, b = z & 3;

    const float* Alog = dir ? Alog_b : Alog_f;
    const float* xdbl = dir ? xdbl_b : xdbl_f;
    const float* xc   = dir ? xc_b   : xc_f;
    const float* dl   = dir ? dl_b   : dl_f;
    const int rowBase = b * LL + c * SCHUNK;

    __shared__ float bs[SCHUNK][16];
#pragma unroll
    for (int i = 0; i < SCHUNK * 16 / 256; ++i) {
        int e = tid + 256 * i;
        int r = e >> 4, n = e & 15;
        bs[r][n] = xdbl[(size_t)(rowBase + r) * 96 + DTRANK + n];
    }
    __syncthreads();

    float Aa[DSTATE], h[DSTATE];
#pragma unroll
    for (int n = 0; n < DSTATE; ++n) {
        Aa[n] = -__expf(Alog[d * DSTATE + n]);
        h[n] = 0.f;
    }
    float sd = 0.f;

    for (int t = 0; t < SCHUNK; ++t) {
        size_t row = (size_t)(rowBase + t);
        float delta = dl[row * DINNER + d];
        float u = xc[row * DINNER + d];
        u = fminf(fmaxf(u, -10.f), 10.f);
        float du = delta * u;
        sd += delta;
#pragma unroll
        for (int n = 0; n < DSTATE; ++n)
            h[n] = __expf(delta * Aa[n]) * h[n] + du * bs[t][n];
    }

    size_t base = (size_t)z * SNC + c;
    sdel[base * DINNER + d] = sd;
#pragma unroll
    for (int n = 0; n < DSTATE; ++n)
        hend[(base * DSTATE + n) * DINNER + d] = h[n];
}

// ---------------------------------------------------------------------------
// Combine: sequential over chunks (per dir,b,d). Writes per-chunk h_in.
// h_in[c+1] = exp(Aa * sdel[c]) * h_in[c] + hend[c]
// ---------------------------------------------------------------------------
__global__ __launch_bounds__(256) void scan_combine(
    const float* __restrict__ Alog_f, const float* __restrict__ Alog_b,
    const float* __restrict__ sdel, const float* __restrict__ hend,
    float* __restrict__ hin)
{
    int g = blockIdx.x * 256 + threadIdx.x;     // 2*4*2048
    int d = g & (DINNER - 1);
    int z = g >> 11;
    int dir = z >> 2;
    const float* Alog = dir ? Alog_b : Alog_f;

    float Aa[DSTATE], hr[DSTATE];
#pragma unroll
    for (int n = 0; n < DSTATE; ++n) {
        Aa[n] = -__expf(Alog[d * DSTATE + n]);
        hr[n] = 0.f;
    }
    for (int c = 0; c < SNC; ++c) {
        size_t base = (size_t)z * SNC + c;
#pragma unroll
        for (int n = 0; n < DSTATE; ++n)
            hin[(base * DSTATE + n) * DINNER + d] = hr[n];
        float sd = sdel[base * DINNER + d];
#pragma unroll
        for (int n = 0; n < DSTATE; ++n)
            hr[n] = __expf(sd * Aa[n]) * hr[n] + hend[(base * DSTATE + n) * DINNER + d];
    }
}

// ---------------------------------------------------------------------------
// Chunked scan phase 2: start from h_in, recompute chunk, emit y (in-place
// over delta buffer). Same grid as phase 1.
// ---------------------------------------------------------------------------
__global__ __launch_bounds__(256) void scan2_kernel(
    const float* __restrict__ Alog_f, const float* __restrict__ Alog_b,
    const float* __restrict__ Df, const float* __restrict__ Db,
    const float* __restrict__ xdbl_f, const float* __restrict__ xdbl_b,
    const float* __restrict__ xc_f, const float* __restrict__ xc_b,
    const float* __restrict__ hin,
    float* __restrict__ dl_f, float* __restrict__ dl_b)
{
    const int tid = threadIdx.x;
    const int d = blockIdx.x * 256 + tid;
    const int c = blockIdx.y;
    const int z = blockIdx.z;
    const int dir = z >> 2, b = z & 3;

    const float* Alog = dir ? Alog_b : Alog_f;
    const float* xdbl = dir ? xdbl_b : xdbl_f;
    const float* xc   = dir ? xc_b   : xc_f;
    float* dl         = dir ? dl_b   : dl_f;
    const int rowBase = b * LL + c * SCHUNK;

    __shared__ float bs[SCHUNK][32];
#pragma unroll
    for (int i = 0; i < SCHUNK * 32 / 256; ++i) {
        int e = tid + 256 * i;
        int r = e >> 5, n = e & 31;
        bs[r][n] = xdbl[(size_t)(rowBase + r) * 96 + DTRANK + n];
    }
    __syncthreads();

    float Dv = (dir ? Db : Df)[d];
    size_t base = (size_t)z * SNC + c;
    float Aa[DSTATE], h[DSTATE];
#pragma unroll
    for (int n = 0; n < DSTATE; ++n) {
        Aa[n] = -__expf(Alog[d * DSTATE + n]);
        h[n] = hin[(base * DSTATE + n) * DINNER + d];
    }

    for (int t = 0; t < SCHUNK; ++t) {
        size_t row = (size_t)(rowBase + t);
        float delta = dl[row * DINNER + d];
        float u = xc[row * DINNER + d];
        u = fminf(fmaxf(u, -10.f), 10.f);
        float du = delta * u;
        float y = 0.f;
#pragma unroll
        for (int n = 0; n < DSTATE; ++n) {
            h[n] = __expf(delta * Aa[n]) * h[n] + du * bs[t][n];
            y += h[n] * bs[t][DSTATE + n];
        }
        dl[row * DINNER + d] = y + u * Dv;
    }
}

// ---------------------------------------------------------------------------
// Gate: ytot = (y_f + y_b_rev) * silu(z), written as bf16 for G4
// ---------------------------------------------------------------------------
__global__ __launch_bounds__(256) void gate_kernel(
    const float* __restrict__ yf, const float* __restrict__ yb,
    const float* __restrict__ xz, bf16* __restrict__ ytot)
{
    int idx = blockIdx.x * 256 + threadIdx.x;
    int d = idx & (DINNER - 1);
    int l = (idx >> 11) & (LL - 1);
    int b = idx >> 20;
    size_t rowf = (size_t)(b * LL + l);
    size_t rowb = (size_t)(b * LL + (LL - 1 - l));
    float y = yf[rowf * DINNER + d] + yb[rowb * DINNER + d];
    float z = xz[rowf * (2 * DINNER) + DINNER + d];
    float s = z / (1.f + __expf(-z));
    ytot[rowf * DINNER + d] = __float2bfloat16(y * s);
}

// ---------------------------------------------------------------------------
extern "C" void kernel_launch(void* const* d_in, const int* in_sizes, int n_in,
                              void* d_out, int out_size, void* d_ws, size_t ws_size,
                              hipStream_t stream)
{
    const float* hidden    = (const float*)d_in[0];
    const float* in_proj_w = (const float*)d_in[1];
    const float* conv_w    = (const float*)d_in[2];
    const float* conv_b    = (const float*)d_in[3];
    const float* xproj_w   = (const float*)d_in[4];
    const float* dtproj_w  = (const float*)d_in[5];
    const float* dtproj_b  = (const float*)d_in[6];
    const float* A_log     = (const float*)d_in[7];
    const float* Dvec      = (const float*)d_in[8];
    const float* conv_bw   = (const float*)d_in[9];
    const float* conv_bb   = (const float*)d_in[10];
    const float* xproj_bw  = (const float*)d_in[11];
    const float* dtproj_bw = (const float*)d_in[12];
    const float* dtproj_bb = (const float*)d_in[13];
    const float* A_b_log   = (const float*)d_in[14];
    const float* D_b       = (const float*)d_in[15];
    const float* out_pw    = (const float*)d_in[16];
    float* out = (float*)d_out;

    float* ws = (float*)d_ws;
    float* xz     = ws;                      // 8388608 f32
    float* xc_f   = xz + 8388608;            // 4194304
    float* xc_b   = xc_f + 4194304;          // 4194304
    float* xdbl_f = xc_b + 4194304;          // 196608
    float* xdbl_b = xdbl_f + 196608;         // 196608
    float* dl_f   = xdbl_b + 196608;         // 4194304 (delta -> y)
    float* dl_b   = dl_f + 4194304;          // 4194304
    float* g2part = dl_b + 4194304;          // 786432
    float* sdel   = g2part + 786432;         // 2*4*8*2048 = 131072
    float* hend   = sdel + 131072;           // 2*4*8*16*2048 = 2097152
    float* hin    = hend + 2097152;          // 2097152

    // bf16 aliases over dead regions
    bf16* hbf = (bf16*)dl_f;                 // live only until G1
    bf16* wbf = (bf16*)(dl_f + 1048576);
    bf16* ytot_bf = (bf16*)xc_f;             // live after scan (xc dead)
    bf16* obf = (bf16*)xc_b;

    dim3 blk(256);

    // casts for G1
    cast_kernel<<<dim3(2097152 / 8 / 256), blk, 0, stream>>>(hidden, hbf, 2097152);
    cast_kernel<<<dim3(4194304 / 8 / 256), blk, 0, stream>>>(in_proj_w, wbf, 4194304);

    // G1: xz = hidden @ in_proj_w.T   (M=2048, N=4096, K=1024) bf16 MFMA
    gemm_bf16<0><<<dim3(4096 / 128, MROWS / 128), blk, 0, stream>>>(
        hbf, wbf, xz, 4096, 1024, 1024, 1024, 4096);

    // conv both dirs
    conv_kernel<<<dim3(2 * BB * LL * DINNER / 256), blk, 0, stream>>>(
        xz, conv_w, conv_b, conv_bw, conv_bb, xc_f, xc_b);

    // G2: x_dbl = xc @ x_proj_w.T  (both dirs, split-K)
    g2_kernel<<<dim3(64, G2KS, 2), blk, 0, stream>>>(
        xc_f, xc_b, xproj_w, xproj_bw, g2part);
    g2_reduce<<<dim3(2 * 2048 * 96 / 256), blk, 0, stream>>>(
        g2part, xdbl_f, xdbl_b);

    // G3 (both dirs in one launch)
    g3_kernel<<<dim3(16, 16, 2), blk, 0, stream>>>(
        xdbl_f, xdbl_b, dtproj_w, dtproj_bw, dtproj_b, dtproj_bb, dl_f, dl_b);

    // chunked scan
    scan1_kernel<<<dim3(DINNER / 256, SNC, 8), blk, 0, stream>>>(
        A_log, A_b_log, xdbl_f, xdbl_b, xc_f, xc_b, dl_f, dl_b, sdel, hend);
    scan_combine<<<dim3(2 * BB * DINNER / 256), blk, 0, stream>>>(
        A_log, A_b_log, sdel, hend, hin);
    scan2_kernel<<<dim3(DINNER / 256, SNC, 8), blk, 0, stream>>>(
        A_log, A_b_log, Dvec, D_b, xdbl_f, xdbl_b, xc_f, xc_b, hin, dl_f, dl_b);

    // gate -> bf16 ytot (into dead xc_f region)
    gate_kernel<<<dim3(BB * LL * DINNER / 256), blk, 0, stream>>>(
        dl_f, dl_b, xz, ytot_bf);

    // cast out_proj_w (xc_b dead after scan)
    cast_kernel<<<dim3(2097152 / 8 / 256), blk, 0, stream>>>(out_pw, obf, 2097152);

    // G4: out = ytot @ out_proj_w.T  bf16 MFMA + nan_to_num
    gemm_bf16<2><<<dim3(DMODEL / 128, MROWS / 128), blk, 0, stream>>>(
        ytot_bf, obf, out, 1024, 2048, 2048, 2048, 1024);
}

// Round 5
// 334.148 us; speedup vs baseline: 6.6518x; 1.1422x over previous
//
#include <hip/hip_runtime.h>
#include <hip/hip_bf16.h>
#include <math.h>

// Problem constants
#define BB 4
#define LL 512
#define DMODEL 1024
#define DSTATE 16
#define DCONV 4
#define DINNER 2048
#define DTRANK 64
#define MROWS (BB*LL)          // 2048 rows of (b,l)
#define G2KS 4                 // split-K factor for the N=96 GEMM
#define SCHUNK 64              // scan chunk length
#define SNC (LL / SCHUNK)      // 8 chunks

typedef __hip_bfloat16 bf16;
typedef __attribute__((ext_vector_type(8))) short short8;
typedef __attribute__((ext_vector_type(4))) float f32x4;

__device__ __forceinline__ float softplusf(float x) {
    return x > 20.f ? x : log1pf(__expf(x));
}

// ---------------------------------------------------------------------------
// bf16 MFMA TN GEMM: C[M][N](f32) = A[M][K](bf16) * W[N][K](bf16)^T
// ---------------------------------------------------------------------------
template<int EPI>
__global__ __launch_bounds__(256) void gemm_bf16(
    const bf16* __restrict__ A, const bf16* __restrict__ W,
    float* __restrict__ C, int N, int K, int lda, int ldw, int ldc)
{
    __shared__ bf16 lA[128 * 40];
    __shared__ bf16 lW[128 * 40];

    const int tid = threadIdx.x;
    const int lane = tid & 63;
    const int wid = tid >> 6;
    const int wr = wid >> 1;
    const int wc = wid & 1;
    const int rowBase = blockIdx.y * 128;
    const int colBase = blockIdx.x * 128;

    const int r16 = lane & 15;
    const int kg = lane >> 4;

    f32x4 acc[4][4];
#pragma unroll
    for (int m = 0; m < 4; ++m)
#pragma unroll
        for (int n = 0; n < 4; ++n) acc[m][n] = (f32x4)0.f;

    const int srow = tid >> 2;
    const int scol = (tid & 3) * 8;

    for (int k0 = 0; k0 < K; k0 += 32) {
#pragma unroll
        for (int it = 0; it < 2; ++it) {
            int r = srow + it * 64;
            short8 va = *(const short8*)&A[(size_t)(rowBase + r) * lda + k0 + scol];
            short8 vw = *(const short8*)&W[(size_t)(colBase + r) * ldw + k0 + scol];
            *(short8*)&lA[r * 40 + scol] = va;
            *(short8*)&lW[r * 40 + scol] = vw;
        }
        __syncthreads();

        short8 a[4], b[4];
#pragma unroll
        for (int m = 0; m < 4; ++m)
            a[m] = *(const short8*)&lA[(wr * 64 + m * 16 + r16) * 40 + kg * 8];
#pragma unroll
        for (int n = 0; n < 4; ++n)
            b[n] = *(const short8*)&lW[(wc * 64 + n * 16 + r16) * 40 + kg * 8];
#pragma unroll
        for (int m = 0; m < 4; ++m)
#pragma unroll
            for (int n = 0; n < 4; ++n)
                acc[m][n] = __builtin_amdgcn_mfma_f32_16x16x32_bf16(
                    a[m], b[n], acc[m][n], 0, 0, 0);
        __syncthreads();
    }

#pragma unroll
    for (int m = 0; m < 4; ++m) {
#pragma unroll
        for (int n = 0; n < 4; ++n) {
            int gc = colBase + wc * 64 + n * 16 + r16;
#pragma unroll
            for (int j = 0; j < 4; ++j) {
                int gr = rowBase + wr * 64 + m * 16 + kg * 4 + j;
                float v = acc[m][n][j];
                if (EPI == 2) {
                    if (isnan(v)) v = 0.f;
                    else if (isinf(v)) v = (v > 0.f) ? 1.f : -1.f;
                }
                C[(size_t)gr * ldc + gc] = v;
            }
        }
    }
}

// ---------------------------------------------------------------------------
// G2 as bf16 MFMA: part[dir][kz] = xcbf[dir][:, kz*512:+512] @ wx[dir].T
// M=2048 (16 tiles of 128), N=96 (6 frags), split-K=4. grid (16,4,2)=128.
// ---------------------------------------------------------------------------
__global__ __launch_bounds__(256) void g2_mfma(
    const bf16* __restrict__ xcbf_f, const bf16* __restrict__ xcbf_b,
    const bf16* __restrict__ wxf, const bf16* __restrict__ wxb,
    float* __restrict__ part)   // [2][G2KS][2048][96]
{
    const int dir = blockIdx.z;
    const bf16* A = dir ? xcbf_b : xcbf_f;   // [2048][2048]
    const bf16* W = dir ? wxb : wxf;         // [96][2048]
    const int rowBase = blockIdx.x * 128;
    const int kz = blockIdx.y;
    const int kBase = kz * (2048 / G2KS);

    __shared__ bf16 lA[128 * 40];
    __shared__ bf16 lW[96 * 40];

    const int tid = threadIdx.x;
    const int lane = tid & 63;
    const int wid = tid >> 6;        // wave handles rows wid*32..+31
    const int r16 = lane & 15;
    const int kg = lane >> 4;

    f32x4 acc[2][6];
#pragma unroll
    for (int m = 0; m < 2; ++m)
#pragma unroll
        for (int n = 0; n < 6; ++n) acc[m][n] = (f32x4)0.f;

    const int srow = tid >> 2;            // 0..63
    const int scol = (tid & 3) * 8;

    for (int k0 = 0; k0 < 2048 / G2KS; k0 += 32) {
#pragma unroll
        for (int it = 0; it < 2; ++it) {
            int r = srow + it * 64;
            short8 va = *(const short8*)&A[(size_t)(rowBase + r) * 2048 + kBase + k0 + scol];
            *(short8*)&lA[r * 40 + scol] = va;
        }
        {
            short8 vw = *(const short8*)&W[(size_t)srow * 2048 + kBase + k0 + scol];
            *(short8*)&lW[srow * 40 + scol] = vw;
        }
        if (tid < 128) {
            int r = 64 + (tid >> 2);
            short8 vw2 = *(const short8*)&W[(size_t)r * 2048 + kBase + k0 + scol];
            *(short8*)&lW[r * 40 + scol] = vw2;
        }
        __syncthreads();

        short8 a[2], b[6];
#pragma unroll
        for (int m = 0; m < 2; ++m)
            a[m] = *(const short8*)&lA[(wid * 32 + m * 16 + r16) * 40 + kg * 8];
#pragma unroll
        for (int n = 0; n < 6; ++n)
            b[n] = *(const short8*)&lW[(n * 16 + r16) * 40 + kg * 8];
#pragma unroll
        for (int m = 0; m < 2; ++m)
#pragma unroll
            for (int n = 0; n < 6; ++n)
                acc[m][n] = __builtin_amdgcn_mfma_f32_16x16x32_bf16(
                    a[m], b[n], acc[m][n], 0, 0, 0);
        __syncthreads();
    }

    float* p = part + ((size_t)(dir * G2KS + kz) * 2048) * 96;
#pragma unroll
    for (int m = 0; m < 2; ++m) {
#pragma unroll
        for (int n = 0; n < 6; ++n) {
            int gc = n * 16 + r16;
#pragma unroll
            for (int j = 0; j < 4; ++j) {
                int gr = rowBase + wid * 32 + m * 16 + kg * 4 + j;
                p[(size_t)gr * 96 + gc] = acc[m][n][j];
            }
        }
    }
}

__global__ __launch_bounds__(256) void g2_reduce(
    const float* __restrict__ part, float* __restrict__ xf, float* __restrict__ xb)
{
    int idx = blockIdx.x * 256 + threadIdx.x;
    int c = idx % 96;
    int r = (idx / 96) & 2047;
    int dir = idx / (96 * 2048);
    float s = 0.f;
#pragma unroll
    for (int ks = 0; ks < G2KS; ++ks)
        s += part[((size_t)(dir * G2KS + ks) * 2048 + r) * 96 + c];
    (dir ? xb : xf)[(size_t)r * 96 + c] = s;
}

// ---------------------------------------------------------------------------
// f32 -> bf16 cast
// ---------------------------------------------------------------------------
__global__ __launch_bounds__(256) void cast_kernel(
    const float* __restrict__ in, bf16* __restrict__ out, int n)
{
    int i = (blockIdx.x * 256 + threadIdx.x) * 8;
    if (i >= n) return;
    float4 x = *(const float4*)&in[i];
    float4 y = *(const float4*)&in[i + 4];
    bf16 t[8] = { __float2bfloat16(x.x), __float2bfloat16(x.y),
                  __float2bfloat16(x.z), __float2bfloat16(x.w),
                  __float2bfloat16(y.x), __float2bfloat16(y.y),
                  __float2bfloat16(y.z), __float2bfloat16(y.w) };
    *(short8*)&out[i] = *(short8*)t;
}

// ---------------------------------------------------------------------------
// G3 dual-direction fp32 GEMM + dt epilogue.
// ---------------------------------------------------------------------------
__global__ __launch_bounds__(256) void g3_kernel(
    const float* __restrict__ xf, const float* __restrict__ xb,
    const float* __restrict__ wf, const float* __restrict__ wb,
    const float* __restrict__ biasf, const float* __restrict__ biasb,
    float* __restrict__ of, float* __restrict__ ob)
{
    const int dir = blockIdx.z;
    const float* A = dir ? xb : xf;
    const float* W = dir ? wb : wf;
    const float* bias = dir ? biasb : biasf;
    float* C = dir ? ob : of;

    __shared__ float As[128][17];
    __shared__ float Ws[128][17];
    const int tid = threadIdx.x;
    const int tx = tid & 15;
    const int ty = tid >> 4;
    const int rowBase = blockIdx.y * 128;
    const int colBase = blockIdx.x * 128;

    float acc[8][8];
#pragma unroll
    for (int i = 0; i < 8; ++i)
#pragma unroll
        for (int j = 0; j < 8; ++j) acc[i][j] = 0.f;

    for (int k0 = 0; k0 < 64; k0 += 16) {
#pragma unroll
        for (int i = 0; i < 8; ++i) {
            int e = tid + i * 256;
            int r = e >> 4, kk = e & 15;
            As[r][kk] = A[(size_t)(rowBase + r) * 96 + (k0 + kk)];
            Ws[r][kk] = W[(size_t)(colBase + r) * 64 + (k0 + kk)];
        }
        __syncthreads();
#pragma unroll
        for (int kk = 0; kk < 16; ++kk) {
            float a[8], w[8];
#pragma unroll
            for (int i = 0; i < 8; ++i) a[i] = As[ty + 16 * i][kk];
#pragma unroll
            for (int j = 0; j < 8; ++j) w[j] = Ws[tx + 16 * j][kk];
#pragma unroll
            for (int i = 0; i < 8; ++i)
#pragma unroll
                for (int j = 0; j < 8; ++j) acc[i][j] += a[i] * w[j];
        }
        __syncthreads();
    }

#pragma unroll
    for (int i = 0; i < 8; ++i) {
        int r = rowBase + ty + 16 * i;
#pragma unroll
        for (int j = 0; j < 8; ++j) {
            int c = colBase + tx + 16 * j;
            float t = acc[i][j] + bias[c];
            t = fminf(fmaxf(t, 1e-5f), 1.0f);
            C[(size_t)r * 2048 + c] = softplusf(t + bias[c]);
        }
    }
}

// ---------------------------------------------------------------------------
// Depthwise causal conv1d, both directions. Also emits bf16 copy for G2.
// ---------------------------------------------------------------------------
__global__ __launch_bounds__(256) void conv_kernel(
    const float* __restrict__ xz,
    const float* __restrict__ wf, const float* __restrict__ bf,
    const float* __restrict__ wb, const float* __restrict__ bb,
    float* __restrict__ xcf, float* __restrict__ xcb,
    bf16* __restrict__ xcbf, bf16* __restrict__ xcbb)
{
    int idx = blockIdx.x * 256 + threadIdx.x;
    int d = idx & (DINNER - 1);
    int rest = idx >> 11;
    int l = rest & (LL - 1);
    int b = (rest >> 9) & (BB - 1);
    int dir = rest >> 11;

    const float* w = dir ? wb : wf;
    float accv = (dir ? bb : bf)[d];
#pragma unroll
    for (int k = 0; k < DCONV; ++k) {
        int j = l - (DCONV - 1) + k;
        if (j >= 0) {
            int jj = dir ? (LL - 1 - j) : j;
            accv += w[d * DCONV + k] * xz[((size_t)(b * LL + jj)) * (2 * DINNER) + d];
        }
    }
    size_t off = ((size_t)(b * LL + l)) * DINNER + d;
    (dir ? xcb : xcf)[off] = accv;
    (dir ? xcbb : xcbf)[off] = __float2bfloat16(accv);
}

// ---------------------------------------------------------------------------
// Chunked scan phase 1
// ---------------------------------------------------------------------------
__global__ __launch_bounds__(256) void scan1_kernel(
    const float* __restrict__ Alog_f, const float* __restrict__ Alog_b,
    const float* __restrict__ xdbl_f, const float* __restrict__ xdbl_b,
    const float* __restrict__ xc_f, const float* __restrict__ xc_b,
    const float* __restrict__ dl_f, const float* __restrict__ dl_b,
    float* __restrict__ sdel, float* __restrict__ hend)
{
    const int tid = threadIdx.x;
    const int d = blockIdx.x * 256 + tid;
    const int c = blockIdx.y;
    const int z = blockIdx.z;           // dir*4 + b
    const int dir = z >> 2, b = z & 3;

    const float* Alog = dir ? Alog_b : Alog_f;
    const float* xdbl = dir ? xdbl_b : xdbl_f;
    const float* xc   = dir ? xc_b   : xc_f;
    const float* dl   = dir ? dl_b   : dl_f;
    const int rowBase = b * LL + c * SCHUNK;

    __shared__ float bs[SCHUNK][16];
#pragma unroll
    for (int i = 0; i < SCHUNK * 16 / 256; ++i) {
        int e = tid + 256 * i;
        int r = e >> 4, n = e & 15;
        bs[r][n] = xdbl[(size_t)(rowBase + r) * 96 + DTRANK + n];
    }
    __syncthreads();

    float Aa[DSTATE], h[DSTATE];
#pragma unroll
    for (int n = 0; n < DSTATE; ++n) {
        Aa[n] = -__expf(Alog[d * DSTATE + n]);
        h[n] = 0.f;
    }
    float sd = 0.f;

    for (int t = 0; t < SCHUNK; ++t) {
        size_t row = (size_t)(rowBase + t);
        float delta = dl[row * DINNER + d];
        float u = xc[row * DINNER + d];
        u = fminf(fmaxf(u, -10.f), 10.f);
        float du = delta * u;
        sd += delta;
#pragma unroll
        for (int n = 0; n < DSTATE; ++n)
            h[n] = __expf(delta * Aa[n]) * h[n] + du * bs[t][n];
    }

    size_t base = (size_t)z * SNC + c;
    sdel[base * DINNER + d] = sd;
#pragma unroll
    for (int n = 0; n < DSTATE; ++n)
        hend[(base * DSTATE + n) * DINNER + d] = h[n];
}

// ---------------------------------------------------------------------------
// Combine: sequential over chunks
// ---------------------------------------------------------------------------
__global__ __launch_bounds__(256) void scan_combine(
    const float* __restrict__ Alog_f, const float* __restrict__ Alog_b,
    const float* __restrict__ sdel, const float* __restrict__ hend,
    float* __restrict__ hin)
{
    int g = blockIdx.x * 256 + threadIdx.x;
    int d = g & (DINNER - 1);
    int z = g >> 11;
    int dir = z >> 2;
    const float* Alog = dir ? Alog_b : Alog_f;

    float Aa[DSTATE], hr[DSTATE];
#pragma unroll
    for (int n = 0; n < DSTATE; ++n) {
        Aa[n] = -__expf(Alog[d * DSTATE + n]);
        hr[n] = 0.f;
    }
    for (int c = 0; c < SNC; ++c) {
        size_t base = (size_t)z * SNC + c;
#pragma unroll
        for (int n = 0; n < DSTATE; ++n)
            hin[(base * DSTATE + n) * DINNER + d] = hr[n];
        float sd = sdel[base * DINNER + d];
#pragma unroll
        for (int n = 0; n < DSTATE; ++n)
            hr[n] = __expf(sd * Aa[n]) * hr[n] + hend[(base * DSTATE + n) * DINNER + d];
    }
}

// ---------------------------------------------------------------------------
// Chunked scan phase 2
// ---------------------------------------------------------------------------
__global__ __launch_bounds__(256) void scan2_kernel(
    const float* __restrict__ Alog_f, const float* __restrict__ Alog_b,
    const float* __restrict__ Df, const float* __restrict__ Db,
    const float* __restrict__ xdbl_f, const float* __restrict__ xdbl_b,
    const float* __restrict__ xc_f, const float* __restrict__ xc_b,
    const float* __restrict__ hin,
    float* __restrict__ dl_f, float* __restrict__ dl_b)
{
    const int tid = threadIdx.x;
    const int d = blockIdx.x * 256 + tid;
    const int c = blockIdx.y;
    const int z = blockIdx.z;
    const int dir = z >> 2, b = z & 3;

    const float* Alog = dir ? Alog_b : Alog_f;
    const float* xdbl = dir ? xdbl_b : xdbl_f;
    const float* xc   = dir ? xc_b   : xc_f;
    float* dl         = dir ? dl_b   : dl_f;
    const int rowBase = b * LL + c * SCHUNK;

    __shared__ float bs[SCHUNK][32];
#pragma unroll
    for (int i = 0; i < SCHUNK * 32 / 256; ++i) {
        int e = tid + 256 * i;
        int r = e >> 5, n = e & 31;
        bs[r][n] = xdbl[(size_t)(rowBase + r) * 96 + DTRANK + n];
    }
    __syncthreads();

    float Dv = (dir ? Db : Df)[d];
    size_t base = (size_t)z * SNC + c;
    float Aa[DSTATE], h[DSTATE];
#pragma unroll
    for (int n = 0; n < DSTATE; ++n) {
        Aa[n] = -__expf(Alog[d * DSTATE + n]);
        h[n] = hin[(base * DSTATE + n) * DINNER + d];
    }

    for (int t = 0; t < SCHUNK; ++t) {
        size_t row = (size_t)(rowBase + t);
        float delta = dl[row * DINNER + d];
        float u = xc[row * DINNER + d];
        u = fminf(fmaxf(u, -10.f), 10.f);
        float du = delta * u;
        float y = 0.f;
#pragma unroll
        for (int n = 0; n < DSTATE; ++n) {
            h[n] = __expf(delta * Aa[n]) * h[n] + du * bs[t][n];
            y += h[n] * bs[t][DSTATE + n];
        }
        dl[row * DINNER + d] = y + u * Dv;
    }
}

// ---------------------------------------------------------------------------
// Gate: ytot = (y_f + y_b_rev) * silu(z), written as bf16 for G4
// ---------------------------------------------------------------------------
__global__ __launch_bounds__(256) void gate_kernel(
    const float* __restrict__ yf, const float* __restrict__ yb,
    const float* __restrict__ xz, bf16* __restrict__ ytot)
{
    int idx = blockIdx.x * 256 + threadIdx.x;
    int d = idx & (DINNER - 1);
    int l = (idx >> 11) & (LL - 1);
    int b = idx >> 20;
    size_t rowf = (size_t)(b * LL + l);
    size_t rowb = (size_t)(b * LL + (LL - 1 - l));
    float y = yf[rowf * DINNER + d] + yb[rowb * DINNER + d];
    float z = xz[rowf * (2 * DINNER) + DINNER + d];
    float s = z / (1.f + __expf(-z));
    ytot[rowf * DINNER + d] = __float2bfloat16(y * s);
}

// ---------------------------------------------------------------------------
extern "C" void kernel_launch(void* const* d_in, const int* in_sizes, int n_in,
                              void* d_out, int out_size, void* d_ws, size_t ws_size,
                              hipStream_t stream)
{
    const float* hidden    = (const float*)d_in[0];
    const float* in_proj_w = (const float*)d_in[1];
    const float* conv_w    = (const float*)d_in[2];
    const float* conv_b    = (const float*)d_in[3];
    const float* xproj_w   = (const float*)d_in[4];
    const float* dtproj_w  = (const float*)d_in[5];
    const float* dtproj_b  = (const float*)d_in[6];
    const float* A_log     = (const float*)d_in[7];
    const float* Dvec      = (const float*)d_in[8];
    const float* conv_bw   = (const float*)d_in[9];
    const float* conv_bb   = (const float*)d_in[10];
    const float* xproj_bw  = (const float*)d_in[11];
    const float* dtproj_bw = (const float*)d_in[12];
    const float* dtproj_bb = (const float*)d_in[13];
    const float* A_b_log   = (const float*)d_in[14];
    const float* D_b       = (const float*)d_in[15];
    const float* out_pw    = (const float*)d_in[16];
    float* out = (float*)d_out;

    float* ws = (float*)d_ws;
    float* xz     = ws;                      // 8388608 f32
    float* xc_f   = xz + 8388608;            // 4194304
    float* xc_b   = xc_f + 4194304;          // 4194304
    float* xdbl_f = xc_b + 4194304;          // 196608
    float* xdbl_b = xdbl_f + 196608;         // 196608
    float* dl_f   = xdbl_b + 196608;         // 4194304 (delta -> y)
    float* dl_b   = dl_f + 4194304;          // 4194304
    float* g2part = dl_b + 4194304;          // 2*G2KS*2048*96 = 1572864
    float* sdel   = g2part + 1572864;        // 131072
    float* hend   = sdel + 131072;           // 2097152
    float* hin    = hend + 2097152;          // 2097152
    // total 31,457,280 floats = 125.8 MB

    // bf16 aliases over regions dead at time of use:
    bf16* hbf = (bf16*)dl_f;                 // pre-G1 only (dl written by g3)
    bf16* wbf = (bf16*)(dl_f + 1048576);
    bf16* wxf = (bf16*)dl_b;                 // xproj weights, dead before g3
    bf16* wxb = (bf16*)(dl_b + 98304);
    bf16* xcbf = (bf16*)hend;                // conv->g2 only (hend written by scan1)
    bf16* xcbb = (bf16*)hin;                 // (hin written by scan_combine)
    bf16* ytot_bf = (bf16*)xc_f;             // post-scan (xc dead)
    bf16* obf = (bf16*)xc_b;

    dim3 blk(256);

    // casts
    cast_kernel<<<dim3(2097152 / 8 / 256), blk, 0, stream>>>(hidden, hbf, 2097152);
    cast_kernel<<<dim3(4194304 / 8 / 256), blk, 0, stream>>>(in_proj_w, wbf, 4194304);
    cast_kernel<<<dim3(196608 / 8 / 256), blk, 0, stream>>>(xproj_w, wxf, 196608);
    cast_kernel<<<dim3(196608 / 8 / 256), blk, 0, stream>>>(xproj_bw, wxb, 196608);

    // G1: xz = hidden @ in_proj_w.T   (M=2048, N=4096, K=1024) bf16 MFMA
    gemm_bf16<0><<<dim3(4096 / 128, MROWS / 128), blk, 0, stream>>>(
        hbf, wbf, xz, 4096, 1024, 1024, 1024, 4096);

    // conv both dirs (fp32 + bf16 outputs)
    conv_kernel<<<dim3(2 * BB * LL * DINNER / 256), blk, 0, stream>>>(
        xz, conv_w, conv_b, conv_bw, conv_bb, xc_f, xc_b, xcbf, xcbb);

    // G2 via bf16 MFMA split-K
    g2_mfma<<<dim3(16, G2KS, 2), blk, 0, stream>>>(
        xcbf, xcbb, wxf, wxb, g2part);
    g2_reduce<<<dim3(2 * 2048 * 96 / 256), blk, 0, stream>>>(
        g2part, xdbl_f, xdbl_b);

    // G3 (both dirs in one launch)
    g3_kernel<<<dim3(16, 16, 2), blk, 0, stream>>>(
        xdbl_f, xdbl_b, dtproj_w, dtproj_bw, dtproj_b, dtproj_bb, dl_f, dl_b);

    // chunked scan
    scan1_kernel<<<dim3(DINNER / 256, SNC, 8), blk, 0, stream>>>(
        A_log, A_b_log, xdbl_f, xdbl_b, xc_f, xc_b, dl_f, dl_b, sdel, hend);
    scan_combine<<<dim3(2 * BB * DINNER / 256), blk, 0, stream>>>(
        A_log, A_b_log, sdel, hend, hin);
    scan2_kernel<<<dim3(DINNER / 256, SNC, 8), blk, 0, stream>>>(
        A_log, A_b_log, Dvec, D_b, xdbl_f, xdbl_b, xc_f, xc_b, hin, dl_f, dl_b);

    // gate -> bf16 ytot (into dead xc_f region)
    gate_kernel<<<dim3(BB * LL * DINNER / 256), blk, 0, stream>>>(
        dl_f, dl_b, xz, ytot_bf);

    // cast out_proj_w (xc_b dead after scan)
    cast_kernel<<<dim3(2097152 / 8 / 256), blk, 0, stream>>>(out_pw, obf, 2097152);

    // G4: out = ytot @ out_proj_w.T  bf16 MFMA + nan_to_num
    gemm_bf16<2><<<dim3(DMODEL / 128, MROWS / 128), blk, 0, stream>>>(
        ytot_bf, obf, out, 1024, 2048, 2048, 2048, 1024);
}

// Round 7
// 303.297 us; speedup vs baseline: 7.3284x; 1.1017x over previous
//
#include <hip/hip_runtime.h>
#include <hip/hip_bf16.h>
#include <math.h>

// Problem constants
#define BB 4
#define LL 512
#define DMODEL 1024
#define DSTATE 16
#define DCONV 4
#define DINNER 2048
#define DTRANK 64
#define MROWS (BB*LL)          // 2048 rows of (b,l)
#define G2KS 4                 // split-K factor for the N=96 GEMM
#define SCHUNK 64              // scan chunk length
#define SNC (LL / SCHUNK)      // 8 chunks

typedef __hip_bfloat16 bf16;
typedef __attribute__((ext_vector_type(8))) short short8;
typedef __attribute__((ext_vector_type(4))) float f32x4;

__device__ __forceinline__ float softplusf(float x) {
    return x > 20.f ? x : log1pf(__expf(x));
}

// ---------------------------------------------------------------------------
// bf16 MFMA TN GEMM: C[M][N](f32) = A[M][K](bf16) * W[N][K](bf16)^T
// 128x128 tile, 4 waves, 4x4 16x16x32 frags. EPI 0: none; 2: nan_to_num.
// ---------------------------------------------------------------------------
template<int EPI>
__global__ __launch_bounds__(256) void gemm_bf16(
    const bf16* __restrict__ A, const bf16* __restrict__ W,
    float* __restrict__ C, int N, int K, int lda, int ldw, int ldc)
{
    __shared__ bf16 lA[128 * 40];
    __shared__ bf16 lW[128 * 40];

    const int tid = threadIdx.x;
    const int lane = tid & 63;
    const int wid = tid >> 6;
    const int wr = wid >> 1;
    const int wc = wid & 1;
    const int rowBase = blockIdx.y * 128;
    const int colBase = blockIdx.x * 128;

    const int r16 = lane & 15;
    const int kg = lane >> 4;

    f32x4 acc[4][4];
#pragma unroll
    for (int m = 0; m < 4; ++m)
#pragma unroll
        for (int n = 0; n < 4; ++n) acc[m][n] = (f32x4)0.f;

    const int srow = tid >> 2;
    const int scol = (tid & 3) * 8;

    for (int k0 = 0; k0 < K; k0 += 32) {
#pragma unroll
        for (int it = 0; it < 2; ++it) {
            int r = srow + it * 64;
            short8 va = *(const short8*)&A[(size_t)(rowBase + r) * lda + k0 + scol];
            short8 vw = *(const short8*)&W[(size_t)(colBase + r) * ldw + k0 + scol];
            *(short8*)&lA[r * 40 + scol] = va;
            *(short8*)&lW[r * 40 + scol] = vw;
        }
        __syncthreads();

        short8 a[4], b[4];
#pragma unroll
        for (int m = 0; m < 4; ++m)
            a[m] = *(const short8*)&lA[(wr * 64 + m * 16 + r16) * 40 + kg * 8];
#pragma unroll
        for (int n = 0; n < 4; ++n)
            b[n] = *(const short8*)&lW[(wc * 64 + n * 16 + r16) * 40 + kg * 8];
#pragma unroll
        for (int m = 0; m < 4; ++m)
#pragma unroll
            for (int n = 0; n < 4; ++n)
                acc[m][n] = __builtin_amdgcn_mfma_f32_16x16x32_bf16(
                    a[m], b[n], acc[m][n], 0, 0, 0);
        __syncthreads();
    }

#pragma unroll
    for (int m = 0; m < 4; ++m) {
#pragma unroll
        for (int n = 0; n < 4; ++n) {
            int gc = colBase + wc * 64 + n * 16 + r16;
#pragma unroll
            for (int j = 0; j < 4; ++j) {
                int gr = rowBase + wr * 64 + m * 16 + kg * 4 + j;
                float v = acc[m][n][j];
                if (EPI == 2) {
                    if (isnan(v)) v = 0.f;
                    else if (isinf(v)) v = (v > 0.f) ? 1.f : -1.f;
                }
                C[(size_t)gr * ldc + gc] = v;
            }
        }
    }
}

// ---------------------------------------------------------------------------
// G3 as bf16 MFMA: dl[dir] = softplus(clip(xdbl_bf[dir][:, :64] @ dtw[dir].T
//                  + bias, 1e-5, 1) + bias).   M=2048, N=2048, K=64.
// ---------------------------------------------------------------------------
__global__ __launch_bounds__(256) void g3_mfma(
    const bf16* __restrict__ xdbl_bf,   // [2][2048][96]
    const bf16* __restrict__ dtw_bf,    // [2][2048][64]
    const float* __restrict__ biasf, const float* __restrict__ biasb,
    float* __restrict__ of, float* __restrict__ ob)
{
    const int dir = blockIdx.z;
    const bf16* A = xdbl_bf + (size_t)dir * 2048 * 96;
    const bf16* W = dtw_bf + (size_t)dir * 2048 * 64;
    const float* bias = dir ? biasb : biasf;
    float* C = dir ? ob : of;

    __shared__ bf16 lA[128 * 40];
    __shared__ bf16 lW[128 * 40];

    const int tid = threadIdx.x;
    const int lane = tid & 63;
    const int wid = tid >> 6;
    const int wr = wid >> 1;
    const int wc = wid & 1;
    const int rowBase = blockIdx.y * 128;
    const int colBase = blockIdx.x * 128;

    const int r16 = lane & 15;
    const int kg = lane >> 4;

    f32x4 acc[4][4];
#pragma unroll
    for (int m = 0; m < 4; ++m)
#pragma unroll
        for (int n = 0; n < 4; ++n) acc[m][n] = (f32x4)0.f;

    const int srow = tid >> 2;
    const int scol = (tid & 3) * 8;

#pragma unroll
    for (int k0 = 0; k0 < 64; k0 += 32) {
#pragma unroll
        for (int it = 0; it < 2; ++it) {
            int r = srow + it * 64;
            short8 va = *(const short8*)&A[(size_t)(rowBase + r) * 96 + k0 + scol];
            short8 vw = *(const short8*)&W[(size_t)(colBase + r) * 64 + k0 + scol];
            *(short8*)&lA[r * 40 + scol] = va;
            *(short8*)&lW[r * 40 + scol] = vw;
        }
        __syncthreads();

        short8 a[4], b[4];
#pragma unroll
        for (int m = 0; m < 4; ++m)
            a[m] = *(const short8*)&lA[(wr * 64 + m * 16 + r16) * 40 + kg * 8];
#pragma unroll
        for (int n = 0; n < 4; ++n)
            b[n] = *(const short8*)&lW[(wc * 64 + n * 16 + r16) * 40 + kg * 8];
#pragma unroll
        for (int m = 0; m < 4; ++m)
#pragma unroll
            for (int n = 0; n < 4; ++n)
                acc[m][n] = __builtin_amdgcn_mfma_f32_16x16x32_bf16(
                    a[m], b[n], acc[m][n], 0, 0, 0);
        __syncthreads();
    }

#pragma unroll
    for (int m = 0; m < 4; ++m) {
#pragma unroll
        for (int n = 0; n < 4; ++n) {
            int gc = colBase + wc * 64 + n * 16 + r16;
            float bv = bias[gc];
#pragma unroll
            for (int j = 0; j < 4; ++j) {
                int gr = rowBase + wr * 64 + m * 16 + kg * 4 + j;
                float t = acc[m][n][j] + bv;
                t = fminf(fmaxf(t, 1e-5f), 1.0f);
                C[(size_t)gr * 2048 + gc] = softplusf(t + bv);
            }
        }
    }
}

// ---------------------------------------------------------------------------
// G2 as bf16 MFMA: part[dir][kz] = xcbf[dir][:, kz*512:+512] @ wx[dir].T
// ---------------------------------------------------------------------------
__global__ __launch_bounds__(256) void g2_mfma(
    const bf16* __restrict__ xcbf_f, const bf16* __restrict__ xcbf_b,
    const bf16* __restrict__ wxf, const bf16* __restrict__ wxb,
    float* __restrict__ part)   // [2][G2KS][2048][96]
{
    const int dir = blockIdx.z;
    const bf16* A = dir ? xcbf_b : xcbf_f;
    const bf16* W = dir ? wxb : wxf;
    const int rowBase = blockIdx.x * 128;
    const int kz = blockIdx.y;
    const int kBase = kz * (2048 / G2KS);

    __shared__ bf16 lA[128 * 40];
    __shared__ bf16 lW[96 * 40];

    const int tid = threadIdx.x;
    const int lane = tid & 63;
    const int wid = tid >> 6;
    const int r16 = lane & 15;
    const int kg = lane >> 4;

    f32x4 acc[2][6];
#pragma unroll
    for (int m = 0; m < 2; ++m)
#pragma unroll
        for (int n = 0; n < 6; ++n) acc[m][n] = (f32x4)0.f;

    const int srow = tid >> 2;
    const int scol = (tid & 3) * 8;

    for (int k0 = 0; k0 < 2048 / G2KS; k0 += 32) {
#pragma unroll
        for (int it = 0; it < 2; ++it) {
            int r = srow + it * 64;
            short8 va = *(const short8*)&A[(size_t)(rowBase + r) * 2048 + kBase + k0 + scol];
            *(short8*)&lA[r * 40 + scol] = va;
        }
        {
            short8 vw = *(const short8*)&W[(size_t)srow * 2048 + kBase + k0 + scol];
            *(short8*)&lW[srow * 40 + scol] = vw;
        }
        if (tid < 128) {
            int r = 64 + (tid >> 2);
            short8 vw2 = *(const short8*)&W[(size_t)r * 2048 + kBase + k0 + scol];
            *(short8*)&lW[r * 40 + scol] = vw2;
        }
        __syncthreads();

        short8 a[2], b[6];
#pragma unroll
        for (int m = 0; m < 2; ++m)
            a[m] = *(const short8*)&lA[(wid * 32 + m * 16 + r16) * 40 + kg * 8];
#pragma unroll
        for (int n = 0; n < 6; ++n)
            b[n] = *(const short8*)&lW[(n * 16 + r16) * 40 + kg * 8];
#pragma unroll
        for (int m = 0; m < 2; ++m)
#pragma unroll
            for (int n = 0; n < 6; ++n)
                acc[m][n] = __builtin_amdgcn_mfma_f32_16x16x32_bf16(
                    a[m], b[n], acc[m][n], 0, 0, 0);
        __syncthreads();
    }

    float* p = part + ((size_t)(dir * G2KS + kz) * 2048) * 96;
#pragma unroll
    for (int m = 0; m < 2; ++m) {
#pragma unroll
        for (int n = 0; n < 6; ++n) {
            int gc = n * 16 + r16;
#pragma unroll
            for (int j = 0; j < 4; ++j) {
                int gr = rowBase + wid * 32 + m * 16 + kg * 4 + j;
                p[(size_t)gr * 96 + gc] = acc[m][n][j];
            }
        }
    }
}

// g2_reduce: sum split-K partials -> fp32 xdbl AND bf16 xdbl copy (for g3)
__global__ __launch_bounds__(256) void g2_reduce(
    const float* __restrict__ part, float* __restrict__ xf, float* __restrict__ xb,
    bf16* __restrict__ xdbl_bf)
{
    int idx = blockIdx.x * 256 + threadIdx.x;
    int c = idx % 96;
    int r = (idx / 96) & 2047;
    int dir = idx / (96 * 2048);
    float s = 0.f;
#pragma unroll
    for (int ks = 0; ks < G2KS; ++ks)
        s += part[((size_t)(dir * G2KS + ks) * 2048 + r) * 96 + c];
    (dir ? xb : xf)[(size_t)r * 96 + c] = s;
    xdbl_bf[((size_t)dir * 2048 + r) * 96 + c] = __float2bfloat16(s);
}

// ---------------------------------------------------------------------------
// f32 -> bf16 cast
// ---------------------------------------------------------------------------
__global__ __launch_bounds__(256) void cast_kernel(
    const float* __restrict__ in, bf16* __restrict__ out, int n)
{
    int i = (blockIdx.x * 256 + threadIdx.x) * 8;
    if (i >= n) return;
    float4 x = *(const float4*)&in[i];
    float4 y = *(const float4*)&in[i + 4];
    bf16 t[8] = { __float2bfloat16(x.x), __float2bfloat16(x.y),
                  __float2bfloat16(x.z), __float2bfloat16(x.w),
                  __float2bfloat16(y.x), __float2bfloat16(y.y),
                  __float2bfloat16(y.z), __float2bfloat16(y.w) };
    *(short8*)&out[i] = *(short8*)t;
}

// ---------------------------------------------------------------------------
// Depthwise causal conv1d, both directions. Also emits bf16 copy for G2.
// ---------------------------------------------------------------------------
__global__ __launch_bounds__(256) void conv_kernel(
    const float* __restrict__ xz,
    const float* __restrict__ wf, const float* __restrict__ bf,
    const float* __restrict__ wb, const float* __restrict__ bb,
    float* __restrict__ xcf, float* __restrict__ xcb,
    bf16* __restrict__ xcbf, bf16* __restrict__ xcbb)
{
    int idx = blockIdx.x * 256 + threadIdx.x;
    int d = idx & (DINNER - 1);
    int rest = idx >> 11;
    int l = rest & (LL - 1);
    int b = (rest >> 9) & (BB - 1);
    int dir = rest >> 11;

    const float* w = dir ? wb : wf;
    float accv = (dir ? bb : bf)[d];
#pragma unroll
    for (int k = 0; k < DCONV; ++k) {
        int j = l - (DCONV - 1) + k;
        if (j >= 0) {
            int jj = dir ? (LL - 1 - j) : j;
            accv += w[d * DCONV + k] * xz[((size_t)(b * LL + jj)) * (2 * DINNER) + d];
        }
    }
    size_t off = ((size_t)(b * LL + l)) * DINNER + d;
    (dir ? xcb : xcf)[off] = accv;
    (dir ? xcbb : xcbf)[off] = __float2bfloat16(accv);
}

// ---------------------------------------------------------------------------
// Chunked scan phase 1
// ---------------------------------------------------------------------------
__global__ __launch_bounds__(256) void scan1_kernel(
    const float* __restrict__ Alog_f, const float* __restrict__ Alog_b,
    const float* __restrict__ xdbl_f, const float* __restrict__ xdbl_b,
    const float* __restrict__ xc_f, const float* __restrict__ xc_b,
    const float* __restrict__ dl_f, const float* __restrict__ dl_b,
    float* __restrict__ sdel, float* __restrict__ hend)
{
    const int tid = threadIdx.x;
    const int d = blockIdx.x * 256 + tid;
    const int c = blockIdx.y;
    const int z = blockIdx.z;           // dir*4 + b
    const int dir = z >> 2, b = z & 3;

    const float* Alog = dir ? Alog_b : Alog_f;
    const float* xdbl = dir ? xdbl_b : xdbl_f;
    const float* xc   = dir ? xc_b   : xc_f;
    const float* dl   = dir ? dl_b   : dl_f;
    const int rowBase = b * LL + c * SCHUNK;

    __shared__ float bs[SCHUNK][16];
#pragma unroll
    for (int i = 0; i < SCHUNK * 16 / 256; ++i) {
        int e = tid + 256 * i;
        int r = e >> 4, n = e & 15;
        bs[r][n] = xdbl[(size_t)(rowBase + r) * 96 + DTRANK + n];
    }
    __syncthreads();

    float Aa[DSTATE], h[DSTATE];
#pragma unroll
    for (int n = 0; n < DSTATE; ++n) {
        Aa[n] = -__expf(Alog[d * DSTATE + n]);
        h[n] = 0.f;
    }
    float sd = 0.f;

    for (int t = 0; t < SCHUNK; ++t) {
        size_t row = (size_t)(rowBase + t);
        float delta = dl[row * DINNER + d];
        float u = xc[row * DINNER + d];
        u = fminf(fmaxf(u, -10.f), 10.f);
        float du = delta * u;
        sd += delta;
#pragma unroll
        for (int n = 0; n < DSTATE; ++n)
            h[n] = __expf(delta * Aa[n]) * h[n] + du * bs[t][n];
    }

    size_t base = (size_t)z * SNC + c;
    sdel[base * DINNER + d] = sd;
#pragma unroll
    for (int n = 0; n < DSTATE; ++n)
        hend[(base * DSTATE + n) * DINNER + d] = h[n];
}

// ---------------------------------------------------------------------------
// Combine: sequential over chunks
// ---------------------------------------------------------------------------
__global__ __launch_bounds__(256) void scan_combine(
    const float* __restrict__ Alog_f, const float* __restrict__ Alog_b,
    const float* __restrict__ sdel, const float* __restrict__ hend,
    float* __restrict__ hin)
{
    int g = blockIdx.x * 256 + threadIdx.x;
    int d = g & (DINNER - 1);
    int z = g >> 11;
    int dir = z >> 2;
    const float* Alog = dir ? Alog_b : Alog_f;

    float Aa[DSTATE], hr[DSTATE];
#pragma unroll
    for (int n = 0; n < DSTATE; ++n) {
        Aa[n] = -__expf(Alog[d * DSTATE + n]);
        hr[n] = 0.f;
    }
    for (int c = 0; c < SNC; ++c) {
        size_t base = (size_t)z * SNC + c;
#pragma unroll
        for (int n = 0; n < DSTATE; ++n)
            hin[(base * DSTATE + n) * DINNER + d] = hr[n];
        float sd = sdel[base * DINNER + d];
#pragma unroll
        for (int n = 0; n < DSTATE; ++n)
            hr[n] = __expf(sd * Aa[n]) * hr[n] + hend[(base * DSTATE + n) * DINNER + d];
    }
}

// ---------------------------------------------------------------------------
// Chunked scan phase 2
// ---------------------------------------------------------------------------
__global__ __launch_bounds__(256) void scan2_kernel(
    const float* __restrict__ Alog_f, const float* __restrict__ Alog_b,
    const float* __restrict__ Df, const float* __restrict__ Db,
    const float* __restrict__ xdbl_f, const float* __restrict__ xdbl_b,
    const float* __restrict__ xc_f, const float* __restrict__ xc_b,
    const float* __restrict__ hin,
    float* __restrict__ dl_f, float* __restrict__ dl_b)
{
    const int tid = threadIdx.x;
    const int d = blockIdx.x * 256 + tid;
    const int c = blockIdx.y;
    const int z = blockIdx.z;
    const int dir = z >> 2, b = z & 3;

    const float* Alog = dir ? Alog_b : Alog_f;
    const float* xdbl = dir ? xdbl_b : xdbl_f;
    const float* xc   = dir ? xc_b   : xc_f;
    float* dl         = dir ? dl_b   : dl_f;
    const int rowBase = b * LL + c * SCHUNK;

    __shared__ float bs[SCHUNK][32];
#pragma unroll
    for (int i = 0; i < SCHUNK * 32 / 256; ++i) {
        int e = tid + 256 * i;
        int r = e >> 5, n = e & 31;
        bs[r][n] = xdbl[(size_t)(rowBase + r) * 96 + DTRANK + n];
    }
    __syncthreads();

    float Dv = (dir ? Db : Df)[d];
    size_t base = (size_t)z * SNC + c;
    float Aa[DSTATE], h[DSTATE];
#pragma unroll
    for (int n = 0; n < DSTATE; ++n) {
        Aa[n] = -__expf(Alog[d * DSTATE + n]);
        h[n] = hin[(base * DSTATE + n) * DINNER + d];
    }

    for (int t = 0; t < SCHUNK; ++t) {
        size_t row = (size_t)(rowBase + t);
        float delta = dl[row * DINNER + d];
        float u = xc[row * DINNER + d];
        u = fminf(fmaxf(u, -10.f), 10.f);
        float du = delta * u;
        float y = 0.f;
#pragma unroll
        for (int n = 0; n < DSTATE; ++n) {
            h[n] = __expf(delta * Aa[n]) * h[n] + du * bs[t][n];
            y += h[n] * bs[t][DSTATE + n];
        }
        dl[row * DINNER + d] = y + u * Dv;
    }
}

// ---------------------------------------------------------------------------
// Gate: ytot = (y_f + y_b_rev) * silu(z), written as bf16 for G4
// ---------------------------------------------------------------------------
__global__ __launch_bounds__(256) void gate_kernel(
    const float* __restrict__ yf, const float* __restrict__ yb,
    const float* __restrict__ xz, bf16* __restrict__ ytot)
{
    int idx = blockIdx.x * 256 + threadIdx.x;
    int d = idx & (DINNER - 1);
    int l = (idx >> 11) & (LL - 1);
    int b = idx >> 20;
    size_t rowf = (size_t)(b * LL + l);
    size_t rowb = (size_t)(b * LL + (LL - 1 - l));
    float y = yf[rowf * DINNER + d] + yb[rowb * DINNER + d];
    float z = xz[rowf * (2 * DINNER) + DINNER + d];
    float s = z / (1.f + __expf(-z));
    ytot[rowf * DINNER + d] = __float2bfloat16(y * s);
}

// ---------------------------------------------------------------------------
extern "C" void kernel_launch(void* const* d_in, const int* in_sizes, int n_in,
                              void* d_out, int out_size, void* d_ws, size_t ws_size,
                              hipStream_t stream)
{
    const float* hidden    = (const float*)d_in[0];
    const float* in_proj_w = (const float*)d_in[1];
    const float* conv_w    = (const float*)d_in[2];
    const float* conv_b    = (const float*)d_in[3];
    const float* xproj_w   = (const float*)d_in[4];
    const float* dtproj_w  = (const float*)d_in[5];
    const float* dtproj_b  = (const float*)d_in[6];
    const float* A_log     = (const float*)d_in[7];
    const float* Dvec      = (const float*)d_in[8];
    const float* conv_bw   = (const float*)d_in[9];
    const float* conv_bb   = (const float*)d_in[10];
    const float* xproj_bw  = (const float*)d_in[11];
    const float* dtproj_bw = (const float*)d_in[12];
    const float* dtproj_bb = (const float*)d_in[13];
    const float* A_b_log   = (const float*)d_in[14];
    const float* D_b       = (const float*)d_in[15];
    const float* out_pw    = (const float*)d_in[16];
    float* out = (float*)d_out;

    float* ws = (float*)d_ws;
    float* xz     = ws;                      // 8388608 f32
    float* xc_f   = xz + 8388608;            // 4194304
    float* xc_b   = xc_f + 4194304;          // 4194304
    float* xdbl_f = xc_b + 4194304;          // 196608
    float* xdbl_b = xdbl_f + 196608;         // 196608
    float* dl_f   = xdbl_b + 196608;         // 4194304 (delta -> y)
    float* dl_b   = dl_f + 4194304;          // 4194304
    float* g2part = dl_b + 4194304;          // 1572864
    float* sdel   = g2part + 1572864;        // 131072
    float* hend   = sdel + 131072;           // 2097152
    float* hin    = hend + 2097152;          // 2097152
    // total 31,457,280 floats = 125.8 MB

    // bf16 aliases over regions dead at time of use (liveness audited R6):
    bf16* hbf = (bf16*)dl_f;                 // [dl_f+0 .. +1048576 f32) pre-G1; dl_f written by g3
    bf16* wbf = (bf16*)(dl_f + 1048576);     // [+1048576 .. +3145728) pre-G1
    bf16* wxf = (bf16*)dl_b;                 // [dl_b+0 .. +98304) consumed by g2_mfma, dl_b written by g3
    bf16* wxb = (bf16*)(dl_b + 98304);       // [+98304 .. +196608)
    bf16* xcbf = (bf16*)hend;                // ALL of hend; conv->g2_mfma; hend written by scan1 (later)
    bf16* xcbb = (bf16*)hin;                 // ALL of hin; hin written by scan_combine (later)
    bf16* xdbl_bf = (bf16*)(hend + 1048576); // written by g2_reduce (xcbf 2nd half dead post-g2_mfma), read by g3
    bf16* dtw_bf  = (bf16*)sdel;             // ALL of sdel (262144 bf16); cast early, read by g3;
                                             // sdel first written by scan1 (after g3)  -- R5 bug fixed
    bf16* ytot_bf = (bf16*)xc_f;             // post-scan (xc dead)
    bf16* obf = (bf16*)xc_b;

    dim3 blk(256);

    // casts
    cast_kernel<<<dim3(2097152 / 8 / 256), blk, 0, stream>>>(hidden, hbf, 2097152);
    cast_kernel<<<dim3(4194304 / 8 / 256), blk, 0, stream>>>(in_proj_w, wbf, 4194304);
    cast_kernel<<<dim3(196608 / 8 / 256), blk, 0, stream>>>(xproj_w, wxf, 196608);
    cast_kernel<<<dim3(196608 / 8 / 256), blk, 0, stream>>>(xproj_bw, wxb, 196608);
    cast_kernel<<<dim3(131072 / 8 / 256), blk, 0, stream>>>(dtproj_w, dtw_bf, 131072);
    cast_kernel<<<dim3(131072 / 8 / 256), blk, 0, stream>>>(dtproj_bw, dtw_bf + 131072, 131072);

    // G1: xz = hidden @ in_proj_w.T   (M=2048, N=4096, K=1024) bf16 MFMA
    gemm_bf16<0><<<dim3(4096 / 128, MROWS / 128), blk, 0, stream>>>(
        hbf, wbf, xz, 4096, 1024, 1024, 1024, 4096);

    // conv both dirs (fp32 + bf16 outputs)
    conv_kernel<<<dim3(2 * BB * LL * DINNER / 256), blk, 0, stream>>>(
        xz, conv_w, conv_b, conv_bw, conv_bb, xc_f, xc_b, xcbf, xcbb);

    // G2 via bf16 MFMA split-K
    g2_mfma<<<dim3(16, G2KS, 2), blk, 0, stream>>>(
        xcbf, xcbb, wxf, wxb, g2part);
    g2_reduce<<<dim3(2 * 2048 * 96 / 256), blk, 0, stream>>>(
        g2part, xdbl_f, xdbl_b, xdbl_bf);

    // G3 via bf16 MFMA (both dirs)
    g3_mfma<<<dim3(16, 16, 2), blk, 0, stream>>>(
        xdbl_bf, dtw_bf, dtproj_b, dtproj_bb, dl_f, dl_b);

    // chunked scan
    scan1_kernel<<<dim3(DINNER / 256, SNC, 8), blk, 0, stream>>>(
        A_log, A_b_log, xdbl_f, xdbl_b, xc_f, xc_b, dl_f, dl_b, sdel, hend);
    scan_combine<<<dim3(2 * BB * DINNER / 256), blk, 0, stream>>>(
        A_log, A_b_log, sdel, hend, hin);
    scan2_kernel<<<dim3(DINNER / 256, SNC, 8), blk, 0, stream>>>(
        A_log, A_b_log, Dvec, D_b, xdbl_f, xdbl_b, xc_f, xc_b, hin, dl_f, dl_b);

    // gate -> bf16 ytot (into dead xc_f region)
    gate_kernel<<<dim3(BB * LL * DINNER / 256), blk, 0, stream>>>(
        dl_f, dl_b, xz, ytot_bf);

    // cast out_proj_w (xc_b dead after scan)
    cast_kernel<<<dim3(2097152 / 8 / 256), blk, 0, stream>>>(out_pw, obf, 2097152);

    // G4: out = ytot @ out_proj_w.T  bf16 MFMA + nan_to_num
    gemm_bf16<2><<<dim3(DMODEL / 128, MROWS / 128), blk, 0, stream>>>(
        ytot_bf, obf, out, 1024, 2048, 2048, 2048, 1024);
}

// Round 8
// 270.299 us; speedup vs baseline: 8.2231x; 1.1221x over previous
//
#include <hip/hip_runtime.h>
#include <hip/hip_bf16.h>
#include <math.h>

// Problem constants
#define BB 4
#define LL 512
#define DMODEL 1024
#define DSTATE 16
#define DCONV 4
#define DINNER 2048
#define DTRANK 64
#define MROWS (BB*LL)          // 2048 rows of (b,l)
#define G2KS 4                 // split-K factor for the N=96 GEMM
#define SCHUNK 64              // scan chunk length
#define SNC (LL / SCHUNK)      // 8 chunks

typedef __hip_bfloat16 bf16;
typedef __attribute__((ext_vector_type(8))) short short8;
typedef __attribute__((ext_vector_type(4))) float f32x4;

__device__ __forceinline__ float softplusf(float x) {
    return x > 20.f ? x : log1pf(__expf(x));
}

// ---------------------------------------------------------------------------
// bf16 MFMA TN GEMM: C[M][N](f32) = A[M][K](bf16) * W[N][K](bf16)^T
// 128x128 tile, 4 waves, 4x4 16x16x32 frags. EPI 0: none; 2: nan_to_num.
// ---------------------------------------------------------------------------
template<int EPI>
__global__ __launch_bounds__(256) void gemm_bf16(
    const bf16* __restrict__ A, const bf16* __restrict__ W,
    float* __restrict__ C, int N, int K, int lda, int ldw, int ldc)
{
    __shared__ bf16 lA[128 * 40];
    __shared__ bf16 lW[128 * 40];

    const int tid = threadIdx.x;
    const int lane = tid & 63;
    const int wid = tid >> 6;
    const int wr = wid >> 1;
    const int wc = wid & 1;
    const int rowBase = blockIdx.y * 128;
    const int colBase = blockIdx.x * 128;

    const int r16 = lane & 15;
    const int kg = lane >> 4;

    f32x4 acc[4][4];
#pragma unroll
    for (int m = 0; m < 4; ++m)
#pragma unroll
        for (int n = 0; n < 4; ++n) acc[m][n] = (f32x4)0.f;

    const int srow = tid >> 2;
    const int scol = (tid & 3) * 8;

    for (int k0 = 0; k0 < K; k0 += 32) {
#pragma unroll
        for (int it = 0; it < 2; ++it) {
            int r = srow + it * 64;
            short8 va = *(const short8*)&A[(size_t)(rowBase + r) * lda + k0 + scol];
            short8 vw = *(const short8*)&W[(size_t)(colBase + r) * ldw + k0 + scol];
            *(short8*)&lA[r * 40 + scol] = va;
            *(short8*)&lW[r * 40 + scol] = vw;
        }
        __syncthreads();

        short8 a[4], b[4];
#pragma unroll
        for (int m = 0; m < 4; ++m)
            a[m] = *(const short8*)&lA[(wr * 64 + m * 16 + r16) * 40 + kg * 8];
#pragma unroll
        for (int n = 0; n < 4; ++n)
            b[n] = *(const short8*)&lW[(wc * 64 + n * 16 + r16) * 40 + kg * 8];
#pragma unroll
        for (int m = 0; m < 4; ++m)
#pragma unroll
            for (int n = 0; n < 4; ++n)
                acc[m][n] = __builtin_amdgcn_mfma_f32_16x16x32_bf16(
                    a[m], b[n], acc[m][n], 0, 0, 0);
        __syncthreads();
    }

#pragma unroll
    for (int m = 0; m < 4; ++m) {
#pragma unroll
        for (int n = 0; n < 4; ++n) {
            int gc = colBase + wc * 64 + n * 16 + r16;
#pragma unroll
            for (int j = 0; j < 4; ++j) {
                int gr = rowBase + wr * 64 + m * 16 + kg * 4 + j;
                float v = acc[m][n][j];
                if (EPI == 2) {
                    if (isnan(v)) v = 0.f;
                    else if (isinf(v)) v = (v > 0.f) ? 1.f : -1.f;
                }
                C[(size_t)gr * ldc + gc] = v;
            }
        }
    }
}

// ---------------------------------------------------------------------------
// G4 split-K: part[kz] = ytot[:, kz*1024:+1024] @ out_pw[:, kz*1024:+1024].T
// M=2048, N=1024, K=1024 per kz. grid (8, 16, 2) = 256 blocks.
// ---------------------------------------------------------------------------
__global__ __launch_bounds__(256) void g4_mfma(
    const bf16* __restrict__ A, const bf16* __restrict__ W,
    float* __restrict__ part)   // [2][2048][1024]
{
    const int kz = blockIdx.z;
    const int kOff = kz * 1024;
    float* C = part + (size_t)kz * 2048 * 1024;

    __shared__ bf16 lA[128 * 40];
    __shared__ bf16 lW[128 * 40];

    const int tid = threadIdx.x;
    const int lane = tid & 63;
    const int wid = tid >> 6;
    const int wr = wid >> 1;
    const int wc = wid & 1;
    const int rowBase = blockIdx.y * 128;
    const int colBase = blockIdx.x * 128;

    const int r16 = lane & 15;
    const int kg = lane >> 4;

    f32x4 acc[4][4];
#pragma unroll
    for (int m = 0; m < 4; ++m)
#pragma unroll
        for (int n = 0; n < 4; ++n) acc[m][n] = (f32x4)0.f;

    const int srow = tid >> 2;
    const int scol = (tid & 3) * 8;

    for (int k0 = 0; k0 < 1024; k0 += 32) {
#pragma unroll
        for (int it = 0; it < 2; ++it) {
            int r = srow + it * 64;
            short8 va = *(const short8*)&A[(size_t)(rowBase + r) * 2048 + kOff + k0 + scol];
            short8 vw = *(const short8*)&W[(size_t)(colBase + r) * 2048 + kOff + k0 + scol];
            *(short8*)&lA[r * 40 + scol] = va;
            *(short8*)&lW[r * 40 + scol] = vw;
        }
        __syncthreads();

        short8 a[4], b[4];
#pragma unroll
        for (int m = 0; m < 4; ++m)
            a[m] = *(const short8*)&lA[(wr * 64 + m * 16 + r16) * 40 + kg * 8];
#pragma unroll
        for (int n = 0; n < 4; ++n)
            b[n] = *(const short8*)&lW[(wc * 64 + n * 16 + r16) * 40 + kg * 8];
#pragma unroll
        for (int m = 0; m < 4; ++m)
#pragma unroll
            for (int n = 0; n < 4; ++n)
                acc[m][n] = __builtin_amdgcn_mfma_f32_16x16x32_bf16(
                    a[m], b[n], acc[m][n], 0, 0, 0);
        __syncthreads();
    }

#pragma unroll
    for (int m = 0; m < 4; ++m) {
#pragma unroll
        for (int n = 0; n < 4; ++n) {
            int gc = colBase + wc * 64 + n * 16 + r16;
#pragma unroll
            for (int j = 0; j < 4; ++j) {
                int gr = rowBase + wr * 64 + m * 16 + kg * 4 + j;
                C[(size_t)gr * 1024 + gc] = acc[m][n][j];
            }
        }
    }
}

// g4_reduce: out = nan_to_num(p0 + p1), vectorized 4/thread
__global__ __launch_bounds__(256) void g4_reduce(
    const float* __restrict__ part, float* __restrict__ out)
{
    int i = (blockIdx.x * 256 + threadIdx.x) * 4;
    float4 p0 = *(const float4*)&part[i];
    float4 p1 = *(const float4*)&part[2048 * 1024 + i];
    float r[4] = { p0.x + p1.x, p0.y + p1.y, p0.z + p1.z, p0.w + p1.w };
#pragma unroll
    for (int j = 0; j < 4; ++j) {
        float v = r[j];
        if (isnan(v)) v = 0.f;
        else if (isinf(v)) v = (v > 0.f) ? 1.f : -1.f;
        r[j] = v;
    }
    *(float4*)&out[i] = *(float4*)r;
}

// ---------------------------------------------------------------------------
// G3 as bf16 MFMA: dl[dir] = softplus(clip(xdbl_bf[dir][:, :64] @ dtw[dir].T
//                  + bias, 1e-5, 1) + bias).   M=2048, N=2048, K=64.
// ---------------------------------------------------------------------------
__global__ __launch_bounds__(256) void g3_mfma(
    const bf16* __restrict__ xdbl_bf,   // [2][2048][96]
    const bf16* __restrict__ dtw_bf,    // [2][2048][64]
    const float* __restrict__ biasf, const float* __restrict__ biasb,
    float* __restrict__ of, float* __restrict__ ob)
{
    const int dir = blockIdx.z;
    const bf16* A = xdbl_bf + (size_t)dir * 2048 * 96;
    const bf16* W = dtw_bf + (size_t)dir * 2048 * 64;
    const float* bias = dir ? biasb : biasf;
    float* C = dir ? ob : of;

    __shared__ bf16 lA[128 * 40];
    __shared__ bf16 lW[128 * 40];

    const int tid = threadIdx.x;
    const int lane = tid & 63;
    const int wid = tid >> 6;
    const int wr = wid >> 1;
    const int wc = wid & 1;
    const int rowBase = blockIdx.y * 128;
    const int colBase = blockIdx.x * 128;

    const int r16 = lane & 15;
    const int kg = lane >> 4;

    f32x4 acc[4][4];
#pragma unroll
    for (int m = 0; m < 4; ++m)
#pragma unroll
        for (int n = 0; n < 4; ++n) acc[m][n] = (f32x4)0.f;

    const int srow = tid >> 2;
    const int scol = (tid & 3) * 8;

#pragma unroll
    for (int k0 = 0; k0 < 64; k0 += 32) {
#pragma unroll
        for (int it = 0; it < 2; ++it) {
            int r = srow + it * 64;
            short8 va = *(const short8*)&A[(size_t)(rowBase + r) * 96 + k0 + scol];
            short8 vw = *(const short8*)&W[(size_t)(colBase + r) * 64 + k0 + scol];
            *(short8*)&lA[r * 40 + scol] = va;
            *(short8*)&lW[r * 40 + scol] = vw;
        }
        __syncthreads();

        short8 a[4], b[4];
#pragma unroll
        for (int m = 0; m < 4; ++m)
            a[m] = *(const short8*)&lA[(wr * 64 + m * 16 + r16) * 40 + kg * 8];
#pragma unroll
        for (int n = 0; n < 4; ++n)
            b[n] = *(const short8*)&lW[(wc * 64 + n * 16 + r16) * 40 + kg * 8];
#pragma unroll
        for (int m = 0; m < 4; ++m)
#pragma unroll
            for (int n = 0; n < 4; ++n)
                acc[m][n] = __builtin_amdgcn_mfma_f32_16x16x32_bf16(
                    a[m], b[n], acc[m][n], 0, 0, 0);
        __syncthreads();
    }

#pragma unroll
    for (int m = 0; m < 4; ++m) {
#pragma unroll
        for (int n = 0; n < 4; ++n) {
            int gc = colBase + wc * 64 + n * 16 + r16;
            float bv = bias[gc];
#pragma unroll
            for (int j = 0; j < 4; ++j) {
                int gr = rowBase + wr * 64 + m * 16 + kg * 4 + j;
                float t = acc[m][n][j] + bv;
                t = fminf(fmaxf(t, 1e-5f), 1.0f);
                C[(size_t)gr * 2048 + gc] = softplusf(t + bv);
            }
        }
    }
}

// ---------------------------------------------------------------------------
// G2 as bf16 MFMA: part[dir][kz] = xcbf[dir][:, kz*512:+512] @ wx[dir].T
// ---------------------------------------------------------------------------
__global__ __launch_bounds__(256) void g2_mfma(
    const bf16* __restrict__ xcbf_f, const bf16* __restrict__ xcbf_b,
    const bf16* __restrict__ wxf, const bf16* __restrict__ wxb,
    float* __restrict__ part)   // [2][G2KS][2048][96]
{
    const int dir = blockIdx.z;
    const bf16* A = dir ? xcbf_b : xcbf_f;
    const bf16* W = dir ? wxb : wxf;
    const int rowBase = blockIdx.x * 128;
    const int kz = blockIdx.y;
    const int kBase = kz * (2048 / G2KS);

    __shared__ bf16 lA[128 * 40];
    __shared__ bf16 lW[96 * 40];

    const int tid = threadIdx.x;
    const int lane = tid & 63;
    const int wid = tid >> 6;
    const int r16 = lane & 15;
    const int kg = lane >> 4;

    f32x4 acc[2][6];
#pragma unroll
    for (int m = 0; m < 2; ++m)
#pragma unroll
        for (int n = 0; n < 6; ++n) acc[m][n] = (f32x4)0.f;

    const int srow = tid >> 2;
    const int scol = (tid & 3) * 8;

    for (int k0 = 0; k0 < 2048 / G2KS; k0 += 32) {
#pragma unroll
        for (int it = 0; it < 2; ++it) {
            int r = srow + it * 64;
            short8 va = *(const short8*)&A[(size_t)(rowBase + r) * 2048 + kBase + k0 + scol];
            *(short8*)&lA[r * 40 + scol] = va;
        }
        {
            short8 vw = *(const short8*)&W[(size_t)srow * 2048 + kBase + k0 + scol];
            *(short8*)&lW[srow * 40 + scol] = vw;
        }
        if (tid < 128) {
            int r = 64 + (tid >> 2);
            short8 vw2 = *(const short8*)&W[(size_t)r * 2048 + kBase + k0 + scol];
            *(short8*)&lW[r * 40 + scol] = vw2;
        }
        __syncthreads();

        short8 a[2], b[6];
#pragma unroll
        for (int m = 0; m < 2; ++m)
            a[m] = *(const short8*)&lA[(wid * 32 + m * 16 + r16) * 40 + kg * 8];
#pragma unroll
        for (int n = 0; n < 6; ++n)
            b[n] = *(const short8*)&lW[(n * 16 + r16) * 40 + kg * 8];
#pragma unroll
        for (int m = 0; m < 2; ++m)
#pragma unroll
            for (int n = 0; n < 6; ++n)
                acc[m][n] = __builtin_amdgcn_mfma_f32_16x16x32_bf16(
                    a[m], b[n], acc[m][n], 0, 0, 0);
        __syncthreads();
    }

    float* p = part + ((size_t)(dir * G2KS + kz) * 2048) * 96;
#pragma unroll
    for (int m = 0; m < 2; ++m) {
#pragma unroll
        for (int n = 0; n < 6; ++n) {
            int gc = n * 16 + r16;
#pragma unroll
            for (int j = 0; j < 4; ++j) {
                int gr = rowBase + wid * 32 + m * 16 + kg * 4 + j;
                p[(size_t)gr * 96 + gc] = acc[m][n][j];
            }
        }
    }
}

// g2_reduce: sum split-K partials -> fp32 xdbl AND bf16 xdbl copy (for g3)
__global__ __launch_bounds__(256) void g2_reduce(
    const float* __restrict__ part, float* __restrict__ xf, float* __restrict__ xb,
    bf16* __restrict__ xdbl_bf)
{
    int idx = blockIdx.x * 256 + threadIdx.x;
    int c = idx % 96;
    int r = (idx / 96) & 2047;
    int dir = idx / (96 * 2048);
    float s = 0.f;
#pragma unroll
    for (int ks = 0; ks < G2KS; ++ks)
        s += part[((size_t)(dir * G2KS + ks) * 2048 + r) * 96 + c];
    (dir ? xb : xf)[(size_t)r * 96 + c] = s;
    xdbl_bf[((size_t)dir * 2048 + r) * 96 + c] = __float2bfloat16(s);
}

// ---------------------------------------------------------------------------
// Fused f32 -> bf16 casts (all pre-G1 weight/activation casts in one launch)
// block ranges: [0,1024) hidden | [1024,3072) in_proj | [3072,3168) xproj_w
// | [3168,3264) xproj_bw | [3264,3328) dtproj_w | [3328,3392) dtproj_bw
// ---------------------------------------------------------------------------
__global__ __launch_bounds__(256) void cast_all(
    const float* __restrict__ hidden, const float* __restrict__ in_proj_w,
    const float* __restrict__ xproj_w, const float* __restrict__ xproj_bw,
    const float* __restrict__ dtproj_w, const float* __restrict__ dtproj_bw,
    bf16* __restrict__ hbf, bf16* __restrict__ wbf,
    bf16* __restrict__ wxf, bf16* __restrict__ wxb,
    bf16* __restrict__ dtwf, bf16* __restrict__ dtwb)
{
    int bid = blockIdx.x;
    const float* src; bf16* dst; int base;
    if (bid < 1024)      { src = hidden;    dst = hbf;  base = bid; }
    else if (bid < 3072) { src = in_proj_w; dst = wbf;  base = bid - 1024; }
    else if (bid < 3168) { src = xproj_w;   dst = wxf;  base = bid - 3072; }
    else if (bid < 3264) { src = xproj_bw;  dst = wxb;  base = bid - 3168; }
    else if (bid < 3328) { src = dtproj_w;  dst = dtwf; base = bid - 3264; }
    else                 { src = dtproj_bw; dst = dtwb; base = bid - 3328; }
    int i = (base * 256 + threadIdx.x) * 8;
    float4 x = *(const float4*)&src[i];
    float4 y = *(const float4*)&src[i + 4];
    bf16 t[8] = { __float2bfloat16(x.x), __float2bfloat16(x.y),
                  __float2bfloat16(x.z), __float2bfloat16(x.w),
                  __float2bfloat16(y.x), __float2bfloat16(y.y),
                  __float2bfloat16(y.z), __float2bfloat16(y.w) };
    *(short8*)&dst[i] = *(short8*)t;
}

// single cast (for out_proj_w, must run after scan frees xc_b)
__global__ __launch_bounds__(256) void cast_kernel(
    const float* __restrict__ in, bf16* __restrict__ out, int n)
{
    int i = (blockIdx.x * 256 + threadIdx.x) * 8;
    if (i >= n) return;
    float4 x = *(const float4*)&in[i];
    float4 y = *(const float4*)&in[i + 4];
    bf16 t[8] = { __float2bfloat16(x.x), __float2bfloat16(x.y),
                  __float2bfloat16(x.z), __float2bfloat16(x.w),
                  __float2bfloat16(y.x), __float2bfloat16(y.y),
                  __float2bfloat16(y.z), __float2bfloat16(y.w) };
    *(short8*)&out[i] = *(short8*)t;
}

// ---------------------------------------------------------------------------
// Depthwise causal conv1d, both directions. Also emits bf16 copy for G2.
// ---------------------------------------------------------------------------
__global__ __launch_bounds__(256) void conv_kernel(
    const float* __restrict__ xz,
    const float* __restrict__ wf, const float* __restrict__ bf,
    const float* __restrict__ wb, const float* __restrict__ bb,
    float* __restrict__ xcf, float* __restrict__ xcb,
    bf16* __restrict__ xcbf, bf16* __restrict__ xcbb)
{
    int idx = blockIdx.x * 256 + threadIdx.x;
    int d = idx & (DINNER - 1);
    int rest = idx >> 11;
    int l = rest & (LL - 1);
    int b = (rest >> 9) & (BB - 1);
    int dir = rest >> 11;

    const float* w = dir ? wb : wf;
    float accv = (dir ? bb : bf)[d];
#pragma unroll
    for (int k = 0; k < DCONV; ++k) {
        int j = l - (DCONV - 1) + k;
        if (j >= 0) {
            int jj = dir ? (LL - 1 - j) : j;
            accv += w[d * DCONV + k] * xz[((size_t)(b * LL + jj)) * (2 * DINNER) + d];
        }
    }
    size_t off = ((size_t)(b * LL + l)) * DINNER + d;
    (dir ? xcb : xcf)[off] = accv;
    (dir ? xcbb : xcbf)[off] = __float2bfloat16(accv);
}

// ---------------------------------------------------------------------------
// Chunked scan phase 1
// ---------------------------------------------------------------------------
__global__ __launch_bounds__(256) void scan1_kernel(
    const float* __restrict__ Alog_f, const float* __restrict__ Alog_b,
    const float* __restrict__ xdbl_f, const float* __restrict__ xdbl_b,
    const float* __restrict__ xc_f, const float* __restrict__ xc_b,
    const float* __restrict__ dl_f, const float* __restrict__ dl_b,
    float* __restrict__ sdel, float* __restrict__ hend)
{
    const int tid = threadIdx.x;
    const int d = blockIdx.x * 256 + tid;
    const int c = blockIdx.y;
    const int z = blockIdx.z;           // dir*4 + b
    const int dir = z >> 2, b = z & 3;

    const float* Alog = dir ? Alog_b : Alog_f;
    const float* xdbl = dir ? xdbl_b : xdbl_f;
    const float* xc   = dir ? xc_b   : xc_f;
    const float* dl   = dir ? dl_b   : dl_f;
    const int rowBase = b * LL + c * SCHUNK;

    __shared__ float bs[SCHUNK][16];
#pragma unroll
    for (int i = 0; i < SCHUNK * 16 / 256; ++i) {
        int e = tid + 256 * i;
        int r = e >> 4, n = e & 15;
        bs[r][n] = xdbl[(size_t)(rowBase + r) * 96 + DTRANK + n];
    }
    __syncthreads();

    float Aa[DSTATE], h[DSTATE];
#pragma unroll
    for (int n = 0; n < DSTATE; ++n) {
        Aa[n] = -__expf(Alog[d * DSTATE + n]);
        h[n] = 0.f;
    }
    float sd = 0.f;

    for (int t = 0; t < SCHUNK; ++t) {
        size_t row = (size_t)(rowBase + t);
        float delta = dl[row * DINNER + d];
        float u = xc[row * DINNER + d];
        u = fminf(fmaxf(u, -10.f), 10.f);
        float du = delta * u;
        sd += delta;
#pragma unroll
        for (int n = 0; n < DSTATE; ++n)
            h[n] = __expf(delta * Aa[n]) * h[n] + du * bs[t][n];
    }

    size_t base = (size_t)z * SNC + c;
    sdel[base * DINNER + d] = sd;
#pragma unroll
    for (int n = 0; n < DSTATE; ++n)
        hend[(base * DSTATE + n) * DINNER + d] = h[n];
}

// ---------------------------------------------------------------------------
// Combine: sequential over chunks
// ---------------------------------------------------------------------------
__global__ __launch_bounds__(256) void scan_combine(
    const float* __restrict__ Alog_f, const float* __restrict__ Alog_b,
    const float* __restrict__ sdel, const float* __restrict__ hend,
    float* __restrict__ hin)
{
    int g = blockIdx.x * 256 + threadIdx.x;
    int d = g & (DINNER - 1);
    int z = g >> 11;
    int dir = z >> 2;
    const float* Alog = dir ? Alog_b : Alog_f;

    float Aa[DSTATE], hr[DSTATE];
#pragma unroll
    for (int n = 0; n < DSTATE; ++n) {
        Aa[n] = -__expf(Alog[d * DSTATE + n]);
        hr[n] = 0.f;
    }
    for (int c = 0; c < SNC; ++c) {
        size_t base = (size_t)z * SNC + c;
#pragma unroll
        for (int n = 0; n < DSTATE; ++n)
            hin[(base * DSTATE + n) * DINNER + d] = hr[n];
        float sd = sdel[base * DINNER + d];
#pragma unroll
        for (int n = 0; n < DSTATE; ++n)
            hr[n] = __expf(sd * Aa[n]) * hr[n] + hend[(base * DSTATE + n) * DINNER + d];
    }
}

// ---------------------------------------------------------------------------
// Chunked scan phase 2
// ---------------------------------------------------------------------------
__global__ __launch_bounds__(256) void scan2_kernel(
    const float* __restrict__ Alog_f, const float* __restrict__ Alog_b,
    const float* __restrict__ Df, const float* __restrict__ Db,
    const float* __restrict__ xdbl_f, const float* __restrict__ xdbl_b,
    const float* __restrict__ xc_f, const float* __restrict__ xc_b,
    const float* __restrict__ hin,
    float* __restrict__ dl_f, float* __restrict__ dl_b)
{
    const int tid = threadIdx.x;
    const int d = blockIdx.x * 256 + tid;
    const int c = blockIdx.y;
    const int z = blockIdx.z;
    const int dir = z >> 2, b = z & 3;

    const float* Alog = dir ? Alog_b : Alog_f;
    const float* xdbl = dir ? xdbl_b : xdbl_f;
    const float* xc   = dir ? xc_b   : xc_f;
    float* dl         = dir ? dl_b   : dl_f;
    const int rowBase = b * LL + c * SCHUNK;

    __shared__ float bs[SCHUNK][32];
#pragma unroll
    for (int i = 0; i < SCHUNK * 32 / 256; ++i) {
        int e = tid + 256 * i;
        int r = e >> 5, n = e & 31;
        bs[r][n] = xdbl[(size_t)(rowBase + r) * 96 + DTRANK + n];
    }
    __syncthreads();

    float Dv = (dir ? Db : Df)[d];
    size_t base = (size_t)z * SNC + c;
    float Aa[DSTATE], h[DSTATE];
#pragma unroll
    for (int n = 0; n < DSTATE; ++n) {
        Aa[n] = -__expf(Alog[d * DSTATE + n]);
        h[n] = hin[(base * DSTATE + n) * DINNER + d];
    }

    for (int t = 0; t < SCHUNK; ++t) {
        size_t row = (size_t)(rowBase + t);
        float delta = dl[row * DINNER + d];
        float u = xc[row * DINNER + d];
        u = fminf(fmaxf(u, -10.f), 10.f);
        float du = delta * u;
        float y = 0.f;
#pragma unroll
        for (int n = 0; n < DSTATE; ++n) {
            h[n] = __expf(delta * Aa[n]) * h[n] + du * bs[t][n];
            y += h[n] * bs[t][DSTATE + n];
        }
        dl[row * DINNER + d] = y + u * Dv;
    }
}

// ---------------------------------------------------------------------------
// Gate: ytot = (y_f + y_b_rev) * silu(z), written as bf16 for G4
// ---------------------------------------------------------------------------
__global__ __launch_bounds__(256) void gate_kernel(
    const float* __restrict__ yf, const float* __restrict__ yb,
    const float* __restrict__ xz, bf16* __restrict__ ytot)
{
    int idx = blockIdx.x * 256 + threadIdx.x;
    int d = idx & (DINNER - 1);
    int l = (idx >> 11) & (LL - 1);
    int b = idx >> 20;
    size_t rowf = (size_t)(b * LL + l);
    size_t rowb = (size_t)(b * LL + (LL - 1 - l));
    float y = yf[rowf * DINNER + d] + yb[rowb * DINNER + d];
    float z = xz[rowf * (2 * DINNER) + DINNER + d];
    float s = z / (1.f + __expf(-z));
    ytot[rowf * DINNER + d] = __float2bfloat16(y * s);
}

// ---------------------------------------------------------------------------
extern "C" void kernel_launch(void* const* d_in, const int* in_sizes, int n_in,
                              void* d_out, int out_size, void* d_ws, size_t ws_size,
                              hipStream_t stream)
{
    const float* hidden    = (const float*)d_in[0];
    const float* in_proj_w = (const float*)d_in[1];
    const float* conv_w    = (const float*)d_in[2];
    const float* conv_b    = (const float*)d_in[3];
    const float* xproj_w   = (const float*)d_in[4];
    const float* dtproj_w  = (const float*)d_in[5];
    const float* dtproj_b  = (const float*)d_in[6];
    const float* A_log     = (const float*)d_in[7];
    const float* Dvec      = (const float*)d_in[8];
    const float* conv_bw   = (const float*)d_in[9];
    const float* conv_bb   = (const float*)d_in[10];
    const float* xproj_bw  = (const float*)d_in[11];
    const float* dtproj_bw = (const float*)d_in[12];
    const float* dtproj_bb = (const float*)d_in[13];
    const float* A_b_log   = (const float*)d_in[14];
    const float* D_b       = (const float*)d_in[15];
    const float* out_pw    = (const float*)d_in[16];
    float* out = (float*)d_out;

    float* ws = (float*)d_ws;
    float* xz     = ws;                      // 8388608 f32
    float* xc_f   = xz + 8388608;            // 4194304
    float* xc_b   = xc_f + 4194304;          // 4194304
    float* xdbl_f = xc_b + 4194304;          // 196608
    float* xdbl_b = xdbl_f + 196608;         // 196608
    float* dl_f   = xdbl_b + 196608;         // 4194304 (delta -> y)
    float* dl_b   = dl_f + 4194304;          // 4194304
    float* g2part = dl_b + 4194304;          // 1572864
    float* sdel   = g2part + 1572864;        // 131072
    float* hend   = sdel + 131072;           // 2097152
    float* hin    = hend + 2097152;          // 2097152
    // total 31,457,280 floats = 125.8 MB

    // bf16 aliases over regions dead at time of use (liveness audited R6):
    bf16* hbf = (bf16*)dl_f;                 // pre-G1; dl_f written by g3
    bf16* wbf = (bf16*)(dl_f + 1048576);
    bf16* wxf = (bf16*)dl_b;                 // consumed by g2_mfma; dl_b written by g3
    bf16* wxb = (bf16*)(dl_b + 98304);
    bf16* xcbf = (bf16*)hend;                // conv->g2_mfma; hend written by scan1
    bf16* xcbb = (bf16*)hin;                 // hin written by scan_combine
    bf16* xdbl_bf = (bf16*)(hend + 1048576); // g2_reduce->g3 (xcbf 2nd half dead post-g2_mfma)
    bf16* dtw_bf  = (bf16*)sdel;             // cast_all->g3; sdel first written by scan1
    bf16* ytot_bf = (bf16*)xc_f;             // post-scan (xc dead)
    bf16* obf = (bf16*)xc_b;
    float* g4part = dl_f;                    // G4 split-K partials: dl dead after gate;
                                             // 2*2048*1024 = 4194304 = exactly dl_f size

    dim3 blk(256);

    // all pre-G1 casts in one launch
    cast_all<<<dim3(3392), blk, 0, stream>>>(
        hidden, in_proj_w, xproj_w, xproj_bw, dtproj_w, dtproj_bw,
        hbf, wbf, wxf, wxb, dtw_bf, dtw_bf + 131072);

    // G1: xz = hidden @ in_proj_w.T   (M=2048, N=4096, K=1024) bf16 MFMA
    gemm_bf16<0><<<dim3(4096 / 128, MROWS / 128), blk, 0, stream>>>(
        hbf, wbf, xz, 4096, 1024, 1024, 1024, 4096);

    // conv both dirs (fp32 + bf16 outputs)
    conv_kernel<<<dim3(2 * BB * LL * DINNER / 256), blk, 0, stream>>>(
        xz, conv_w, conv_b, conv_bw, conv_bb, xc_f, xc_b, xcbf, xcbb);

    // G2 via bf16 MFMA split-K
    g2_mfma<<<dim3(16, G2KS, 2), blk, 0, stream>>>(
        xcbf, xcbb, wxf, wxb, g2part);
    g2_reduce<<<dim3(2 * 2048 * 96 / 256), blk, 0, stream>>>(
        g2part, xdbl_f, xdbl_b, xdbl_bf);

    // G3 via bf16 MFMA (both dirs)
    g3_mfma<<<dim3(16, 16, 2), blk, 0, stream>>>(
        xdbl_bf, dtw_bf, dtproj_b, dtproj_bb, dl_f, dl_b);

    // chunked scan
    scan1_kernel<<<dim3(DINNER / 256, SNC, 8), blk, 0, stream>>>(
        A_log, A_b_log, xdbl_f, xdbl_b, xc_f, xc_b, dl_f, dl_b, sdel, hend);
    scan_combine<<<dim3(2 * BB * DINNER / 256), blk, 0, stream>>>(
        A_log, A_b_log, sdel, hend, hin);
    scan2_kernel<<<dim3(DINNER / 256, SNC, 8), blk, 0, stream>>>(
        A_log, A_b_log, Dvec, D_b, xdbl_f, xdbl_b, xc_f, xc_b, hin, dl_f, dl_b);

    // gate -> bf16 ytot (into dead xc_f region)
    gate_kernel<<<dim3(BB * LL * DINNER / 256), blk, 0, stream>>>(
        dl_f, dl_b, xz, ytot_bf);

    // cast out_proj_w (xc_b dead after scan)
    cast_kernel<<<dim3(2097152 / 8 / 256), blk, 0, stream>>>(out_pw, obf, 2097152);

    // G4 split-K=2: partials into dead dl region, then fused reduce+nan_to_num
    g4_mfma<<<dim3(1024 / 128, MROWS / 128, 2), blk, 0, stream>>>(
        ytot_bf, obf, g4part);
    g4_reduce<<<dim3(2048 * 1024 / 4 / 256), blk, 0, stream>>>(g4part, out);
}

// Round 10
// 249.012 us; speedup vs baseline: 8.9260x; 1.0855x over previous
//
#include <hip/hip_runtime.h>
#include <hip/hip_bf16.h>
#include <math.h>

// Problem constants
#define BB 4
#define LL 512
#define DMODEL 1024
#define DSTATE 16
#define DCONV 4
#define DINNER 2048
#define DTRANK 64
#define MROWS (BB*LL)          // 2048 rows of (b,l)
#define G2KS 4                 // split-K factor for the N=96 GEMM
#define SCHUNK 32              // scan chunk length
#define SNC (LL / SCHUNK)      // 16 chunks

typedef __hip_bfloat16 bf16;
typedef __attribute__((ext_vector_type(8))) short short8;
typedef __attribute__((ext_vector_type(4))) float f32x4;

__device__ __forceinline__ float softplusf(float x) {
    return x > 20.f ? x : log1pf(__expf(x));
}

// ---------------------------------------------------------------------------
// bf16 MFMA TN GEMM: C[M][N](f32) = A[M][K](bf16) * W[N][K](bf16)^T
// ---------------------------------------------------------------------------
template<int EPI>
__global__ __launch_bounds__(256) void gemm_bf16(
    const bf16* __restrict__ A, const bf16* __restrict__ W,
    float* __restrict__ C, int N, int K, int lda, int ldw, int ldc)
{
    __shared__ bf16 lA[128 * 40];
    __shared__ bf16 lW[128 * 40];

    const int tid = threadIdx.x;
    const int lane = tid & 63;
    const int wid = tid >> 6;
    const int wr = wid >> 1;
    const int wc = wid & 1;
    const int rowBase = blockIdx.y * 128;
    const int colBase = blockIdx.x * 128;

    const int r16 = lane & 15;
    const int kg = lane >> 4;

    f32x4 acc[4][4];
#pragma unroll
    for (int m = 0; m < 4; ++m)
#pragma unroll
        for (int n = 0; n < 4; ++n) acc[m][n] = (f32x4)0.f;

    const int srow = tid >> 2;
    const int scol = (tid & 3) * 8;

    for (int k0 = 0; k0 < K; k0 += 32) {
#pragma unroll
        for (int it = 0; it < 2; ++it) {
            int r = srow + it * 64;
            short8 va = *(const short8*)&A[(size_t)(rowBase + r) * lda + k0 + scol];
            short8 vw = *(const short8*)&W[(size_t)(colBase + r) * ldw + k0 + scol];
            *(short8*)&lA[r * 40 + scol] = va;
            *(short8*)&lW[r * 40 + scol] = vw;
        }
        __syncthreads();

        short8 a[4], b[4];
#pragma unroll
        for (int m = 0; m < 4; ++m)
            a[m] = *(const short8*)&lA[(wr * 64 + m * 16 + r16) * 40 + kg * 8];
#pragma unroll
        for (int n = 0; n < 4; ++n)
            b[n] = *(const short8*)&lW[(wc * 64 + n * 16 + r16) * 40 + kg * 8];
#pragma unroll
        for (int m = 0; m < 4; ++m)
#pragma unroll
            for (int n = 0; n < 4; ++n)
                acc[m][n] = __builtin_amdgcn_mfma_f32_16x16x32_bf16(
                    a[m], b[n], acc[m][n], 0, 0, 0);
        __syncthreads();
    }

#pragma unroll
    for (int m = 0; m < 4; ++m) {
#pragma unroll
        for (int n = 0; n < 4; ++n) {
            int gc = colBase + wc * 64 + n * 16 + r16;
#pragma unroll
            for (int j = 0; j < 4; ++j) {
                int gr = rowBase + wr * 64 + m * 16 + kg * 4 + j;
                float v = acc[m][n][j];
                if (EPI == 2) {
                    if (isnan(v)) v = 0.f;
                    else if (isinf(v)) v = (v > 0.f) ? 1.f : -1.f;
                }
                C[(size_t)gr * ldc + gc] = v;
            }
        }
    }
}

// ---------------------------------------------------------------------------
// G4 split-K: part[kz] = ytot[:, kz*1024:+1024] @ out_pw[:, kz*1024:+1024].T
// ---------------------------------------------------------------------------
__global__ __launch_bounds__(256) void g4_mfma(
    const bf16* __restrict__ A, const bf16* __restrict__ W,
    float* __restrict__ part)   // [2][2048][1024]
{
    const int kz = blockIdx.z;
    const int kOff = kz * 1024;
    float* C = part + (size_t)kz * 2048 * 1024;

    __shared__ bf16 lA[128 * 40];
    __shared__ bf16 lW[128 * 40];

    const int tid = threadIdx.x;
    const int lane = tid & 63;
    const int wid = tid >> 6;
    const int wr = wid >> 1;
    const int wc = wid & 1;
    const int rowBase = blockIdx.y * 128;
    const int colBase = blockIdx.x * 128;

    const int r16 = lane & 15;
    const int kg = lane >> 4;

    f32x4 acc[4][4];
#pragma unroll
    for (int m = 0; m < 4; ++m)
#pragma unroll
        for (int n = 0; n < 4; ++n) acc[m][n] = (f32x4)0.f;

    const int srow = tid >> 2;
    const int scol = (tid & 3) * 8;

    for (int k0 = 0; k0 < 1024; k0 += 32) {
#pragma unroll
        for (int it = 0; it < 2; ++it) {
            int r = srow + it * 64;
            short8 va = *(const short8*)&A[(size_t)(rowBase + r) * 2048 + kOff + k0 + scol];
            short8 vw = *(const short8*)&W[(size_t)(colBase + r) * 2048 + kOff + k0 + scol];
            *(short8*)&lA[r * 40 + scol] = va;
            *(short8*)&lW[r * 40 + scol] = vw;
        }
        __syncthreads();

        short8 a[4], b[4];
#pragma unroll
        for (int m = 0; m < 4; ++m)
            a[m] = *(const short8*)&lA[(wr * 64 + m * 16 + r16) * 40 + kg * 8];
#pragma unroll
        for (int n = 0; n < 4; ++n)
            b[n] = *(const short8*)&lW[(wc * 64 + n * 16 + r16) * 40 + kg * 8];
#pragma unroll
        for (int m = 0; m < 4; ++m)
#pragma unroll
            for (int n = 0; n < 4; ++n)
                acc[m][n] = __builtin_amdgcn_mfma_f32_16x16x32_bf16(
                    a[m], b[n], acc[m][n], 0, 0, 0);
        __syncthreads();
    }

#pragma unroll
    for (int m = 0; m < 4; ++m) {
#pragma unroll
        for (int n = 0; n < 4; ++n) {
            int gc = colBase + wc * 64 + n * 16 + r16;
#pragma unroll
            for (int j = 0; j < 4; ++j) {
                int gr = rowBase + wr * 64 + m * 16 + kg * 4 + j;
                C[(size_t)gr * 1024 + gc] = acc[m][n][j];
            }
        }
    }
}

// g4_reduce: out = nan_to_num(p0 + p1)
__global__ __launch_bounds__(256) void g4_reduce(
    const float* __restrict__ part, float* __restrict__ out)
{
    int i = (blockIdx.x * 256 + threadIdx.x) * 4;
    float4 p0 = *(const float4*)&part[i];
    float4 p1 = *(const float4*)&part[2048 * 1024 + i];
    float r[4] = { p0.x + p1.x, p0.y + p1.y, p0.z + p1.z, p0.w + p1.w };
#pragma unroll
    for (int j = 0; j < 4; ++j) {
        float v = r[j];
        if (isnan(v)) v = 0.f;
        else if (isinf(v)) v = (v > 0.f) ? 1.f : -1.f;
        r[j] = v;
    }
    *(float4*)&out[i] = *(float4*)r;
}

// ---------------------------------------------------------------------------
// G3 as bf16 MFMA + dt epilogue.
// ---------------------------------------------------------------------------
__global__ __launch_bounds__(256) void g3_mfma(
    const bf16* __restrict__ xdbl_bf,   // [2][2048][96]
    const bf16* __restrict__ dtw_bf,    // [2][2048][64]
    const float* __restrict__ biasf, const float* __restrict__ biasb,
    float* __restrict__ of, float* __restrict__ ob)
{
    const int dir = blockIdx.z;
    const bf16* A = xdbl_bf + (size_t)dir * 2048 * 96;
    const bf16* W = dtw_bf + (size_t)dir * 2048 * 64;
    const float* bias = dir ? biasb : biasf;
    float* C = dir ? ob : of;

    __shared__ bf16 lA[128 * 40];
    __shared__ bf16 lW[128 * 40];

    const int tid = threadIdx.x;
    const int lane = tid & 63;
    const int wid = tid >> 6;
    const int wr = wid >> 1;
    const int wc = wid & 1;
    const int rowBase = blockIdx.y * 128;
    const int colBase = blockIdx.x * 128;

    const int r16 = lane & 15;
    const int kg = lane >> 4;

    f32x4 acc[4][4];
#pragma unroll
    for (int m = 0; m < 4; ++m)
#pragma unroll
        for (int n = 0; n < 4; ++n) acc[m][n] = (f32x4)0.f;

    const int srow = tid >> 2;
    const int scol = (tid & 3) * 8;

#pragma unroll
    for (int k0 = 0; k0 < 64; k0 += 32) {
#pragma unroll
        for (int it = 0; it < 2; ++it) {
            int r = srow + it * 64;
            short8 va = *(const short8*)&A[(size_t)(rowBase + r) * 96 + k0 + scol];
            short8 vw = *(const short8*)&W[(size_t)(colBase + r) * 64 + k0 + scol];
            *(short8*)&lA[r * 40 + scol] = va;
            *(short8*)&lW[r * 40 + scol] = vw;
        }
        __syncthreads();

        short8 a[4], b[4];
#pragma unroll
        for (int m = 0; m < 4; ++m)
            a[m] = *(const short8*)&lA[(wr * 64 + m * 16 + r16) * 40 + kg * 8];
#pragma unroll
        for (int n = 0; n < 4; ++n)
            b[n] = *(const short8*)&lW[(wc * 64 + n * 16 + r16) * 40 + kg * 8];
#pragma unroll
        for (int m = 0; m < 4; ++m)
#pragma unroll
            for (int n = 0; n < 4; ++n)
                acc[m][n] = __builtin_amdgcn_mfma_f32_16x16x32_bf16(
                    a[m], b[n], acc[m][n], 0, 0, 0);
        __syncthreads();
    }

#pragma unroll
    for (int m = 0; m < 4; ++m) {
#pragma unroll
        for (int n = 0; n < 4; ++n) {
            int gc = colBase + wc * 64 + n * 16 + r16;
            float bv = bias[gc];
#pragma unroll
            for (int j = 0; j < 4; ++j) {
                int gr = rowBase + wr * 64 + m * 16 + kg * 4 + j;
                float t = acc[m][n][j] + bv;
                t = fminf(fmaxf(t, 1e-5f), 1.0f);
                C[(size_t)gr * 2048 + gc] = softplusf(t + bv);
            }
        }
    }
}

// ---------------------------------------------------------------------------
// G2 as bf16 MFMA split-K
// ---------------------------------------------------------------------------
__global__ __launch_bounds__(256) void g2_mfma(
    const bf16* __restrict__ xcbf_f, const bf16* __restrict__ xcbf_b,
    const bf16* __restrict__ wxf, const bf16* __restrict__ wxb,
    float* __restrict__ part)   // [2][G2KS][2048][96]
{
    const int dir = blockIdx.z;
    const bf16* A = dir ? xcbf_b : xcbf_f;
    const bf16* W = dir ? wxb : wxf;
    const int rowBase = blockIdx.x * 128;
    const int kz = blockIdx.y;
    const int kBase = kz * (2048 / G2KS);

    __shared__ bf16 lA[128 * 40];
    __shared__ bf16 lW[96 * 40];

    const int tid = threadIdx.x;
    const int lane = tid & 63;
    const int wid = tid >> 6;
    const int r16 = lane & 15;
    const int kg = lane >> 4;

    f32x4 acc[2][6];
#pragma unroll
    for (int m = 0; m < 2; ++m)
#pragma unroll
        for (int n = 0; n < 6; ++n) acc[m][n] = (f32x4)0.f;

    const int srow = tid >> 2;
    const int scol = (tid & 3) * 8;

    for (int k0 = 0; k0 < 2048 / G2KS; k0 += 32) {
#pragma unroll
        for (int it = 0; it < 2; ++it) {
            int r = srow + it * 64;
            short8 va = *(const short8*)&A[(size_t)(rowBase + r) * 2048 + kBase + k0 + scol];
            *(short8*)&lA[r * 40 + scol] = va;
        }
        {
            short8 vw = *(const short8*)&W[(size_t)srow * 2048 + kBase + k0 + scol];
            *(short8*)&lW[srow * 40 + scol] = vw;
        }
        if (tid < 128) {
            int r = 64 + (tid >> 2);
            short8 vw2 = *(const short8*)&W[(size_t)r * 2048 + kBase + k0 + scol];
            *(short8*)&lW[r * 40 + scol] = vw2;
        }
        __syncthreads();

        short8 a[2], b[6];
#pragma unroll
        for (int m = 0; m < 2; ++m)
            a[m] = *(const short8*)&lA[(wid * 32 + m * 16 + r16) * 40 + kg * 8];
#pragma unroll
        for (int n = 0; n < 6; ++n)
            b[n] = *(const short8*)&lW[(n * 16 + r16) * 40 + kg * 8];
#pragma unroll
        for (int m = 0; m < 2; ++m)
#pragma unroll
            for (int n = 0; n < 6; ++n)
                acc[m][n] = __builtin_amdgcn_mfma_f32_16x16x32_bf16(
                    a[m], b[n], acc[m][n], 0, 0, 0);
        __syncthreads();
    }

    float* p = part + ((size_t)(dir * G2KS + kz) * 2048) * 96;
#pragma unroll
    for (int m = 0; m < 2; ++m) {
#pragma unroll
        for (int n = 0; n < 6; ++n) {
            int gc = n * 16 + r16;
#pragma unroll
            for (int j = 0; j < 4; ++j) {
                int gr = rowBase + wid * 32 + m * 16 + kg * 4 + j;
                p[(size_t)gr * 96 + gc] = acc[m][n][j];
            }
        }
    }
}

// g2_reduce: sum split-K partials -> fp32 xdbl AND bf16 xdbl copy (for g3)
__global__ __launch_bounds__(256) void g2_reduce(
    const float* __restrict__ part, float* __restrict__ xf, float* __restrict__ xb,
    bf16* __restrict__ xdbl_bf)
{
    int idx = blockIdx.x * 256 + threadIdx.x;
    int c = idx % 96;
    int r = (idx / 96) & 2047;
    int dir = idx / (96 * 2048);
    float s = 0.f;
#pragma unroll
    for (int ks = 0; ks < G2KS; ++ks)
        s += part[((size_t)(dir * G2KS + ks) * 2048 + r) * 96 + c];
    (dir ? xb : xf)[(size_t)r * 96 + c] = s;
    xdbl_bf[((size_t)dir * 2048 + r) * 96 + c] = __float2bfloat16(s);
}

// ---------------------------------------------------------------------------
// Fused f32 -> bf16 casts (all pre-G1 casts, one launch)
// ---------------------------------------------------------------------------
__global__ __launch_bounds__(256) void cast_all(
    const float* __restrict__ hidden, const float* __restrict__ in_proj_w,
    const float* __restrict__ xproj_w, const float* __restrict__ xproj_bw,
    const float* __restrict__ dtproj_w, const float* __restrict__ dtproj_bw,
    bf16* __restrict__ hbf, bf16* __restrict__ wbf,
    bf16* __restrict__ wxf, bf16* __restrict__ wxb,
    bf16* __restrict__ dtwf, bf16* __restrict__ dtwb)
{
    int bid = blockIdx.x;
    const float* src; bf16* dst; int base;
    if (bid < 1024)      { src = hidden;    dst = hbf;  base = bid; }
    else if (bid < 3072) { src = in_proj_w; dst = wbf;  base = bid - 1024; }
    else if (bid < 3168) { src = xproj_w;   dst = wxf;  base = bid - 3072; }
    else if (bid < 3264) { src = xproj_bw;  dst = wxb;  base = bid - 3168; }
    else if (bid < 3328) { src = dtproj_w;  dst = dtwf; base = bid - 3264; }
    else                 { src = dtproj_bw; dst = dtwb; base = bid - 3328; }
    int i = (base * 256 + threadIdx.x) * 8;
    float4 x = *(const float4*)&src[i];
    float4 y = *(const float4*)&src[i + 4];
    bf16 t[8] = { __float2bfloat16(x.x), __float2bfloat16(x.y),
                  __float2bfloat16(x.z), __float2bfloat16(x.w),
                  __float2bfloat16(y.x), __float2bfloat16(y.y),
                  __float2bfloat16(y.z), __float2bfloat16(y.w) };
    *(short8*)&dst[i] = *(short8*)t;
}

// ---------------------------------------------------------------------------
// Depthwise causal conv1d, both directions. Also emits bf16 copy for G2.
// ---------------------------------------------------------------------------
__global__ __launch_bounds__(256) void conv_kernel(
    const float* __restrict__ xz,
    const float* __restrict__ wf, const float* __restrict__ bf,
    const float* __restrict__ wb, const float* __restrict__ bb,
    float* __restrict__ xcf, float* __restrict__ xcb,
    bf16* __restrict__ xcbf, bf16* __restrict__ xcbb)
{
    int idx = blockIdx.x * 256 + threadIdx.x;
    int d = idx & (DINNER - 1);
    int rest = idx >> 11;
    int l = rest & (LL - 1);
    int b = (rest >> 9) & (BB - 1);
    int dir = rest >> 11;

    const float* w = dir ? wb : wf;
    float accv = (dir ? bb : bf)[d];
#pragma unroll
    for (int k = 0; k < DCONV; ++k) {
        int j = l - (DCONV - 1) + k;
        if (j >= 0) {
            int jj = dir ? (LL - 1 - j) : j;
            accv += w[d * DCONV + k] * xz[((size_t)(b * LL + jj)) * (2 * DINNER) + d];
        }
    }
    size_t off = ((size_t)(b * LL + l)) * DINNER + d;
    (dir ? xcb : xcf)[off] = accv;
    (dir ? xcbb : xcbf)[off] = __float2bfloat16(accv);
}

// ---------------------------------------------------------------------------
// Chunked scan phase 1: local h_end (h0=0) + sum of deltas, with prefetch.
// ---------------------------------------------------------------------------
__global__ __launch_bounds__(256) void scan1_kernel(
    const float* __restrict__ Alog_f, const float* __restrict__ Alog_b,
    const float* __restrict__ xdbl_f, const float* __restrict__ xdbl_b,
    const float* __restrict__ xc_f, const float* __restrict__ xc_b,
    const float* __restrict__ dl_f, const float* __restrict__ dl_b,
    float* __restrict__ sdel, float* __restrict__ hend)
{
    const int tid = threadIdx.x;
    const int d = blockIdx.x * 256 + tid;
    const int c = blockIdx.y;
    const int z = blockIdx.z;           // dir*4 + b
    const int dir = z >> 2, b = z & 3;

    const float* Alog = dir ? Alog_b : Alog_f;
    const float* xdbl = dir ? xdbl_b : xdbl_f;
    const float* xc   = dir ? xc_b   : xc_f;
    const float* dl   = dir ? dl_b   : dl_f;
    const int rowBase = b * LL + c * SCHUNK;

    __shared__ float bs[SCHUNK][16];
#pragma unroll
    for (int i = 0; i < SCHUNK * 16 / 256; ++i) {
        int e = tid + 256 * i;
        int r = e >> 4, n = e & 15;
        bs[r][n] = xdbl[(size_t)(rowBase + r) * 96 + DTRANK + n];
    }
    __syncthreads();

    float Aa[DSTATE], h[DSTATE];
#pragma unroll
    for (int n = 0; n < DSTATE; ++n) {
        Aa[n] = -__expf(Alog[d * DSTATE + n]);
        h[n] = 0.f;
    }
    float sd = 0.f;

    float nxd = dl[(size_t)rowBase * DINNER + d];
    float nxu = xc[(size_t)rowBase * DINNER + d];
#pragma unroll 4
    for (int t = 0; t < SCHUNK; ++t) {
        float delta = nxd, u = nxu;
        if (t + 1 < SCHUNK) {
            size_t nrow = (size_t)(rowBase + t + 1);
            nxd = dl[nrow * DINNER + d];
            nxu = xc[nrow * DINNER + d];
        }
        u = fminf(fmaxf(u, -10.f), 10.f);
        float du = delta * u;
        sd += delta;
#pragma unroll
        for (int n = 0; n < DSTATE; ++n)
            h[n] = __expf(delta * Aa[n]) * h[n] + du * bs[t][n];
    }

    size_t base = (size_t)z * SNC + c;
    sdel[base * DINNER + d] = sd;
#pragma unroll
    for (int n = 0; n < DSTATE; ++n)
        hend[(base * DSTATE + n) * DINNER + d] = h[n];
}

// ---------------------------------------------------------------------------
// Combine (n-parallel, IN PLACE): hend[c] is replaced by h_in[c].
// One thread per (z, d, n): 262144 threads.
// ---------------------------------------------------------------------------
__global__ __launch_bounds__(256) void scan_combine(
    const float* __restrict__ Alog_f, const float* __restrict__ Alog_b,
    const float* __restrict__ sdel, float* __restrict__ hend)
{
    int g = blockIdx.x * 256 + threadIdx.x;
    int d = g & (DINNER - 1);
    int n = (g >> 11) & (DSTATE - 1);
    int z = g >> 15;
    const float* Alog = (z >> 2) ? Alog_b : Alog_f;

    float Aa = -__expf(Alog[d * DSTATE + n]);
    float hr = 0.f;
    for (int c = 0; c < SNC; ++c) {
        size_t base = (size_t)z * SNC + c;
        size_t idx = (base * DSTATE + n) * DINNER + d;
        float he = hend[idx];
        hend[idx] = hr;                     // now holds h_in for chunk c
        float sd = sdel[base * DINNER + d];
        hr = __expf(sd * Aa) * hr + he;
    }
}

// ---------------------------------------------------------------------------
// Chunked scan phase 2: start from h_in (stored in hend), emit y in place.
// ---------------------------------------------------------------------------
__global__ __launch_bounds__(256) void scan2_kernel(
    const float* __restrict__ Alog_f, const float* __restrict__ Alog_b,
    const float* __restrict__ Df, const float* __restrict__ Db,
    const float* __restrict__ xdbl_f, const float* __restrict__ xdbl_b,
    const float* __restrict__ xc_f, const float* __restrict__ xc_b,
    const float* __restrict__ hin,
    float* __restrict__ dl_f, float* __restrict__ dl_b)
{
    const int tid = threadIdx.x;
    const int d = blockIdx.x * 256 + tid;
    const int c = blockIdx.y;
    const int z = blockIdx.z;
    const int dir = z >> 2, b = z & 3;

    const float* Alog = dir ? Alog_b : Alog_f;
    const float* xdbl = dir ? xdbl_b : xdbl_f;
    const float* xc   = dir ? xc_b   : xc_f;
    float* dl         = dir ? dl_b   : dl_f;
    const int rowBase = b * LL + c * SCHUNK;

    __shared__ float bs[SCHUNK][32];
#pragma unroll
    for (int i = 0; i < SCHUNK * 32 / 256; ++i) {
        int e = tid + 256 * i;
        int r = e >> 5, n = e & 31;
        bs[r][n] = xdbl[(size_t)(rowBase + r) * 96 + DTRANK + n];
    }
    __syncthreads();

    float Dv = (dir ? Db : Df)[d];
    size_t base = (size_t)z * SNC + c;
    float Aa[DSTATE], h[DSTATE];
#pragma unroll
    for (int n = 0; n < DSTATE; ++n) {
        Aa[n] = -__expf(Alog[d * DSTATE + n]);
        h[n] = hin[(base * DSTATE + n) * DINNER + d];
    }

    float nxd = dl[(size_t)rowBase * DINNER + d];
    float nxu = xc[(size_t)rowBase * DINNER + d];
#pragma unroll 4
    for (int t = 0; t < SCHUNK; ++t) {
        float delta = nxd, u = nxu;
        if (t + 1 < SCHUNK) {
            size_t nrow = (size_t)(rowBase + t + 1);
            nxd = dl[nrow * DINNER + d];
            nxu = xc[nrow * DINNER + d];
        }
        u = fminf(fmaxf(u, -10.f), 10.f);
        float du = delta * u;
        float y = 0.f;
#pragma unroll
        for (int n = 0; n < DSTATE; ++n) {
            h[n] = __expf(delta * Aa[n]) * h[n] + du * bs[t][n];
            y += h[n] * bs[t][DSTATE + n];
        }
        dl[(size_t)(rowBase + t) * DINNER + d] = y + u * Dv;
    }
}

// ---------------------------------------------------------------------------
// Gate + out_pw cast fused (block-range dispatch):
// blocks [0,16384): ytot = (y_f + y_b_rev) * silu(z) -> bf16  (4,194,304 elems)
// blocks [16384,17408): out_pw -> bf16
// ---------------------------------------------------------------------------
__global__ __launch_bounds__(256) void gate_cast(
    const float* __restrict__ yf, const float* __restrict__ yb,
    const float* __restrict__ xz, bf16* __restrict__ ytot,
    const float* __restrict__ out_pw, bf16* __restrict__ obf)
{
    int bid = blockIdx.x;
    if (bid < 16384) {
        int idx = bid * 256 + threadIdx.x;
        int d = idx & (DINNER - 1);
        int l = (idx >> 11) & (LL - 1);
        int b = idx >> 20;
        size_t rowf = (size_t)(b * LL + l);
        size_t rowb = (size_t)(b * LL + (LL - 1 - l));
        float y = yf[rowf * DINNER + d] + yb[rowb * DINNER + d];
        float z = xz[rowf * (2 * DINNER) + DINNER + d];
        float s = z / (1.f + __expf(-z));
        ytot[rowf * DINNER + d] = __float2bfloat16(y * s);
    } else {
        int i = ((bid - 16384) * 256 + threadIdx.x) * 8;
        float4 x = *(const float4*)&out_pw[i];
        float4 y = *(const float4*)&out_pw[i + 4];
        bf16 t[8] = { __float2bfloat16(x.x), __float2bfloat16(x.y),
                      __float2bfloat16(x.z), __float2bfloat16(x.w),
                      __float2bfloat16(y.x), __float2bfloat16(y.y),
                      __float2bfloat16(y.z), __float2bfloat16(y.w) };
        *(short8*)&obf[i] = *(short8*)t;
    }
}

// ---------------------------------------------------------------------------
extern "C" void kernel_launch(void* const* d_in, const int* in_sizes, int n_in,
                              void* d_out, int out_size, void* d_ws, size_t ws_size,
                              hipStream_t stream)
{
    const float* hidden    = (const float*)d_in[0];
    const float* in_proj_w = (const float*)d_in[1];
    const float* conv_w    = (const float*)d_in[2];
    const float* conv_b    = (const float*)d_in[3];
    const float* xproj_w   = (const float*)d_in[4];
    const float* dtproj_w  = (const float*)d_in[5];
    const float* dtproj_b  = (const float*)d_in[6];
    const float* A_log     = (const float*)d_in[7];
    const float* Dvec      = (const float*)d_in[8];
    const float* conv_bw   = (const float*)d_in[9];
    const float* conv_bb   = (const float*)d_in[10];
    const float* xproj_bw  = (const float*)d_in[11];
    const float* dtproj_bw = (const float*)d_in[12];
    const float* dtproj_bb = (const float*)d_in[13];
    const float* A_b_log   = (const float*)d_in[14];
    const float* D_b       = (const float*)d_in[15];
    const float* out_pw    = (const float*)d_in[16];
    float* out = (float*)d_out;

    // Workspace layout (f32 elements). Total 31,916,032 = 127.7 MB.
    float* ws = (float*)d_ws;
    float* xz      = ws;                       // 8388608
    float* xc_f    = xz + 8388608;             // 4194304
    float* xc_b    = xc_f + 4194304;           // 4194304
    float* xdbl_f  = xc_b + 4194304;           // 196608
    float* xdbl_b  = xdbl_f + 196608;          // 196608
    float* dl_f    = xdbl_b + 196608;          // 4194304 (delta -> y)
    float* dl_b    = dl_f + 4194304;           // 4194304
    float* g2part  = dl_b + 4194304;           // 1572864
    float* sdel    = g2part + 1572864;         // 262144  (2*4*16*2048)
    float* hend    = sdel + 262144;            // 4194304 (2*4*16*16*2048); becomes hin in place
    float* smallb  = hend + 4194304;           // 327680  (xdbl_bf 196608 + dtw_bf 131072)

    // bf16 aliases over regions dead at time of use:
    bf16* hbf = (bf16*)dl_f;                   // cast_all->G1; dl_f written by g3 later
    bf16* wbf = (bf16*)(dl_f + 1048576);       // cast_all->G1
    bf16* wxf = (bf16*)dl_b;                   // cast_all->g2_mfma; dl_b written by g3 later
    bf16* wxb = (bf16*)(dl_b + 98304);
    bf16* xcbf = (bf16*)hend;                  // conv->g2_mfma; hend[0:2097152); scan1 writes later
    bf16* xcbb = (bf16*)(hend + 2097152);      // conv->g2_mfma; hend[2097152:4194304)
    bf16* xdbl_bf = (bf16*)smallb;             // g2_reduce->g3
    bf16* dtw_bf  = (bf16*)(smallb + 196608);  // cast_all->g3
    bf16* ytot_bf = (bf16*)xc_f;               // gate->g4 (xc dead after scan2)
    bf16* obf = (bf16*)xc_b;                   // gate_cast->g4
    float* g4part = dl_f;                      // g4 partials (dl dead after gate), 4194304 exact

    dim3 blk(256);

    // all pre-G1 casts in one launch
    cast_all<<<dim3(3392), blk, 0, stream>>>(
        hidden, in_proj_w, xproj_w, xproj_bw, dtproj_w, dtproj_bw,
        hbf, wbf, wxf, wxb, dtw_bf, dtw_bf + 131072);

    // G1: xz = hidden @ in_proj_w.T   (M=2048, N=4096, K=1024) bf16 MFMA
    gemm_bf16<0><<<dim3(4096 / 128, MROWS / 128), blk, 0, stream>>>(
        hbf, wbf, xz, 4096, 1024, 1024, 1024, 4096);

    // conv both dirs (fp32 + bf16 outputs)
    conv_kernel<<<dim3(2 * BB * LL * DINNER / 256), blk, 0, stream>>>(
        xz, conv_w, conv_b, conv_bw, conv_bb, xc_f, xc_b, xcbf, xcbb);

    // G2 via bf16 MFMA split-K
    g2_mfma<<<dim3(16, G2KS, 2), blk, 0, stream>>>(
        xcbf, xcbb, wxf, wxb, g2part);
    g2_reduce<<<dim3(2 * 2048 * 96 / 256), blk, 0, stream>>>(
        g2part, xdbl_f, xdbl_b, xdbl_bf);

    // G3 via bf16 MFMA (both dirs)
    g3_mfma<<<dim3(16, 16, 2), blk, 0, stream>>>(
        xdbl_bf, dtw_bf, dtproj_b, dtproj_bb, dl_f, dl_b);

    // chunked scan (SCHUNK=32, 1024-block phases, in-place combine)
    scan1_kernel<<<dim3(DINNER / 256, SNC, 8), blk, 0, stream>>>(
        A_log, A_b_log, xdbl_f, xdbl_b, xc_f, xc_b, dl_f, dl_b, sdel, hend);
    scan_combine<<<dim3(2 * BB * DSTATE * DINNER / 256), blk, 0, stream>>>(
        A_log, A_b_log, sdel, hend);
    scan2_kernel<<<dim3(DINNER / 256, SNC, 8), blk, 0, stream>>>(
        A_log, A_b_log, Dvec, D_b, xdbl_f, xdbl_b, xc_f, xc_b, hend, dl_f, dl_b);

    // gate -> bf16 ytot, + out_pw cast (fused; 16384 gate blocks + 1024 cast)
    gate_cast<<<dim3(16384 + 1024), blk, 0, stream>>>(
        dl_f, dl_b, xz, ytot_bf, out_pw, obf);

    // G4 split-K=2 + fused reduce/nan_to_num
    g4_mfma<<<dim3(1024 / 128, MROWS / 128, 2), blk, 0, stream>>>(
        ytot_bf, obf, g4part);
    g4_reduce<<<dim3(2048 * 1024 / 4 / 256), blk, 0, stream>>>(g4part, out);
}

// Round 11
// 239.456 us; speedup vs baseline: 9.2822x; 1.0399x over previous
//
#include <hip/hip_runtime.h>
#include <hip/hip_bf16.h>
#include <math.h>

// Problem constants
#define BB 4
#define LL 512
#define DMODEL 1024
#define DSTATE 16
#define DCONV 4
#define DINNER 2048
#define DTRANK 64
#define MROWS (BB*LL)          // 2048 rows of (b,l)
#define G2KS 4                 // split-K factor for the N=96 GEMM
#define SCHUNK 32              // scan chunk length
#define SNC (LL / SCHUNK)      // 16 chunks

typedef __hip_bfloat16 bf16;
typedef __attribute__((ext_vector_type(8))) short short8;
typedef __attribute__((ext_vector_type(4))) short short4v;
typedef __attribute__((ext_vector_type(4))) float f32x4;

__device__ __forceinline__ float softplusf(float x) {
    return x > 20.f ? x : log1pf(__expf(x));
}

// ---------------------------------------------------------------------------
// bf16 MFMA TN GEMM: C[M][N](f32) = A[M][K](bf16) * W[N][K](bf16)^T
// ---------------------------------------------------------------------------
template<int EPI>
__global__ __launch_bounds__(256) void gemm_bf16(
    const bf16* __restrict__ A, const bf16* __restrict__ W,
    float* __restrict__ C, int N, int K, int lda, int ldw, int ldc)
{
    __shared__ bf16 lA[128 * 40];
    __shared__ bf16 lW[128 * 40];

    const int tid = threadIdx.x;
    const int lane = tid & 63;
    const int wid = tid >> 6;
    const int wr = wid >> 1;
    const int wc = wid & 1;
    const int rowBase = blockIdx.y * 128;
    const int colBase = blockIdx.x * 128;

    const int r16 = lane & 15;
    const int kg = lane >> 4;

    f32x4 acc[4][4];
#pragma unroll
    for (int m = 0; m < 4; ++m)
#pragma unroll
        for (int n = 0; n < 4; ++n) acc[m][n] = (f32x4)0.f;

    const int srow = tid >> 2;
    const int scol = (tid & 3) * 8;

    for (int k0 = 0; k0 < K; k0 += 32) {
#pragma unroll
        for (int it = 0; it < 2; ++it) {
            int r = srow + it * 64;
            short8 va = *(const short8*)&A[(size_t)(rowBase + r) * lda + k0 + scol];
            short8 vw = *(const short8*)&W[(size_t)(colBase + r) * ldw + k0 + scol];
            *(short8*)&lA[r * 40 + scol] = va;
            *(short8*)&lW[r * 40 + scol] = vw;
        }
        __syncthreads();

        short8 a[4], b[4];
#pragma unroll
        for (int m = 0; m < 4; ++m)
            a[m] = *(const short8*)&lA[(wr * 64 + m * 16 + r16) * 40 + kg * 8];
#pragma unroll
        for (int n = 0; n < 4; ++n)
            b[n] = *(const short8*)&lW[(wc * 64 + n * 16 + r16) * 40 + kg * 8];
#pragma unroll
        for (int m = 0; m < 4; ++m)
#pragma unroll
            for (int n = 0; n < 4; ++n)
                acc[m][n] = __builtin_amdgcn_mfma_f32_16x16x32_bf16(
                    a[m], b[n], acc[m][n], 0, 0, 0);
        __syncthreads();
    }

#pragma unroll
    for (int m = 0; m < 4; ++m) {
#pragma unroll
        for (int n = 0; n < 4; ++n) {
            int gc = colBase + wc * 64 + n * 16 + r16;
#pragma unroll
            for (int j = 0; j < 4; ++j) {
                int gr = rowBase + wr * 64 + m * 16 + kg * 4 + j;
                float v = acc[m][n][j];
                if (EPI == 2) {
                    if (isnan(v)) v = 0.f;
                    else if (isinf(v)) v = (v > 0.f) ? 1.f : -1.f;
                }
                C[(size_t)gr * ldc + gc] = v;
            }
        }
    }
}

// ---------------------------------------------------------------------------
// G4 split-K: part[kz] = ytot[:, kz*1024:+1024] @ out_pw[:, kz*1024:+1024].T
// ---------------------------------------------------------------------------
__global__ __launch_bounds__(256) void g4_mfma(
    const bf16* __restrict__ A, const bf16* __restrict__ W,
    float* __restrict__ part)   // [2][2048][1024]
{
    const int kz = blockIdx.z;
    const int kOff = kz * 1024;
    float* C = part + (size_t)kz * 2048 * 1024;

    __shared__ bf16 lA[128 * 40];
    __shared__ bf16 lW[128 * 40];

    const int tid = threadIdx.x;
    const int lane = tid & 63;
    const int wid = tid >> 6;
    const int wr = wid >> 1;
    const int wc = wid & 1;
    const int rowBase = blockIdx.y * 128;
    const int colBase = blockIdx.x * 128;

    const int r16 = lane & 15;
    const int kg = lane >> 4;

    f32x4 acc[4][4];
#pragma unroll
    for (int m = 0; m < 4; ++m)
#pragma unroll
        for (int n = 0; n < 4; ++n) acc[m][n] = (f32x4)0.f;

    const int srow = tid >> 2;
    const int scol = (tid & 3) * 8;

    for (int k0 = 0; k0 < 1024; k0 += 32) {
#pragma unroll
        for (int it = 0; it < 2; ++it) {
            int r = srow + it * 64;
            short8 va = *(const short8*)&A[(size_t)(rowBase + r) * 2048 + kOff + k0 + scol];
            short8 vw = *(const short8*)&W[(size_t)(colBase + r) * 2048 + kOff + k0 + scol];
            *(short8*)&lA[r * 40 + scol] = va;
            *(short8*)&lW[r * 40 + scol] = vw;
        }
        __syncthreads();

        short8 a[4], b[4];
#pragma unroll
        for (int m = 0; m < 4; ++m)
            a[m] = *(const short8*)&lA[(wr * 64 + m * 16 + r16) * 40 + kg * 8];
#pragma unroll
        for (int n = 0; n < 4; ++n)
            b[n] = *(const short8*)&lW[(wc * 64 + n * 16 + r16) * 40 + kg * 8];
#pragma unroll
        for (int m = 0; m < 4; ++m)
#pragma unroll
            for (int n = 0; n < 4; ++n)
                acc[m][n] = __builtin_amdgcn_mfma_f32_16x16x32_bf16(
                    a[m], b[n], acc[m][n], 0, 0, 0);
        __syncthreads();
    }

#pragma unroll
    for (int m = 0; m < 4; ++m) {
#pragma unroll
        for (int n = 0; n < 4; ++n) {
            int gc = colBase + wc * 64 + n * 16 + r16;
#pragma unroll
            for (int j = 0; j < 4; ++j) {
                int gr = rowBase + wr * 64 + m * 16 + kg * 4 + j;
                C[(size_t)gr * 1024 + gc] = acc[m][n][j];
            }
        }
    }
}

// g4_reduce: out = nan_to_num(p0 + p1)
__global__ __launch_bounds__(256) void g4_reduce(
    const float* __restrict__ part, float* __restrict__ out)
{
    int i = (blockIdx.x * 256 + threadIdx.x) * 4;
    float4 p0 = *(const float4*)&part[i];
    float4 p1 = *(const float4*)&part[2048 * 1024 + i];
    float r[4] = { p0.x + p1.x, p0.y + p1.y, p0.z + p1.z, p0.w + p1.w };
#pragma unroll
    for (int j = 0; j < 4; ++j) {
        float v = r[j];
        if (isnan(v)) v = 0.f;
        else if (isinf(v)) v = (v > 0.f) ? 1.f : -1.f;
        r[j] = v;
    }
    *(float4*)&out[i] = *(float4*)r;
}

// ---------------------------------------------------------------------------
// G3 as bf16 MFMA + dt epilogue.
// ---------------------------------------------------------------------------
__global__ __launch_bounds__(256) void g3_mfma(
    const bf16* __restrict__ xdbl_bf,   // [2][2048][96]
    const bf16* __restrict__ dtw_bf,    // [2][2048][64]
    const float* __restrict__ biasf, const float* __restrict__ biasb,
    float* __restrict__ of, float* __restrict__ ob)
{
    const int dir = blockIdx.z;
    const bf16* A = xdbl_bf + (size_t)dir * 2048 * 96;
    const bf16* W = dtw_bf + (size_t)dir * 2048 * 64;
    const float* bias = dir ? biasb : biasf;
    float* C = dir ? ob : of;

    __shared__ bf16 lA[128 * 40];
    __shared__ bf16 lW[128 * 40];

    const int tid = threadIdx.x;
    const int lane = tid & 63;
    const int wid = tid >> 6;
    const int wr = wid >> 1;
    const int wc = wid & 1;
    const int rowBase = blockIdx.y * 128;
    const int colBase = blockIdx.x * 128;

    const int r16 = lane & 15;
    const int kg = lane >> 4;

    f32x4 acc[4][4];
#pragma unroll
    for (int m = 0; m < 4; ++m)
#pragma unroll
        for (int n = 0; n < 4; ++n) acc[m][n] = (f32x4)0.f;

    const int srow = tid >> 2;
    const int scol = (tid & 3) * 8;

#pragma unroll
    for (int k0 = 0; k0 < 64; k0 += 32) {
#pragma unroll
        for (int it = 0; it < 2; ++it) {
            int r = srow + it * 64;
            short8 va = *(const short8*)&A[(size_t)(rowBase + r) * 96 + k0 + scol];
            short8 vw = *(const short8*)&W[(size_t)(colBase + r) * 64 + k0 + scol];
            *(short8*)&lA[r * 40 + scol] = va;
            *(short8*)&lW[r * 40 + scol] = vw;
        }
        __syncthreads();

        short8 a[4], b[4];
#pragma unroll
        for (int m = 0; m < 4; ++m)
            a[m] = *(const short8*)&lA[(wr * 64 + m * 16 + r16) * 40 + kg * 8];
#pragma unroll
        for (int n = 0; n < 4; ++n)
            b[n] = *(const short8*)&lW[(wc * 64 + n * 16 + r16) * 40 + kg * 8];
#pragma unroll
        for (int m = 0; m < 4; ++m)
#pragma unroll
            for (int n = 0; n < 4; ++n)
                acc[m][n] = __builtin_amdgcn_mfma_f32_16x16x32_bf16(
                    a[m], b[n], acc[m][n], 0, 0, 0);
        __syncthreads();
    }

#pragma unroll
    for (int m = 0; m < 4; ++m) {
#pragma unroll
        for (int n = 0; n < 4; ++n) {
            int gc = colBase + wc * 64 + n * 16 + r16;
            float bv = bias[gc];
#pragma unroll
            for (int j = 0; j < 4; ++j) {
                int gr = rowBase + wr * 64 + m * 16 + kg * 4 + j;
                float t = acc[m][n][j] + bv;
                t = fminf(fmaxf(t, 1e-5f), 1.0f);
                C[(size_t)gr * 2048 + gc] = softplusf(t + bv);
            }
        }
    }
}

// ---------------------------------------------------------------------------
// G2 as bf16 MFMA split-K
// ---------------------------------------------------------------------------
__global__ __launch_bounds__(256) void g2_mfma(
    const bf16* __restrict__ xcbf_f, const bf16* __restrict__ xcbf_b,
    const bf16* __restrict__ wxf, const bf16* __restrict__ wxb,
    float* __restrict__ part)   // [2][G2KS][2048][96]
{
    const int dir = blockIdx.z;
    const bf16* A = dir ? xcbf_b : xcbf_f;
    const bf16* W = dir ? wxb : wxf;
    const int rowBase = blockIdx.x * 128;
    const int kz = blockIdx.y;
    const int kBase = kz * (2048 / G2KS);

    __shared__ bf16 lA[128 * 40];
    __shared__ bf16 lW[96 * 40];

    const int tid = threadIdx.x;
    const int lane = tid & 63;
    const int wid = tid >> 6;
    const int r16 = lane & 15;
    const int kg = lane >> 4;

    f32x4 acc[2][6];
#pragma unroll
    for (int m = 0; m < 2; ++m)
#pragma unroll
        for (int n = 0; n < 6; ++n) acc[m][n] = (f32x4)0.f;

    const int srow = tid >> 2;
    const int scol = (tid & 3) * 8;

    for (int k0 = 0; k0 < 2048 / G2KS; k0 += 32) {
#pragma unroll
        for (int it = 0; it < 2; ++it) {
            int r = srow + it * 64;
            short8 va = *(const short8*)&A[(size_t)(rowBase + r) * 2048 + kBase + k0 + scol];
            *(short8*)&lA[r * 40 + scol] = va;
        }
        {
            short8 vw = *(const short8*)&W[(size_t)srow * 2048 + kBase + k0 + scol];
            *(short8*)&lW[srow * 40 + scol] = vw;
        }
        if (tid < 128) {
            int r = 64 + (tid >> 2);
            short8 vw2 = *(const short8*)&W[(size_t)r * 2048 + kBase + k0 + scol];
            *(short8*)&lW[r * 40 + scol] = vw2;
        }
        __syncthreads();

        short8 a[2], b[6];
#pragma unroll
        for (int m = 0; m < 2; ++m)
            a[m] = *(const short8*)&lA[(wid * 32 + m * 16 + r16) * 40 + kg * 8];
#pragma unroll
        for (int n = 0; n < 6; ++n)
            b[n] = *(const short8*)&lW[(n * 16 + r16) * 40 + kg * 8];
#pragma unroll
        for (int m = 0; m < 2; ++m)
#pragma unroll
            for (int n = 0; n < 6; ++n)
                acc[m][n] = __builtin_amdgcn_mfma_f32_16x16x32_bf16(
                    a[m], b[n], acc[m][n], 0, 0, 0);
        __syncthreads();
    }

    float* p = part + ((size_t)(dir * G2KS + kz) * 2048) * 96;
#pragma unroll
    for (int m = 0; m < 2; ++m) {
#pragma unroll
        for (int n = 0; n < 6; ++n) {
            int gc = n * 16 + r16;
#pragma unroll
            for (int j = 0; j < 4; ++j) {
                int gr = rowBase + wid * 32 + m * 16 + kg * 4 + j;
                p[(size_t)gr * 96 + gc] = acc[m][n][j];
            }
        }
    }
}

// g2_reduce: sum split-K partials -> fp32 xdbl AND bf16 xdbl copy (for g3)
__global__ __launch_bounds__(256) void g2_reduce(
    const float* __restrict__ part, float* __restrict__ xf, float* __restrict__ xb,
    bf16* __restrict__ xdbl_bf)
{
    int idx = blockIdx.x * 256 + threadIdx.x;
    int c = idx % 96;
    int r = (idx / 96) & 2047;
    int dir = idx / (96 * 2048);
    float s = 0.f;
#pragma unroll
    for (int ks = 0; ks < G2KS; ++ks)
        s += part[((size_t)(dir * G2KS + ks) * 2048 + r) * 96 + c];
    (dir ? xb : xf)[(size_t)r * 96 + c] = s;
    xdbl_bf[((size_t)dir * 2048 + r) * 96 + c] = __float2bfloat16(s);
}

// ---------------------------------------------------------------------------
// Fused f32 -> bf16 casts (all pre-G1 casts, one launch)
// ---------------------------------------------------------------------------
__global__ __launch_bounds__(256) void cast_all(
    const float* __restrict__ hidden, const float* __restrict__ in_proj_w,
    const float* __restrict__ xproj_w, const float* __restrict__ xproj_bw,
    const float* __restrict__ dtproj_w, const float* __restrict__ dtproj_bw,
    bf16* __restrict__ hbf, bf16* __restrict__ wbf,
    bf16* __restrict__ wxf, bf16* __restrict__ wxb,
    bf16* __restrict__ dtwf, bf16* __restrict__ dtwb)
{
    int bid = blockIdx.x;
    const float* src; bf16* dst; int base;
    if (bid < 1024)      { src = hidden;    dst = hbf;  base = bid; }
    else if (bid < 3072) { src = in_proj_w; dst = wbf;  base = bid - 1024; }
    else if (bid < 3168) { src = xproj_w;   dst = wxf;  base = bid - 3072; }
    else if (bid < 3264) { src = xproj_bw;  dst = wxb;  base = bid - 3168; }
    else if (bid < 3328) { src = dtproj_w;  dst = dtwf; base = bid - 3264; }
    else                 { src = dtproj_bw; dst = dtwb; base = bid - 3328; }
    int i = (base * 256 + threadIdx.x) * 8;
    float4 x = *(const float4*)&src[i];
    float4 y = *(const float4*)&src[i + 4];
    bf16 t[8] = { __float2bfloat16(x.x), __float2bfloat16(x.y),
                  __float2bfloat16(x.z), __float2bfloat16(x.w),
                  __float2bfloat16(y.x), __float2bfloat16(y.y),
                  __float2bfloat16(y.z), __float2bfloat16(y.w) };
    *(short8*)&dst[i] = *(short8*)t;
}

// ---------------------------------------------------------------------------
// Depthwise causal conv1d, both directions, 4 channels/thread (vectorized).
// Emits fp32 xc + bf16 copy for G2.
// ---------------------------------------------------------------------------
__global__ __launch_bounds__(256) void conv_kernel(
    const float* __restrict__ xz,
    const float* __restrict__ wf, const float* __restrict__ bf,
    const float* __restrict__ wb, const float* __restrict__ bb,
    float* __restrict__ xcf, float* __restrict__ xcb,
    bf16* __restrict__ xcbf, bf16* __restrict__ xcbb)
{
    int idx = blockIdx.x * 256 + threadIdx.x;   // 2*B*L*512 thread-groups
    int dg = idx & 511;                         // channel group (4 ch)
    int rest = idx >> 9;
    int l = rest & (LL - 1);
    int b = (rest >> 9) & (BB - 1);
    int dir = rest >> 11;
    int d0 = dg * 4;

    const float* w = dir ? wb : wf;
    const float* bias = dir ? bb : bf;

    // per-channel weights: w[(d0+c)*4 + k]
    float4 wv[4];
#pragma unroll
    for (int c = 0; c < 4; ++c)
        wv[c] = *(const float4*)&w[(d0 + c) * DCONV];

    float4 acc = *(const float4*)&bias[d0];
#pragma unroll
    for (int k = 0; k < DCONV; ++k) {
        int j = l - (DCONV - 1) + k;
        if (j >= 0) {
            int jj = dir ? (LL - 1 - j) : j;
            float4 x = *(const float4*)&xz[((size_t)(b * LL + jj)) * (2 * DINNER) + d0];
            acc.x += ((const float*)&wv[0])[k] * x.x;
            acc.y += ((const float*)&wv[1])[k] * x.y;
            acc.z += ((const float*)&wv[2])[k] * x.z;
            acc.w += ((const float*)&wv[3])[k] * x.w;
        }
    }

    size_t off = ((size_t)(b * LL + l)) * DINNER + d0;
    *(float4*)&((dir ? xcb : xcf)[off]) = acc;
    bf16 t[4] = { __float2bfloat16(acc.x), __float2bfloat16(acc.y),
                  __float2bfloat16(acc.z), __float2bfloat16(acc.w) };
    *(short4v*)&((dir ? xcbb : xcbf)[off]) = *(short4v*)t;
}

// ---------------------------------------------------------------------------
// Chunked scan phase 1: local h_end (h0=0) + sum of deltas, with prefetch.
// ---------------------------------------------------------------------------
__global__ __launch_bounds__(256) void scan1_kernel(
    const float* __restrict__ Alog_f, const float* __restrict__ Alog_b,
    const float* __restrict__ xdbl_f, const float* __restrict__ xdbl_b,
    const float* __restrict__ xc_f, const float* __restrict__ xc_b,
    const float* __restrict__ dl_f, const float* __restrict__ dl_b,
    float* __restrict__ sdel, float* __restrict__ hend)
{
    const int tid = threadIdx.x;
    const int d = blockIdx.x * 256 + tid;
    const int c = blockIdx.y;
    const int z = blockIdx.z;           // dir*4 + b
    const int dir = z >> 2, b = z & 3;

    const float* Alog = dir ? Alog_b : Alog_f;
    const float* xdbl = dir ? xdbl_b : xdbl_f;
    const float* xc   = dir ? xc_b   : xc_f;
    const float* dl   = dir ? dl_b   : dl_f;
    const int rowBase = b * LL + c * SCHUNK;

    __shared__ float bs[SCHUNK][16];
#pragma unroll
    for (int i = 0; i < SCHUNK * 16 / 256; ++i) {
        int e = tid + 256 * i;
        int r = e >> 4, n = e & 15;
        bs[r][n] = xdbl[(size_t)(rowBase + r) * 96 + DTRANK + n];
    }
    __syncthreads();

    float Aa[DSTATE], h[DSTATE];
#pragma unroll
    for (int n = 0; n < DSTATE; ++n) {
        Aa[n] = -__expf(Alog[d * DSTATE + n]);
        h[n] = 0.f;
    }
    float sd = 0.f;

    float nxd = dl[(size_t)rowBase * DINNER + d];
    float nxu = xc[(size_t)rowBase * DINNER + d];
#pragma unroll 4
    for (int t = 0; t < SCHUNK; ++t) {
        float delta = nxd, u = nxu;
        if (t + 1 < SCHUNK) {
            size_t nrow = (size_t)(rowBase + t + 1);
            nxd = dl[nrow * DINNER + d];
            nxu = xc[nrow * DINNER + d];
        }
        u = fminf(fmaxf(u, -10.f), 10.f);
        float du = delta * u;
        sd += delta;
#pragma unroll
        for (int n = 0; n < DSTATE; ++n)
            h[n] = __expf(delta * Aa[n]) * h[n] + du * bs[t][n];
    }

    size_t base = (size_t)z * SNC + c;
    sdel[base * DINNER + d] = sd;
#pragma unroll
    for (int n = 0; n < DSTATE; ++n)
        hend[(base * DSTATE + n) * DINNER + d] = h[n];
}

// ---------------------------------------------------------------------------
// Combine (n-parallel, IN PLACE): hend[c] is replaced by h_in[c].
// ---------------------------------------------------------------------------
__global__ __launch_bounds__(256) void scan_combine(
    const float* __restrict__ Alog_f, const float* __restrict__ Alog_b,
    const float* __restrict__ sdel, float* __restrict__ hend)
{
    int g = blockIdx.x * 256 + threadIdx.x;
    int d = g & (DINNER - 1);
    int n = (g >> 11) & (DSTATE - 1);
    int z = g >> 15;
    const float* Alog = (z >> 2) ? Alog_b : Alog_f;

    float Aa = -__expf(Alog[d * DSTATE + n]);
    float hr = 0.f;
    for (int c = 0; c < SNC; ++c) {
        size_t base = (size_t)z * SNC + c;
        size_t idx = (base * DSTATE + n) * DINNER + d;
        float he = hend[idx];
        hend[idx] = hr;                     // now holds h_in for chunk c
        float sd = sdel[base * DINNER + d];
        hr = __expf(sd * Aa) * hr + he;
    }
}

// ---------------------------------------------------------------------------
// Chunked scan phase 2: start from h_in (stored in hend), emit y in place.
// ---------------------------------------------------------------------------
__global__ __launch_bounds__(256) void scan2_kernel(
    const float* __restrict__ Alog_f, const float* __restrict__ Alog_b,
    const float* __restrict__ Df, const float* __restrict__ Db,
    const float* __restrict__ xdbl_f, const float* __restrict__ xdbl_b,
    const float* __restrict__ xc_f, const float* __restrict__ xc_b,
    const float* __restrict__ hin,
    float* __restrict__ dl_f, float* __restrict__ dl_b)
{
    const int tid = threadIdx.x;
    const int d = blockIdx.x * 256 + tid;
    const int c = blockIdx.y;
    const int z = blockIdx.z;
    const int dir = z >> 2, b = z & 3;

    const float* Alog = dir ? Alog_b : Alog_f;
    const float* xdbl = dir ? xdbl_b : xdbl_f;
    const float* xc   = dir ? xc_b   : xc_f;
    float* dl         = dir ? dl_b   : dl_f;
    const int rowBase = b * LL + c * SCHUNK;

    __shared__ float bs[SCHUNK][32];
#pragma unroll
    for (int i = 0; i < SCHUNK * 32 / 256; ++i) {
        int e = tid + 256 * i;
        int r = e >> 5, n = e & 31;
        bs[r][n] = xdbl[(size_t)(rowBase + r) * 96 + DTRANK + n];
    }
    __syncthreads();

    float Dv = (dir ? Db : Df)[d];
    size_t base = (size_t)z * SNC + c;
    float Aa[DSTATE], h[DSTATE];
#pragma unroll
    for (int n = 0; n < DSTATE; ++n) {
        Aa[n] = -__expf(Alog[d * DSTATE + n]);
        h[n] = hin[(base * DSTATE + n) * DINNER + d];
    }

    float nxd = dl[(size_t)rowBase * DINNER + d];
    float nxu = xc[(size_t)rowBase * DINNER + d];
#pragma unroll 4
    for (int t = 0; t < SCHUNK; ++t) {
        float delta = nxd, u = nxu;
        if (t + 1 < SCHUNK) {
            size_t nrow = (size_t)(rowBase + t + 1);
            nxd = dl[nrow * DINNER + d];
            nxu = xc[nrow * DINNER + d];
        }
        u = fminf(fmaxf(u, -10.f), 10.f);
        float du = delta * u;
        float y = 0.f;
#pragma unroll
        for (int n = 0; n < DSTATE; ++n) {
            h[n] = __expf(delta * Aa[n]) * h[n] + du * bs[t][n];
            y += h[n] * bs[t][DSTATE + n];
        }
        dl[(size_t)(rowBase + t) * DINNER + d] = y + u * Dv;
    }
}

// ---------------------------------------------------------------------------
// Gate + out_pw cast fused:
// blocks [0,16384): ytot = (y_f + y_b_rev) * silu(z) -> bf16
// blocks [16384,17408): out_pw -> bf16
// ---------------------------------------------------------------------------
__global__ __launch_bounds__(256) void gate_cast(
    const float* __restrict__ yf, const float* __restrict__ yb,
    const float* __restrict__ xz, bf16* __restrict__ ytot,
    const float* __restrict__ out_pw, bf16* __restrict__ obf)
{
    int bid = blockIdx.x;
    if (bid < 16384) {
        int idx = bid * 256 + threadIdx.x;
        int d = idx & (DINNER - 1);
        int l = (idx >> 11) & (LL - 1);
        int b = idx >> 20;
        size_t rowf = (size_t)(b * LL + l);
        size_t rowb = (size_t)(b * LL + (LL - 1 - l));
        float y = yf[rowf * DINNER + d] + yb[rowb * DINNER + d];
        float z = xz[rowf * (2 * DINNER) + DINNER + d];
        float s = z / (1.f + __expf(-z));
        ytot[rowf * DINNER + d] = __float2bfloat16(y * s);
    } else {
        int i = ((bid - 16384) * 256 + threadIdx.x) * 8;
        float4 x = *(const float4*)&out_pw[i];
        float4 y = *(const float4*)&out_pw[i + 4];
        bf16 t[8] = { __float2bfloat16(x.x), __float2bfloat16(x.y),
                      __float2bfloat16(x.z), __float2bfloat16(x.w),
                      __float2bfloat16(y.x), __float2bfloat16(y.y),
                      __float2bfloat16(y.z), __float2bfloat16(y.w) };
        *(short8*)&obf[i] = *(short8*)t;
    }
}

// ---------------------------------------------------------------------------
extern "C" void kernel_launch(void* const* d_in, const int* in_sizes, int n_in,
                              void* d_out, int out_size, void* d_ws, size_t ws_size,
                              hipStream_t stream)
{
    const float* hidden    = (const float*)d_in[0];
    const float* in_proj_w = (const float*)d_in[1];
    const float* conv_w    = (const float*)d_in[2];
    const float* conv_b    = (const float*)d_in[3];
    const float* xproj_w   = (const float*)d_in[4];
    const float* dtproj_w  = (const float*)d_in[5];
    const float* dtproj_b  = (const float*)d_in[6];
    const float* A_log     = (const float*)d_in[7];
    const float* Dvec      = (const float*)d_in[8];
    const float* conv_bw   = (const float*)d_in[9];
    const float* conv_bb   = (const float*)d_in[10];
    const float* xproj_bw  = (const float*)d_in[11];
    const float* dtproj_bw = (const float*)d_in[12];
    const float* dtproj_bb = (const float*)d_in[13];
    const float* A_b_log   = (const float*)d_in[14];
    const float* D_b       = (const float*)d_in[15];
    const float* out_pw    = (const float*)d_in[16];
    float* out = (float*)d_out;

    // Workspace layout (f32 elements). Total 31,916,032 = 127.7 MB.
    float* ws = (float*)d_ws;
    float* xz      = ws;                       // 8388608
    float* xc_f    = xz + 8388608;             // 4194304
    float* xc_b    = xc_f + 4194304;           // 4194304
    float* xdbl_f  = xc_b + 4194304;           // 196608
    float* xdbl_b  = xdbl_f + 196608;          // 196608
    float* dl_f    = xdbl_b + 196608;          // 4194304 (delta -> y)
    float* dl_b    = dl_f + 4194304;           // 4194304
    float* g2part  = dl_b + 4194304;           // 1572864
    float* sdel    = g2part + 1572864;         // 262144
    float* hend    = sdel + 262144;            // 4194304; becomes hin in place
    float* smallb  = hend + 4194304;           // 327680

    // bf16 aliases over regions dead at time of use:
    bf16* hbf = (bf16*)dl_f;
    bf16* wbf = (bf16*)(dl_f + 1048576);
    bf16* wxf = (bf16*)dl_b;
    bf16* wxb = (bf16*)(dl_b + 98304);
    bf16* xcbf = (bf16*)hend;
    bf16* xcbb = (bf16*)(hend + 2097152);
    bf16* xdbl_bf = (bf16*)smallb;
    bf16* dtw_bf  = (bf16*)(smallb + 196608);
    bf16* ytot_bf = (bf16*)xc_f;
    bf16* obf = (bf16*)xc_b;
    float* g4part = dl_f;

    dim3 blk(256);

    // all pre-G1 casts in one launch
    cast_all<<<dim3(3392), blk, 0, stream>>>(
        hidden, in_proj_w, xproj_w, xproj_bw, dtproj_w, dtproj_bw,
        hbf, wbf, wxf, wxb, dtw_bf, dtw_bf + 131072);

    // G1: xz = hidden @ in_proj_w.T   (M=2048, N=4096, K=1024) bf16 MFMA
    gemm_bf16<0><<<dim3(4096 / 128, MROWS / 128), blk, 0, stream>>>(
        hbf, wbf, xz, 4096, 1024, 1024, 1024, 4096);

    // conv both dirs, 4 channels/thread (fp32 + bf16 outputs)
    conv_kernel<<<dim3(2 * BB * LL * DINNER / 4 / 256), blk, 0, stream>>>(
        xz, conv_w, conv_b, conv_bw, conv_bb, xc_f, xc_b, xcbf, xcbb);

    // G2 via bf16 MFMA split-K
    g2_mfma<<<dim3(16, G2KS, 2), blk, 0, stream>>>(
        xcbf, xcbb, wxf, wxb, g2part);
    g2_reduce<<<dim3(2 * 2048 * 96 / 256), blk, 0, stream>>>(
        g2part, xdbl_f, xdbl_b, xdbl_bf);

    // G3 via bf16 MFMA (both dirs)
    g3_mfma<<<dim3(16, 16, 2), blk, 0, stream>>>(
        xdbl_bf, dtw_bf, dtproj_b, dtproj_bb, dl_f, dl_b);

    // chunked scan (SCHUNK=32, in-place combine)
    scan1_kernel<<<dim3(DINNER / 256, SNC, 8), blk, 0, stream>>>(
        A_log, A_b_log, xdbl_f, xdbl_b, xc_f, xc_b, dl_f, dl_b, sdel, hend);
    scan_combine<<<dim3(2 * BB * DSTATE * DINNER / 256), blk, 0, stream>>>(
        A_log, A_b_log, sdel, hend);
    scan2_kernel<<<dim3(DINNER / 256, SNC, 8), blk, 0, stream>>>(
        A_log, A_b_log, Dvec, D_b, xdbl_f, xdbl_b, xc_f, xc_b, hend, dl_f, dl_b);

    // gate -> bf16 ytot, + out_pw cast (fused)
    gate_cast<<<dim3(16384 + 1024), blk, 0, stream>>>(
        dl_f, dl_b, xz, ytot_bf, out_pw, obf);

    // G4 split-K=2 + fused reduce/nan_to_num
    g4_mfma<<<dim3(1024 / 128, MROWS / 128, 2), blk, 0, stream>>>(
        ytot_bf, obf, g4part);
    g4_reduce<<<dim3(2048 * 1024 / 4 / 256), blk, 0, stream>>>(g4part, out);
}

// Round 12
// 224.705 us; speedup vs baseline: 9.8916x; 1.0656x over previous
//
#include <hip/hip_runtime.h>
#include <hip/hip_bf16.h>
#include <math.h>

// Problem constants
#define BB 4
#define LL 512
#define DMODEL 1024
#define DSTATE 16
#define DCONV 4
#define DINNER 2048
#define DTRANK 64
#define MROWS (BB*LL)          // 2048 rows of (b,l)
#define G2KS 4                 // split-K factor for the N=96 GEMM
#define SCHUNK 32              // scan chunk length
#define SNC (LL / SCHUNK)      // 16 chunks

typedef __hip_bfloat16 bf16;
typedef __attribute__((ext_vector_type(8))) short short8;
typedef __attribute__((ext_vector_type(4))) short short4v;
typedef __attribute__((ext_vector_type(4))) float f32x4;

__device__ __forceinline__ float softplusf(float x) {
    return x > 20.f ? x : log1pf(__expf(x));
}

// A has the Vim structure Aa[n] == (n+1)*Aa[0] (A_log = log(arange(1..16)))?
// Wave-uniform for this model; fallback path keeps generic correctness.
__device__ __forceinline__ bool a_is_arange(const float* Aa) {
    bool ok = true;
#pragma unroll
    for (int n = 1; n < DSTATE; ++n) {
        float k = (float)(n + 1);
        ok = ok && (fabsf(Aa[n] - k * Aa[0]) <= 1e-4f * k * fabsf(Aa[0]));
    }
    return ok;
}

// ---------------------------------------------------------------------------
// bf16 MFMA TN GEMM: C[M][N](f32) = A[M][K](bf16) * W[N][K](bf16)^T
// ---------------------------------------------------------------------------
template<int EPI>
__global__ __launch_bounds__(256) void gemm_bf16(
    const bf16* __restrict__ A, const bf16* __restrict__ W,
    float* __restrict__ C, int N, int K, int lda, int ldw, int ldc)
{
    __shared__ bf16 lA[128 * 40];
    __shared__ bf16 lW[128 * 40];

    const int tid = threadIdx.x;
    const int lane = tid & 63;
    const int wid = tid >> 6;
    const int wr = wid >> 1;
    const int wc = wid & 1;
    const int rowBase = blockIdx.y * 128;
    const int colBase = blockIdx.x * 128;

    const int r16 = lane & 15;
    const int kg = lane >> 4;

    f32x4 acc[4][4];
#pragma unroll
    for (int m = 0; m < 4; ++m)
#pragma unroll
        for (int n = 0; n < 4; ++n) acc[m][n] = (f32x4)0.f;

    const int srow = tid >> 2;
    const int scol = (tid & 3) * 8;

    for (int k0 = 0; k0 < K; k0 += 32) {
#pragma unroll
        for (int it = 0; it < 2; ++it) {
            int r = srow + it * 64;
            short8 va = *(const short8*)&A[(size_t)(rowBase + r) * lda + k0 + scol];
            short8 vw = *(const short8*)&W[(size_t)(colBase + r) * ldw + k0 + scol];
            *(short8*)&lA[r * 40 + scol] = va;
            *(short8*)&lW[r * 40 + scol] = vw;
        }
        __syncthreads();

        short8 a[4], b[4];
#pragma unroll
        for (int m = 0; m < 4; ++m)
            a[m] = *(const short8*)&lA[(wr * 64 + m * 16 + r16) * 40 + kg * 8];
#pragma unroll
        for (int n = 0; n < 4; ++n)
            b[n] = *(const short8*)&lW[(wc * 64 + n * 16 + r16) * 40 + kg * 8];
#pragma unroll
        for (int m = 0; m < 4; ++m)
#pragma unroll
            for (int n = 0; n < 4; ++n)
                acc[m][n] = __builtin_amdgcn_mfma_f32_16x16x32_bf16(
                    a[m], b[n], acc[m][n], 0, 0, 0);
        __syncthreads();
    }

#pragma unroll
    for (int m = 0; m < 4; ++m) {
#pragma unroll
        for (int n = 0; n < 4; ++n) {
            int gc = colBase + wc * 64 + n * 16 + r16;
#pragma unroll
            for (int j = 0; j < 4; ++j) {
                int gr = rowBase + wr * 64 + m * 16 + kg * 4 + j;
                float v = acc[m][n][j];
                if (EPI == 2) {
                    if (isnan(v)) v = 0.f;
                    else if (isinf(v)) v = (v > 0.f) ? 1.f : -1.f;
                }
                C[(size_t)gr * ldc + gc] = v;
            }
        }
    }
}

// ---------------------------------------------------------------------------
// G4 split-K
// ---------------------------------------------------------------------------
__global__ __launch_bounds__(256) void g4_mfma(
    const bf16* __restrict__ A, const bf16* __restrict__ W,
    float* __restrict__ part)   // [2][2048][1024]
{
    const int kz = blockIdx.z;
    const int kOff = kz * 1024;
    float* C = part + (size_t)kz * 2048 * 1024;

    __shared__ bf16 lA[128 * 40];
    __shared__ bf16 lW[128 * 40];

    const int tid = threadIdx.x;
    const int lane = tid & 63;
    const int wid = tid >> 6;
    const int wr = wid >> 1;
    const int wc = wid & 1;
    const int rowBase = blockIdx.y * 128;
    const int colBase = blockIdx.x * 128;

    const int r16 = lane & 15;
    const int kg = lane >> 4;

    f32x4 acc[4][4];
#pragma unroll
    for (int m = 0; m < 4; ++m)
#pragma unroll
        for (int n = 0; n < 4; ++n) acc[m][n] = (f32x4)0.f;

    const int srow = tid >> 2;
    const int scol = (tid & 3) * 8;

    for (int k0 = 0; k0 < 1024; k0 += 32) {
#pragma unroll
        for (int it = 0; it < 2; ++it) {
            int r = srow + it * 64;
            short8 va = *(const short8*)&A[(size_t)(rowBase + r) * 2048 + kOff + k0 + scol];
            short8 vw = *(const short8*)&W[(size_t)(colBase + r) * 2048 + kOff + k0 + scol];
            *(short8*)&lA[r * 40 + scol] = va;
            *(short8*)&lW[r * 40 + scol] = vw;
        }
        __syncthreads();

        short8 a[4], b[4];
#pragma unroll
        for (int m = 0; m < 4; ++m)
            a[m] = *(const short8*)&lA[(wr * 64 + m * 16 + r16) * 40 + kg * 8];
#pragma unroll
        for (int n = 0; n < 4; ++n)
            b[n] = *(const short8*)&lW[(wc * 64 + n * 16 + r16) * 40 + kg * 8];
#pragma unroll
        for (int m = 0; m < 4; ++m)
#pragma unroll
            for (int n = 0; n < 4; ++n)
                acc[m][n] = __builtin_amdgcn_mfma_f32_16x16x32_bf16(
                    a[m], b[n], acc[m][n], 0, 0, 0);
        __syncthreads();
    }

#pragma unroll
    for (int m = 0; m < 4; ++m) {
#pragma unroll
        for (int n = 0; n < 4; ++n) {
            int gc = colBase + wc * 64 + n * 16 + r16;
#pragma unroll
            for (int j = 0; j < 4; ++j) {
                int gr = rowBase + wr * 64 + m * 16 + kg * 4 + j;
                C[(size_t)gr * 1024 + gc] = acc[m][n][j];
            }
        }
    }
}

// g4_reduce: out = nan_to_num(p0 + p1)
__global__ __launch_bounds__(256) void g4_reduce(
    const float* __restrict__ part, float* __restrict__ out)
{
    int i = (blockIdx.x * 256 + threadIdx.x) * 4;
    float4 p0 = *(const float4*)&part[i];
    float4 p1 = *(const float4*)&part[2048 * 1024 + i];
    float r[4] = { p0.x + p1.x, p0.y + p1.y, p0.z + p1.z, p0.w + p1.w };
#pragma unroll
    for (int j = 0; j < 4; ++j) {
        float v = r[j];
        if (isnan(v)) v = 0.f;
        else if (isinf(v)) v = (v > 0.f) ? 1.f : -1.f;
        r[j] = v;
    }
    *(float4*)&out[i] = *(float4*)r;
}

// ---------------------------------------------------------------------------
// G3 as bf16 MFMA + dt epilogue.
// ---------------------------------------------------------------------------
__global__ __launch_bounds__(256) void g3_mfma(
    const bf16* __restrict__ xdbl_bf,   // [2][2048][96]
    const bf16* __restrict__ dtw_bf,    // [2][2048][64]
    const float* __restrict__ biasf, const float* __restrict__ biasb,
    float* __restrict__ of, float* __restrict__ ob)
{
    const int dir = blockIdx.z;
    const bf16* A = xdbl_bf + (size_t)dir * 2048 * 96;
    const bf16* W = dtw_bf + (size_t)dir * 2048 * 64;
    const float* bias = dir ? biasb : biasf;
    float* C = dir ? ob : of;

    __shared__ bf16 lA[128 * 40];
    __shared__ bf16 lW[128 * 40];

    const int tid = threadIdx.x;
    const int lane = tid & 63;
    const int wid = tid >> 6;
    const int wr = wid >> 1;
    const int wc = wid & 1;
    const int rowBase = blockIdx.y * 128;
    const int colBase = blockIdx.x * 128;

    const int r16 = lane & 15;
    const int kg = lane >> 4;

    f32x4 acc[4][4];
#pragma unroll
    for (int m = 0; m < 4; ++m)
#pragma unroll
        for (int n = 0; n < 4; ++n) acc[m][n] = (f32x4)0.f;

    const int srow = tid >> 2;
    const int scol = (tid & 3) * 8;

#pragma unroll
    for (int k0 = 0; k0 < 64; k0 += 32) {
#pragma unroll
        for (int it = 0; it < 2; ++it) {
            int r = srow + it * 64;
            short8 va = *(const short8*)&A[(size_t)(rowBase + r) * 96 + k0 + scol];
            short8 vw = *(const short8*)&W[(size_t)(colBase + r) * 64 + k0 + scol];
            *(short8*)&lA[r * 40 + scol] = va;
            *(short8*)&lW[r * 40 + scol] = vw;
        }
        __syncthreads();

        short8 a[4], b[4];
#pragma unroll
        for (int m = 0; m < 4; ++m)
            a[m] = *(const short8*)&lA[(wr * 64 + m * 16 + r16) * 40 + kg * 8];
#pragma unroll
        for (int n = 0; n < 4; ++n)
            b[n] = *(const short8*)&lW[(wc * 64 + n * 16 + r16) * 40 + kg * 8];
#pragma unroll
        for (int m = 0; m < 4; ++m)
#pragma unroll
            for (int n = 0; n < 4; ++n)
                acc[m][n] = __builtin_amdgcn_mfma_f32_16x16x32_bf16(
                    a[m], b[n], acc[m][n], 0, 0, 0);
        __syncthreads();
    }

#pragma unroll
    for (int m = 0; m < 4; ++m) {
#pragma unroll
        for (int n = 0; n < 4; ++n) {
            int gc = colBase + wc * 64 + n * 16 + r16;
            float bv = bias[gc];
#pragma unroll
            for (int j = 0; j < 4; ++j) {
                int gr = rowBase + wr * 64 + m * 16 + kg * 4 + j;
                float t = acc[m][n][j] + bv;
                t = fminf(fmaxf(t, 1e-5f), 1.0f);
                C[(size_t)gr * 2048 + gc] = softplusf(t + bv);
            }
        }
    }
}

// ---------------------------------------------------------------------------
// G2 as bf16 MFMA split-K
// ---------------------------------------------------------------------------
__global__ __launch_bounds__(256) void g2_mfma(
    const bf16* __restrict__ xcbf_f, const bf16* __restrict__ xcbf_b,
    const bf16* __restrict__ wxf, const bf16* __restrict__ wxb,
    float* __restrict__ part)   // [2][G2KS][2048][96]
{
    const int dir = blockIdx.z;
    const bf16* A = dir ? xcbf_b : xcbf_f;
    const bf16* W = dir ? wxb : wxf;
    const int rowBase = blockIdx.x * 128;
    const int kz = blockIdx.y;
    const int kBase = kz * (2048 / G2KS);

    __shared__ bf16 lA[128 * 40];
    __shared__ bf16 lW[96 * 40];

    const int tid = threadIdx.x;
    const int lane = tid & 63;
    const int wid = tid >> 6;
    const int r16 = lane & 15;
    const int kg = lane >> 4;

    f32x4 acc[2][6];
#pragma unroll
    for (int m = 0; m < 2; ++m)
#pragma unroll
        for (int n = 0; n < 6; ++n) acc[m][n] = (f32x4)0.f;

    const int srow = tid >> 2;
    const int scol = (tid & 3) * 8;

    for (int k0 = 0; k0 < 2048 / G2KS; k0 += 32) {
#pragma unroll
        for (int it = 0; it < 2; ++it) {
            int r = srow + it * 64;
            short8 va = *(const short8*)&A[(size_t)(rowBase + r) * 2048 + kBase + k0 + scol];
            *(short8*)&lA[r * 40 + scol] = va;
        }
        {
            short8 vw = *(const short8*)&W[(size_t)srow * 2048 + kBase + k0 + scol];
            *(short8*)&lW[srow * 40 + scol] = vw;
        }
        if (tid < 128) {
            int r = 64 + (tid >> 2);
            short8 vw2 = *(const short8*)&W[(size_t)r * 2048 + kBase + k0 + scol];
            *(short8*)&lW[r * 40 + scol] = vw2;
        }
        __syncthreads();

        short8 a[2], b[6];
#pragma unroll
        for (int m = 0; m < 2; ++m)
            a[m] = *(const short8*)&lA[(wid * 32 + m * 16 + r16) * 40 + kg * 8];
#pragma unroll
        for (int n = 0; n < 6; ++n)
            b[n] = *(const short8*)&lW[(n * 16 + r16) * 40 + kg * 8];
#pragma unroll
        for (int m = 0; m < 2; ++m)
#pragma unroll
            for (int n = 0; n < 6; ++n)
                acc[m][n] = __builtin_amdgcn_mfma_f32_16x16x32_bf16(
                    a[m], b[n], acc[m][n], 0, 0, 0);
        __syncthreads();
    }

    float* p = part + ((size_t)(dir * G2KS + kz) * 2048) * 96;
#pragma unroll
    for (int m = 0; m < 2; ++m) {
#pragma unroll
        for (int n = 0; n < 6; ++n) {
            int gc = n * 16 + r16;
#pragma unroll
            for (int j = 0; j < 4; ++j) {
                int gr = rowBase + wid * 32 + m * 16 + kg * 4 + j;
                p[(size_t)gr * 96 + gc] = acc[m][n][j];
            }
        }
    }
}

// g2_reduce: sum split-K partials -> fp32 xdbl AND bf16 xdbl copy (for g3)
__global__ __launch_bounds__(256) void g2_reduce(
    const float* __restrict__ part, float* __restrict__ xf, float* __restrict__ xb,
    bf16* __restrict__ xdbl_bf)
{
    int idx = blockIdx.x * 256 + threadIdx.x;
    int c = idx % 96;
    int r = (idx / 96) & 2047;
    int dir = idx / (96 * 2048);
    float s = 0.f;
#pragma unroll
    for (int ks = 0; ks < G2KS; ++ks)
        s += part[((size_t)(dir * G2KS + ks) * 2048 + r) * 96 + c];
    (dir ? xb : xf)[(size_t)r * 96 + c] = s;
    xdbl_bf[((size_t)dir * 2048 + r) * 96 + c] = __float2bfloat16(s);
}

// ---------------------------------------------------------------------------
// Fused f32 -> bf16 casts (all pre-G1 casts, one launch)
// ---------------------------------------------------------------------------
__global__ __launch_bounds__(256) void cast_all(
    const float* __restrict__ hidden, const float* __restrict__ in_proj_w,
    const float* __restrict__ xproj_w, const float* __restrict__ xproj_bw,
    const float* __restrict__ dtproj_w, const float* __restrict__ dtproj_bw,
    bf16* __restrict__ hbf, bf16* __restrict__ wbf,
    bf16* __restrict__ wxf, bf16* __restrict__ wxb,
    bf16* __restrict__ dtwf, bf16* __restrict__ dtwb)
{
    int bid = blockIdx.x;
    const float* src; bf16* dst; int base;
    if (bid < 1024)      { src = hidden;    dst = hbf;  base = bid; }
    else if (bid < 3072) { src = in_proj_w; dst = wbf;  base = bid - 1024; }
    else if (bid < 3168) { src = xproj_w;   dst = wxf;  base = bid - 3072; }
    else if (bid < 3264) { src = xproj_bw;  dst = wxb;  base = bid - 3168; }
    else if (bid < 3328) { src = dtproj_w;  dst = dtwf; base = bid - 3264; }
    else                 { src = dtproj_bw; dst = dtwb; base = bid - 3328; }
    int i = (base * 256 + threadIdx.x) * 8;
    float4 x = *(const float4*)&src[i];
    float4 y = *(const float4*)&src[i + 4];
    bf16 t[8] = { __float2bfloat16(x.x), __float2bfloat16(x.y),
                  __float2bfloat16(x.z), __float2bfloat16(x.w),
                  __float2bfloat16(y.x), __float2bfloat16(y.y),
                  __float2bfloat16(y.z), __float2bfloat16(y.w) };
    *(short8*)&dst[i] = *(short8*)t;
}

// ---------------------------------------------------------------------------
// Depthwise causal conv1d, 4 channels/thread (vectorized).
// ---------------------------------------------------------------------------
__global__ __launch_bounds__(256) void conv_kernel(
    const float* __restrict__ xz,
    const float* __restrict__ wf, const float* __restrict__ bf,
    const float* __restrict__ wb, const float* __restrict__ bb,
    float* __restrict__ xcf, float* __restrict__ xcb,
    bf16* __restrict__ xcbf, bf16* __restrict__ xcbb)
{
    int idx = blockIdx.x * 256 + threadIdx.x;
    int dg = idx & 511;
    int rest = idx >> 9;
    int l = rest & (LL - 1);
    int b = (rest >> 9) & (BB - 1);
    int dir = rest >> 11;
    int d0 = dg * 4;

    const float* w = dir ? wb : wf;
    const float* bias = dir ? bb : bf;

    float4 wv[4];
#pragma unroll
    for (int c = 0; c < 4; ++c)
        wv[c] = *(const float4*)&w[(d0 + c) * DCONV];

    float4 acc = *(const float4*)&bias[d0];
#pragma unroll
    for (int k = 0; k < DCONV; ++k) {
        int j = l - (DCONV - 1) + k;
        if (j >= 0) {
            int jj = dir ? (LL - 1 - j) : j;
            float4 x = *(const float4*)&xz[((size_t)(b * LL + jj)) * (2 * DINNER) + d0];
            acc.x += ((const float*)&wv[0])[k] * x.x;
            acc.y += ((const float*)&wv[1])[k] * x.y;
            acc.z += ((const float*)&wv[2])[k] * x.z;
            acc.w += ((const float*)&wv[3])[k] * x.w;
        }
    }

    size_t off = ((size_t)(b * LL + l)) * DINNER + d0;
    *(float4*)&((dir ? xcb : xcf)[off]) = acc;
    bf16 t[4] = { __float2bfloat16(acc.x), __float2bfloat16(acc.y),
                  __float2bfloat16(acc.z), __float2bfloat16(acc.w) };
    *(short4v*)&((dir ? xcbb : xcbf)[off]) = *(short4v*)t;
}

// ---------------------------------------------------------------------------
// Chunked scan phase 1: local h_end (h0=0) + sum of deltas.
// Fast path exploits Aa[n] = (n+1)*Aa[0] (1 exp + log-tree powers per step).
// ---------------------------------------------------------------------------
__global__ __launch_bounds__(256) void scan1_kernel(
    const float* __restrict__ Alog_f, const float* __restrict__ Alog_b,
    const float* __restrict__ xdbl_f, const float* __restrict__ xdbl_b,
    const float* __restrict__ xc_f, const float* __restrict__ xc_b,
    const float* __restrict__ dl_f, const float* __restrict__ dl_b,
    float* __restrict__ sdel, float* __restrict__ hend)
{
    const int tid = threadIdx.x;
    const int d = blockIdx.x * 256 + tid;
    const int c = blockIdx.y;
    const int z = blockIdx.z;           // dir*4 + b
    const int dir = z >> 2, b = z & 3;

    const float* Alog = dir ? Alog_b : Alog_f;
    const float* xdbl = dir ? xdbl_b : xdbl_f;
    const float* xc   = dir ? xc_b   : xc_f;
    const float* dl   = dir ? dl_b   : dl_f;
    const int rowBase = b * LL + c * SCHUNK;

    __shared__ float bs[SCHUNK][16];
#pragma unroll
    for (int i = 0; i < SCHUNK * 16 / 256; ++i) {
        int e = tid + 256 * i;
        int r = e >> 4, n = e & 15;
        bs[r][n] = xdbl[(size_t)(rowBase + r) * 96 + DTRANK + n];
    }
    __syncthreads();

    float Aa[DSTATE], h[DSTATE];
#pragma unroll
    for (int n = 0; n < DSTATE; ++n) {
        Aa[n] = -__expf(Alog[d * DSTATE + n]);
        h[n] = 0.f;
    }
    float sd = 0.f;
    const bool fast = a_is_arange(Aa);
    const float a0l2 = Aa[0] * 1.44269504f;   // fold log2(e): exp(x)=exp2(x*log2e)

    float nxd = dl[(size_t)rowBase * DINNER + d];
    float nxu = xc[(size_t)rowBase * DINNER + d];

    if (fast) {
#pragma unroll 4
        for (int t = 0; t < SCHUNK; ++t) {
            float delta = nxd, u = nxu;
            if (t + 1 < SCHUNK) {
                size_t nrow = (size_t)(rowBase + t + 1);
                nxd = dl[nrow * DINNER + d];
                nxu = xc[nrow * DINNER + d];
            }
            u = fminf(fmaxf(u, -10.f), 10.f);
            float du = delta * u;
            sd += delta;
            float p[DSTATE];
            p[0] = exp2f(delta * a0l2);       // e^(delta*Aa0)
#pragma unroll
            for (int n = 1; n < DSTATE; ++n)  // p[n] = e^(n+1), log depth
                p[n] = p[n >> 1] * p[(n - 1) >> 1];
#pragma unroll
            for (int n = 0; n < DSTATE; ++n)
                h[n] = p[n] * h[n] + du * bs[t][n];
        }
    } else {
#pragma unroll 4
        for (int t = 0; t < SCHUNK; ++t) {
            float delta = nxd, u = nxu;
            if (t + 1 < SCHUNK) {
                size_t nrow = (size_t)(rowBase + t + 1);
                nxd = dl[nrow * DINNER + d];
                nxu = xc[nrow * DINNER + d];
            }
            u = fminf(fmaxf(u, -10.f), 10.f);
            float du = delta * u;
            sd += delta;
#pragma unroll
            for (int n = 0; n < DSTATE; ++n)
                h[n] = __expf(delta * Aa[n]) * h[n] + du * bs[t][n];
        }
    }

    size_t base = (size_t)z * SNC + c;
    sdel[base * DINNER + d] = sd;
#pragma unroll
    for (int n = 0; n < DSTATE; ++n)
        hend[(base * DSTATE + n) * DINNER + d] = h[n];
}

// ---------------------------------------------------------------------------
// Combine (n-parallel, IN PLACE): hend[c] is replaced by h_in[c].
// ---------------------------------------------------------------------------
__global__ __launch_bounds__(256) void scan_combine(
    const float* __restrict__ Alog_f, const float* __restrict__ Alog_b,
    const float* __restrict__ sdel, float* __restrict__ hend)
{
    int g = blockIdx.x * 256 + threadIdx.x;
    int d = g & (DINNER - 1);
    int n = (g >> 11) & (DSTATE - 1);
    int z = g >> 15;
    const float* Alog = (z >> 2) ? Alog_b : Alog_f;

    float Aa = -__expf(Alog[d * DSTATE + n]);
    float hr = 0.f;
    for (int c = 0; c < SNC; ++c) {
        size_t base = (size_t)z * SNC + c;
        size_t idx = (base * DSTATE + n) * DINNER + d;
        float he = hend[idx];
        hend[idx] = hr;                     // now holds h_in for chunk c
        float sd = sdel[base * DINNER + d];
        hr = __expf(sd * Aa) * hr + he;
    }
}

// ---------------------------------------------------------------------------
// Chunked scan phase 2: start from h_in (stored in hend), emit y in place.
// Fast path as in scan1.
// ---------------------------------------------------------------------------
__global__ __launch_bounds__(256) void scan2_kernel(
    const float* __restrict__ Alog_f, const float* __restrict__ Alog_b,
    const float* __restrict__ Df, const float* __restrict__ Db,
    const float* __restrict__ xdbl_f, const float* __restrict__ xdbl_b,
    const float* __restrict__ xc_f, const float* __restrict__ xc_b,
    const float* __restrict__ hin,
    float* __restrict__ dl_f, float* __restrict__ dl_b)
{
    const int tid = threadIdx.x;
    const int d = blockIdx.x * 256 + tid;
    const int c = blockIdx.y;
    const int z = blockIdx.z;
    const int dir = z >> 2, b = z & 3;

    const float* Alog = dir ? Alog_b : Alog_f;
    const float* xdbl = dir ? xdbl_b : xdbl_f;
    const float* xc   = dir ? xc_b   : xc_f;
    float* dl         = dir ? dl_b   : dl_f;
    const int rowBase = b * LL + c * SCHUNK;

    __shared__ float bs[SCHUNK][32];
#pragma unroll
    for (int i = 0; i < SCHUNK * 32 / 256; ++i) {
        int e = tid + 256 * i;
        int r = e >> 5, n = e & 31;
        bs[r][n] = xdbl[(size_t)(rowBase + r) * 96 + DTRANK + n];
    }
    __syncthreads();

    float Dv = (dir ? Db : Df)[d];
    size_t base = (size_t)z * SNC + c;
    float Aa[DSTATE], h[DSTATE];
#pragma unroll
    for (int n = 0; n < DSTATE; ++n) {
        Aa[n] = -__expf(Alog[d * DSTATE + n]);
        h[n] = hin[(base * DSTATE + n) * DINNER + d];
    }
    const bool fast = a_is_arange(Aa);
    const float a0l2 = Aa[0] * 1.44269504f;

    float nxd = dl[(size_t)rowBase * DINNER + d];
    float nxu = xc[(size_t)rowBase * DINNER + d];

    if (fast) {
#pragma unroll 4
        for (int t = 0; t < SCHUNK; ++t) {
            float delta = nxd, u = nxu;
            if (t + 1 < SCHUNK) {
                size_t nrow = (size_t)(rowBase + t + 1);
                nxd = dl[nrow * DINNER + d];
                nxu = xc[nrow * DINNER + d];
            }
            u = fminf(fmaxf(u, -10.f), 10.f);
            float du = delta * u;
            float p[DSTATE];
            p[0] = exp2f(delta * a0l2);
#pragma unroll
            for (int n = 1; n < DSTATE; ++n)
                p[n] = p[n >> 1] * p[(n - 1) >> 1];
            float y = 0.f;
#pragma unroll
            for (int n = 0; n < DSTATE; ++n) {
                h[n] = p[n] * h[n] + du * bs[t][n];
                y += h[n] * bs[t][DSTATE + n];
            }
            dl[(size_t)(rowBase + t) * DINNER + d] = y + u * Dv;
        }
    } else {
#pragma unroll 4
        for (int t = 0; t < SCHUNK; ++t) {
            float delta = nxd, u = nxu;
            if (t + 1 < SCHUNK) {
                size_t nrow = (size_t)(rowBase + t + 1);
                nxd = dl[nrow * DINNER + d];
                nxu = xc[nrow * DINNER + d];
            }
            u = fminf(fmaxf(u, -10.f), 10.f);
            float du = delta * u;
            float y = 0.f;
#pragma unroll
            for (int n = 0; n < DSTATE; ++n) {
                h[n] = __expf(delta * Aa[n]) * h[n] + du * bs[t][n];
                y += h[n] * bs[t][DSTATE + n];
            }
            dl[(size_t)(rowBase + t) * DINNER + d] = y + u * Dv;
        }
    }
}

// ---------------------------------------------------------------------------
// Gate + out_pw cast fused
// ---------------------------------------------------------------------------
__global__ __launch_bounds__(256) void gate_cast(
    const float* __restrict__ yf, const float* __restrict__ yb,
    const float* __restrict__ xz, bf16* __restrict__ ytot,
    const float* __restrict__ out_pw, bf16* __restrict__ obf)
{
    int bid = blockIdx.x;
    if (bid < 16384) {
        int idx = bid * 256 + threadIdx.x;
        int d = idx & (DINNER - 1);
        int l = (idx >> 11) & (LL - 1);
        int b = idx >> 20;
        size_t rowf = (size_t)(b * LL + l);
        size_t rowb = (size_t)(b * LL + (LL - 1 - l));
        float y = yf[rowf * DINNER + d] + yb[rowb * DINNER + d];
        float z = xz[rowf * (2 * DINNER) + DINNER + d];
        float s = z / (1.f + __expf(-z));
        ytot[rowf * DINNER + d] = __float2bfloat16(y * s);
    } else {
        int i = ((bid - 16384) * 256 + threadIdx.x) * 8;
        float4 x = *(const float4*)&out_pw[i];
        float4 y = *(const float4*)&out_pw[i + 4];
        bf16 t[8] = { __float2bfloat16(x.x), __float2bfloat16(x.y),
                      __float2bfloat16(x.z), __float2bfloat16(x.w),
                      __float2bfloat16(y.x), __float2bfloat16(y.y),
                      __float2bfloat16(y.z), __float2bfloat16(y.w) };
        *(short8*)&obf[i] = *(short8*)t;
    }
}

// ---------------------------------------------------------------------------
extern "C" void kernel_launch(void* const* d_in, const int* in_sizes, int n_in,
                              void* d_out, int out_size, void* d_ws, size_t ws_size,
                              hipStream_t stream)
{
    const float* hidden    = (const float*)d_in[0];
    const float* in_proj_w = (const float*)d_in[1];
    const float* conv_w    = (const float*)d_in[2];
    const float* conv_b    = (const float*)d_in[3];
    const float* xproj_w   = (const float*)d_in[4];
    const float* dtproj_w  = (const float*)d_in[5];
    const float* dtproj_b  = (const float*)d_in[6];
    const float* A_log     = (const float*)d_in[7];
    const float* Dvec      = (const float*)d_in[8];
    const float* conv_bw   = (const float*)d_in[9];
    const float* conv_bb   = (const float*)d_in[10];
    const float* xproj_bw  = (const float*)d_in[11];
    const float* dtproj_bw = (const float*)d_in[12];
    const float* dtproj_bb = (const float*)d_in[13];
    const float* A_b_log   = (const float*)d_in[14];
    const float* D_b       = (const float*)d_in[15];
    const float* out_pw    = (const float*)d_in[16];
    float* out = (float*)d_out;

    // Workspace layout (f32 elements). Total 31,916,032 = 127.7 MB.
    float* ws = (float*)d_ws;
    float* xz      = ws;                       // 8388608
    float* xc_f    = xz + 8388608;             // 4194304
    float* xc_b    = xc_f + 4194304;           // 4194304
    float* xdbl_f  = xc_b + 4194304;           // 196608
    float* xdbl_b  = xdbl_f + 196608;          // 196608
    float* dl_f    = xdbl_b + 196608;          // 4194304 (delta -> y)
    float* dl_b    = dl_f + 4194304;           // 4194304
    float* g2part  = dl_b + 4194304;           // 1572864
    float* sdel    = g2part + 1572864;         // 262144
    float* hend    = sdel + 262144;            // 4194304; becomes hin in place
    float* smallb  = hend + 4194304;           // 327680

    // bf16 aliases over regions dead at time of use:
    bf16* hbf = (bf16*)dl_f;
    bf16* wbf = (bf16*)(dl_f + 1048576);
    bf16* wxf = (bf16*)dl_b;
    bf16* wxb = (bf16*)(dl_b + 98304);
    bf16* xcbf = (bf16*)hend;
    bf16* xcbb = (bf16*)(hend + 2097152);
    bf16* xdbl_bf = (bf16*)smallb;
    bf16* dtw_bf  = (bf16*)(smallb + 196608);
    bf16* ytot_bf = (bf16*)xc_f;
    bf16* obf = (bf16*)xc_b;
    float* g4part = dl_f;

    dim3 blk(256);

    // all pre-G1 casts in one launch
    cast_all<<<dim3(3392), blk, 0, stream>>>(
        hidden, in_proj_w, xproj_w, xproj_bw, dtproj_w, dtproj_bw,
        hbf, wbf, wxf, wxb, dtw_bf, dtw_bf + 131072);

    // G1: xz = hidden @ in_proj_w.T   (M=2048, N=4096, K=1024) bf16 MFMA
    gemm_bf16<0><<<dim3(4096 / 128, MROWS / 128), blk, 0, stream>>>(
        hbf, wbf, xz, 4096, 1024, 1024, 1024, 4096);

    // conv both dirs, 4 channels/thread (fp32 + bf16 outputs)
    conv_kernel<<<dim3(2 * BB * LL * DINNER / 4 / 256), blk, 0, stream>>>(
        xz, conv_w, conv_b, conv_bw, conv_bb, xc_f, xc_b, xcbf, xcbb);

    // G2 via bf16 MFMA split-K
    g2_mfma<<<dim3(16, G2KS, 2), blk, 0, stream>>>(
        xcbf, xcbb, wxf, wxb, g2part);
    g2_reduce<<<dim3(2 * 2048 * 96 / 256), blk, 0, stream>>>(
        g2part, xdbl_f, xdbl_b, xdbl_bf);

    // G3 via bf16 MFMA (both dirs)
    g3_mfma<<<dim3(16, 16, 2), blk, 0, stream>>>(
        xdbl_bf, dtw_bf, dtproj_b, dtproj_bb, dl_f, dl_b);

    // chunked scan (SCHUNK=32, in-place combine, arange-A fast path)
    scan1_kernel<<<dim3(DINNER / 256, SNC, 8), blk, 0, stream>>>(
        A_log, A_b_log, xdbl_f, xdbl_b, xc_f, xc_b, dl_f, dl_b, sdel, hend);
    scan_combine<<<dim3(2 * BB * DSTATE * DINNER / 256), blk, 0, stream>>>(
        A_log, A_b_log, sdel, hend);
    scan2_kernel<<<dim3(DINNER / 256, SNC, 8), blk, 0, stream>>>(
        A_log, A_b_log, Dvec, D_b, xdbl_f, xdbl_b, xc_f, xc_b, hend, dl_f, dl_b);

    // gate -> bf16 ytot, + out_pw cast (fused)
    gate_cast<<<dim3(16384 + 1024), blk, 0, stream>>>(
        dl_f, dl_b, xz, ytot_bf, out_pw, obf);

    // G4 split-K=2 + fused reduce/nan_to_num
    g4_mfma<<<dim3(1024 / 128, MROWS / 128, 2), blk, 0, stream>>>(
        ytot_bf, obf, g4part);
    g4_reduce<<<dim3(2048 * 1024 / 4 / 256), blk, 0, stream>>>(g4part, out);
}